// Round 2
// baseline (5857.552 us; speedup 1.0000x reference)
//
#include <hip/hip_runtime.h>
#include <math.h>

#define NN 100000
#define EE 1600000

// ---------------------------------------------------------------------------
// Weight folding:  M_g = convW_g @ linW_g[0:128,:]        (128x128)
//                  B_g = [ W1 @ M_g ; linW_g[128:256,:] ] (256x128)
//                  v_g = b1 @ M_g                          (128)
//                  c_g = convb_g @ linW_g[0:128,:] + linb_g (128)
// Gate pre-activation: a_g = [y | H] @ B_g + s*v_g + c_g
// where y = Norm(x) (N x 128), s = Norm(1) (N), Norm = D^-1/2 (A+I) D^-1/2
// ---------------------------------------------------------------------------

__global__ void prep1(const float* __restrict__ Wcz, const float* __restrict__ Wcr,
                      const float* __restrict__ Wch,
                      const float* __restrict__ Wlz, const float* __restrict__ Wlr,
                      const float* __restrict__ Wlh,
                      float* __restrict__ M) {
    int idx = blockIdx.x * 256 + threadIdx.x;   // 3*16384
    int g = idx >> 14, r = idx & 16383;
    int i = r >> 7, j = r & 127;
    const float* Wc = g == 0 ? Wcz : (g == 1 ? Wcr : Wch);
    const float* Wl = g == 0 ? Wlz : (g == 1 ? Wlr : Wlh);
    float s = 0.f;
    for (int m = 0; m < 128; m++) s += Wc[i * 128 + m] * Wl[m * 128 + j];
    M[idx] = s;
}

__global__ void prep2(const float* __restrict__ W1, const float* __restrict__ M,
                      const float* __restrict__ Wlz, const float* __restrict__ Wlr,
                      const float* __restrict__ Wlh,
                      float* __restrict__ B) {
    int idx = blockIdx.x * 256 + threadIdx.x;  // 3*256*128
    int g = idx >> 15, r = idx & 32767;
    int k = r >> 7, j = r & 127;
    float o;
    if (k < 128) {
        const float* Mg = M + g * 16384;
        float sacc = 0.f;
        for (int m = 0; m < 128; m++) sacc += W1[k * 128 + m] * Mg[m * 128 + j];
        o = sacc;
    } else {
        const float* Wl = g == 0 ? Wlz : (g == 1 ? Wlr : Wlh);
        o = Wl[k * 128 + j];
    }
    B[idx] = o;
}

__global__ void prep3(const float* __restrict__ b1, const float* __restrict__ M,
                      const float* __restrict__ bcz, const float* __restrict__ bcr,
                      const float* __restrict__ bch,
                      const float* __restrict__ Wlz, const float* __restrict__ Wlr,
                      const float* __restrict__ Wlh,
                      const float* __restrict__ blz, const float* __restrict__ blr,
                      const float* __restrict__ blh,
                      float* __restrict__ v, float* __restrict__ c) {
    int idx = blockIdx.x * 256 + threadIdx.x;
    if (idx >= 384) return;
    int g = idx >> 7, j = idx & 127;
    const float* Mg = M + g * 16384;
    float sv = 0.f;
    for (int m = 0; m < 128; m++) sv += b1[m] * Mg[m * 128 + j];
    v[idx] = sv;
    const float* bc = g == 0 ? bcz : (g == 1 ? bcr : bch);
    const float* Wl = g == 0 ? Wlz : (g == 1 ? Wlr : Wlh);
    const float* bl = g == 0 ? blz : (g == 1 ? blr : blh);
    float sc = bl[j];
    for (int m = 0; m < 128; m++) sc += bc[m] * Wl[m * 128 + j];
    c[idx] = sc;
}

// ---------------------------------------------------------------------------
__global__ void deg_kernel(const int* __restrict__ dst, float* __restrict__ deg) {
    int i = blockIdx.x * blockDim.x + threadIdx.x;
    int stride = gridDim.x * blockDim.x;
    for (; i < EE; i += stride) atomicAdd(&deg[dst[i]], 1.0f);
}

__global__ void dinv_kernel(const float* __restrict__ deg, float* __restrict__ dinv) {
    int i = blockIdx.x * blockDim.x + threadIdx.x;
    if (i < NN) dinv[i] = rsqrtf(deg[i] + 1.0f);  // +1 = self loop
}

__global__ void s_scatter(const int* __restrict__ src, const int* __restrict__ dst,
                          const float* __restrict__ dinv, float* __restrict__ sv) {
    int i = blockIdx.x * blockDim.x + threadIdx.x;
    int stride = gridDim.x * blockDim.x;
    for (; i < EE; i += stride) atomicAdd(&sv[dst[i]], dinv[src[i]]);
}

__global__ void s_finish(const float* __restrict__ dinv, float* __restrict__ sv) {
    int i = blockIdx.x * blockDim.x + threadIdx.x;
    if (i < NN) sv[i] = dinv[i] * (sv[i] + dinv[i]);
}

// agg[dst] += dinv[src] * x[src]   (128 feats, one wave per edge, float2/lane)
__global__ void x_scatter(const int* __restrict__ src, const int* __restrict__ dst,
                          const float* __restrict__ x, const float* __restrict__ dinv,
                          float* __restrict__ agg) {
    int lane = threadIdx.x & 63;
    int wave = blockIdx.x * (blockDim.x >> 6) + (threadIdx.x >> 6);
    int nw = gridDim.x * (blockDim.x >> 6);
    for (int e = wave; e < EE; e += nw) {
        int s = src[e], d = dst[e];
        float f = dinv[s];
        float2 xv = *(const float2*)&x[(size_t)s * 128 + lane * 2];
        float* ap = &agg[(size_t)d * 128 + lane * 2];
        atomicAdd(ap, f * xv.x);
        atomicAdd(ap + 1, f * xv.y);
    }
}

// y[i] = dinv[i] * (agg[i] + dinv[i]*x[i])   (in place into agg)
__global__ void y_finish(const float* __restrict__ x, const float* __restrict__ dinv,
                         float* __restrict__ agg) {
    int idx = blockIdx.x * 256 + threadIdx.x;      // N*32 threads, float4 each
    int row = idx >> 5;
    int c4 = (idx & 31) * 4;
    float di = dinv[row];
    size_t o = (size_t)row * 128 + c4;
    float4 a = *(float4*)&agg[o];
    float4 xv = *(const float4*)&x[o];
    a.x = di * (a.x + di * xv.x);
    a.y = di * (a.y + di * xv.y);
    a.z = di * (a.z + di * xv.z);
    a.w = di * (a.w + di * xv.w);
    *(float4*)&agg[o] = a;
}

// ---------------------------------------------------------------------------
// Gate GEMM: 64 rows x 128 cols per block, K=256 over virtual [y | A1].
// FUSED=false (r gate): out = H * sigmoid(a_r)            (A1 = H)
// FUSED=true  (z+h)   : out = z*H + (1-z)*tanh(a_h)       (A1z = H, A1h = HR)
//                       written in place over HR (block owns its rows fully)
// ---------------------------------------------------------------------------
template <bool FUSED>
__launch_bounds__(256, 2)
__global__ void gate_gemm(const float* __restrict__ Y,
                          const float* __restrict__ H,
                          const float* __restrict__ HR,
                          const float* __restrict__ B0, const float* __restrict__ B1,
                          const float* __restrict__ v0, const float* __restrict__ c0,
                          const float* __restrict__ v1, const float* __restrict__ c1,
                          const float* __restrict__ svec,
                          float* __restrict__ out) {
    __shared__ float As0[32][64];
    __shared__ float As1[FUSED ? 32 : 1][64];
    __shared__ float Bs0[32][128];
    __shared__ float Bs1[FUSED ? 32 : 1][128];

    const int tid = threadIdx.x;
    const int rowBase = blockIdx.x * 64;
    const int lar = tid >> 2, lak = (tid & 3) * 8;
    const int lbk = tid >> 3, lbc = (tid & 7) * 16;
    const int tr = (tid >> 4) * 4, tc = (tid & 15) * 8;

    float acc0[4][8] = {};
    float acc1[4][8] = {};

    const int grow = rowBase + lar;
    const bool inr = grow < NN;

    for (int kc = 0; kc < 256; kc += 32) {
        // ---- stage A tiles ----
        float4 av0 = {0, 0, 0, 0}, av1 = {0, 0, 0, 0};
        if (inr) {
            const float* p = ((kc < 128) ? Y : H) + (size_t)grow * 128 + (kc & 127) + lak;
            av0 = *(const float4*)p;
            av1 = *(const float4*)(p + 4);
        }
        As0[lak + 0][lar] = av0.x; As0[lak + 1][lar] = av0.y;
        As0[lak + 2][lar] = av0.z; As0[lak + 3][lar] = av0.w;
        As0[lak + 4][lar] = av1.x; As0[lak + 5][lar] = av1.y;
        As0[lak + 6][lar] = av1.z; As0[lak + 7][lar] = av1.w;
        if (FUSED) {
            float4 bv0 = av0, bv1 = av1;
            if (kc >= 128) {
                bv0 = make_float4(0, 0, 0, 0); bv1 = make_float4(0, 0, 0, 0);
                if (inr) {
                    const float* p = HR + (size_t)grow * 128 + (kc - 128) + lak;
                    bv0 = *(const float4*)p;
                    bv1 = *(const float4*)(p + 4);
                }
            }
            As1[lak + 0][lar] = bv0.x; As1[lak + 1][lar] = bv0.y;
            As1[lak + 2][lar] = bv0.z; As1[lak + 3][lar] = bv0.w;
            As1[lak + 4][lar] = bv1.x; As1[lak + 5][lar] = bv1.y;
            As1[lak + 6][lar] = bv1.z; As1[lak + 7][lar] = bv1.w;
        }
        // ---- stage B tiles ----
        {
            const float* p = B0 + (size_t)(kc + lbk) * 128 + lbc;
            *(float4*)&Bs0[lbk][lbc]      = *(const float4*)p;
            *(float4*)&Bs0[lbk][lbc + 4]  = *(const float4*)(p + 4);
            *(float4*)&Bs0[lbk][lbc + 8]  = *(const float4*)(p + 8);
            *(float4*)&Bs0[lbk][lbc + 12] = *(const float4*)(p + 12);
            if (FUSED) {
                const float* q = B1 + (size_t)(kc + lbk) * 128 + lbc;
                *(float4*)&Bs1[lbk][lbc]      = *(const float4*)q;
                *(float4*)&Bs1[lbk][lbc + 4]  = *(const float4*)(q + 4);
                *(float4*)&Bs1[lbk][lbc + 8]  = *(const float4*)(q + 8);
                *(float4*)&Bs1[lbk][lbc + 12] = *(const float4*)(q + 12);
            }
        }
        __syncthreads();

        #pragma unroll
        for (int kk = 0; kk < 32; kk++) {
            float4 a4 = *(const float4*)&As0[kk][tr];
            float a[4] = {a4.x, a4.y, a4.z, a4.w};
            float b0[8];
            *(float4*)&b0[0] = *(const float4*)&Bs0[kk][tc];
            *(float4*)&b0[4] = *(const float4*)&Bs0[kk][tc + 4];
            #pragma unroll
            for (int i = 0; i < 4; i++)
                #pragma unroll
                for (int j = 0; j < 8; j++) acc0[i][j] += a[i] * b0[j];
            if (FUSED) {
                float4 c4v = *(const float4*)&As1[kk][tr];
                float aa[4] = {c4v.x, c4v.y, c4v.z, c4v.w};
                float b1r[8];
                *(float4*)&b1r[0] = *(const float4*)&Bs1[kk][tc];
                *(float4*)&b1r[4] = *(const float4*)&Bs1[kk][tc + 4];
                #pragma unroll
                for (int i = 0; i < 4; i++)
                    #pragma unroll
                    for (int j = 0; j < 8; j++) acc1[i][j] += aa[i] * b1r[j];
            }
        }
        __syncthreads();
    }

    #pragma unroll
    for (int i = 0; i < 4; i++) {
        int row = rowBase + tr + i;
        if (row >= NN) break;
        float srow = svec[row];
        #pragma unroll
        for (int j = 0; j < 8; j++) {
            int col = tc + j;
            size_t o = (size_t)row * 128 + col;
            float a = acc0[i][j] + srow * v0[col] + c0[col];
            if (FUSED) {
                float z = 1.f / (1.f + expf(-a));
                float b = acc1[i][j] + srow * v1[col] + c1[col];
                float ht = tanhf(b);
                out[o] = z * H[o] + (1.f - z) * ht;
            } else {
                out[o] = H[o] / (1.f + expf(-a));
            }
        }
    }
}

// ---------------------------------------------------------------------------
__global__ void maxpool_partial(const float* __restrict__ H, float* __restrict__ part) {
    int c = threadIdx.x;  // 128
    float m = -1e30f;
    for (int r = blockIdx.x; r < NN; r += gridDim.x)
        m = fmaxf(m, H[(size_t)r * 128 + c]);
    part[blockIdx.x * 128 + c] = m;
}

__global__ void final_out(const float* __restrict__ part, const float* __restrict__ W2,
                          const float* __restrict__ b2, float* __restrict__ out) {
    __shared__ float hmax[128];
    int tid = threadIdx.x;  // 128
    float m = -1e30f;
    for (int b = 0; b < 256; b++) m = fmaxf(m, part[b * 128 + tid]);
    hmax[tid] = m;
    __syncthreads();
    if (tid < 10) {
        float sacc = b2[tid];
        for (int c = 0; c < 128; c++) sacc += hmax[c] * W2[c * 10 + tid];
        out[tid] = sacc;
    }
}

extern "C" void kernel_launch(void* const* d_in, const int* in_sizes, int n_in,
                              void* d_out, int out_size, void* d_ws, size_t ws_size,
                              hipStream_t stream) {
    const float* x[3]     = {(const float*)d_in[0], (const float*)d_in[2], (const float*)d_in[4]};
    const int*   edges[3] = {(const int*)d_in[1], (const int*)d_in[3], (const int*)d_in[5]};
    const float* W1 = (const float*)d_in[6];
    const float* b1 = (const float*)d_in[7];
    const float* convW[3] = {(const float*)d_in[8], (const float*)d_in[12], (const float*)d_in[16]};
    const float* convb[3] = {(const float*)d_in[9], (const float*)d_in[13], (const float*)d_in[17]};
    const float* linW[3]  = {(const float*)d_in[10], (const float*)d_in[14], (const float*)d_in[18]};
    const float* linb[3]  = {(const float*)d_in[11], (const float*)d_in[15], (const float*)d_in[19]};
    const float* W2 = (const float*)d_in[20];
    const float* b2 = (const float*)d_in[21];

    float* ws   = (float*)d_ws;
    float* B3   = ws;                  // 3*256*128 = 98304
    float* v3   = B3 + 98304;          // 384
    float* c3   = v3 + 384;            // 384
    float* M    = c3 + 384;            // 3*128*128 = 49152
    float* deg  = M + 49152;           // NN
    float* sv   = deg + NN;            // NN   (adjacent to deg: one memset)
    float* dinv = sv + NN;             // NN
    float* part = dinv + NN;           // 256*128 = 32768
    float* agg  = part + 32768;        // NN*128  (y, in place)
    float* bufA = agg + (size_t)NN * 128;
    float* bufB = bufA + (size_t)NN * 128;
    // total: 481024 + 3*12.8M floats = 38,881,024 floats = 155.5 MB

    prep1<<<192, 256, 0, stream>>>(convW[0], convW[1], convW[2],
                                   linW[0], linW[1], linW[2], M);
    prep2<<<384, 256, 0, stream>>>(W1, M, linW[0], linW[1], linW[2], B3);
    prep3<<<2, 256, 0, stream>>>(b1, M, convb[0], convb[1], convb[2],
                                 linW[0], linW[1], linW[2],
                                 linb[0], linb[1], linb[2], v3, c3);

    hipMemsetAsync(bufA, 0, (size_t)NN * 128 * sizeof(float), stream);  // H = 0

    float* P = bufA;  // H in
    float* Q = bufB;  // Hr then H out

    for (int t = 0; t < 3; t++) {
        const int* src = edges[t];
        const int* dst = edges[t] + EE;

        hipMemsetAsync(deg, 0, 2 * NN * sizeof(float), stream);  // deg + sv
        deg_kernel<<<2048, 256, 0, stream>>>(dst, deg);
        dinv_kernel<<<(NN + 255) / 256, 256, 0, stream>>>(deg, dinv);
        s_scatter<<<2048, 256, 0, stream>>>(src, dst, dinv, sv);
        s_finish<<<(NN + 255) / 256, 256, 0, stream>>>(dinv, sv);

        hipMemsetAsync(agg, 0, (size_t)NN * 128 * sizeof(float), stream);
        x_scatter<<<8192, 256, 0, stream>>>(src, dst, x[t], dinv, agg);
        y_finish<<<12500, 256, 0, stream>>>(x[t], dinv, agg);

        // r gate: Q = H * sigmoid(a_r)
        gate_gemm<false><<<1563, 256, 0, stream>>>(
            agg, P, nullptr, B3 + 1 * 32768, nullptr,
            v3 + 128, c3 + 128, nullptr, nullptr, sv, Q);
        // z + h gates: Q = z*H + (1-z)*tanh(a_h)   (in place over Hr)
        gate_gemm<true><<<1563, 256, 0, stream>>>(
            agg, P, Q, B3 + 0 * 32768, B3 + 2 * 32768,
            v3 + 0, c3 + 0, v3 + 256, c3 + 256, sv, Q);

        float* tmp = P; P = Q; Q = tmp;  // H <- new H
    }

    maxpool_partial<<<256, 128, 0, stream>>>(P, part);
    final_out<<<1, 128, 0, stream>>>(part, W2, b2, (float*)d_out);
}

// Round 3
// 2172.041 us; speedup vs baseline: 2.6968x; 2.6968x over previous
//
#include <hip/hip_runtime.h>
#include <math.h>

#define NN 100000
#define EE 1600000
#define SCAN_B 1024
#define SCAN_NB 98   // ceil(100000/1024)

// ---------------------------------------------------------------------------
// Weight folding:  M_g = convW_g @ linW_g[0:128,:]        (128x128)
//                  B_g = [ W1 @ M_g ; linW_g[128:256,:] ] (256x128)
//                  v_g = b1 @ M_g                          (128)
//                  c_g = convb_g @ linW_g[0:128,:] + linb_g (128)
// Gate pre-activation: a_g = [y | H] @ B_g + s*v_g + c_g
// where y = Norm(x) (N x 128), s = Norm(1) (N), Norm = D^-1/2 (A+I) D^-1/2
// ---------------------------------------------------------------------------
__global__ void prep1(const float* __restrict__ Wcz, const float* __restrict__ Wcr,
                      const float* __restrict__ Wch,
                      const float* __restrict__ Wlz, const float* __restrict__ Wlr,
                      const float* __restrict__ Wlh,
                      float* __restrict__ M) {
    int idx = blockIdx.x * 256 + threadIdx.x;   // 3*16384
    int g = idx >> 14, r = idx & 16383;
    int i = r >> 7, j = r & 127;
    const float* Wc = g == 0 ? Wcz : (g == 1 ? Wcr : Wch);
    const float* Wl = g == 0 ? Wlz : (g == 1 ? Wlr : Wlh);
    float s = 0.f;
    for (int m = 0; m < 128; m++) s += Wc[i * 128 + m] * Wl[m * 128 + j];
    M[idx] = s;
}

__global__ void prep2(const float* __restrict__ W1, const float* __restrict__ M,
                      const float* __restrict__ Wlz, const float* __restrict__ Wlr,
                      const float* __restrict__ Wlh,
                      float* __restrict__ B) {
    int idx = blockIdx.x * 256 + threadIdx.x;  // 3*256*128
    int g = idx >> 15, r = idx & 32767;
    int k = r >> 7, j = r & 127;
    float o;
    if (k < 128) {
        const float* Mg = M + g * 16384;
        float sacc = 0.f;
        for (int m = 0; m < 128; m++) sacc += W1[k * 128 + m] * Mg[m * 128 + j];
        o = sacc;
    } else {
        const float* Wl = g == 0 ? Wlz : (g == 1 ? Wlr : Wlh);
        o = Wl[k * 128 + j];
    }
    B[idx] = o;
}

__global__ void prep3(const float* __restrict__ b1, const float* __restrict__ M,
                      const float* __restrict__ bcz, const float* __restrict__ bcr,
                      const float* __restrict__ bch,
                      const float* __restrict__ Wlz, const float* __restrict__ Wlr,
                      const float* __restrict__ Wlh,
                      const float* __restrict__ blz, const float* __restrict__ blr,
                      const float* __restrict__ blh,
                      float* __restrict__ v, float* __restrict__ c) {
    int idx = blockIdx.x * 256 + threadIdx.x;
    if (idx >= 384) return;
    int g = idx >> 7, j = idx & 127;
    const float* Mg = M + g * 16384;
    float sv = 0.f;
    for (int m = 0; m < 128; m++) sv += b1[m] * Mg[m * 128 + j];
    v[idx] = sv;
    const float* bc = g == 0 ? bcz : (g == 1 ? bcr : bch);
    const float* Wl = g == 0 ? Wlz : (g == 1 ? Wlr : Wlh);
    const float* bl = g == 0 ? blz : (g == 1 ? blr : blh);
    float sc = bl[j];
    for (int m = 0; m < 128; m++) sc += bc[m] * Wl[m * 128 + j];
    c[idx] = sc;
}

// ---------------------------------------------------------------------------
// CSR build: histogram -> exclusive scan -> bucket fill
// ---------------------------------------------------------------------------
__global__ void hist_kernel(const int* __restrict__ dst, int* __restrict__ deg) {
    int i = blockIdx.x * blockDim.x + threadIdx.x;
    int stride = gridDim.x * blockDim.x;
    for (; i < EE; i += stride) atomicAdd(&deg[dst[i]], 1);
}

__global__ void dinv_kernel(const int* __restrict__ deg, float* __restrict__ dinv) {
    int i = blockIdx.x * blockDim.x + threadIdx.x;
    if (i < NN) dinv[i] = rsqrtf((float)deg[i] + 1.0f);  // +1 = self loop
}

// exclusive scan within chunk of 1024; partial[b] = chunk total
__global__ void scan_local(const int* __restrict__ deg, int* __restrict__ offs,
                           int* __restrict__ partial) {
    __shared__ int sm[SCAN_B];
    int t = threadIdx.x;
    int i = blockIdx.x * SCAN_B + t;
    int v = (i < NN) ? deg[i] : 0;
    sm[t] = v;
    __syncthreads();
    #pragma unroll
    for (int off = 1; off < SCAN_B; off <<= 1) {
        int x = (t >= off) ? sm[t - off] : 0;
        __syncthreads();
        sm[t] += x;
        __syncthreads();
    }
    if (i < NN) offs[i] = sm[t] - v;   // exclusive (local)
    if (t == SCAN_B - 1) partial[blockIdx.x] = sm[t];
}

__global__ void scan_carry(int* __restrict__ partial, int* __restrict__ offs) {
    if (threadIdx.x == 0) {
        int carry = 0;
        for (int b = 0; b < SCAN_NB; b++) {
            int p = partial[b];
            partial[b] = carry;
            carry += p;
        }
        offs[NN] = carry;  // == EE
    }
}

__global__ void scan_add(int* __restrict__ offs, const int* __restrict__ partial) {
    int i = blockIdx.x * SCAN_B + threadIdx.x;
    if (i < NN) offs[i] += partial[blockIdx.x];
}

__global__ void bucket_fill(const int* __restrict__ src, const int* __restrict__ dst,
                            const int* __restrict__ offs, int* __restrict__ cursor,
                            int* __restrict__ sorted_src) {
    int i = blockIdx.x * blockDim.x + threadIdx.x;
    int stride = gridDim.x * blockDim.x;
    for (; i < EE; i += stride) {
        int d = dst[i];
        int pos = offs[d] + atomicAdd(&cursor[d], 1);
        sorted_src[pos] = src[i];
    }
}

// ---------------------------------------------------------------------------
// Gather aggregation: one wave per dst node.
// y[i] = dinv[i] * ( sum_{s in N(i)} dinv[s]*x[s] + dinv[i]*x[i] )
// sv[i] = dinv[i] * ( sum dinv[s] + dinv[i] )
// ---------------------------------------------------------------------------
__global__ void gather_agg(const int* __restrict__ sorted_src,
                           const int* __restrict__ offs,
                           const float* __restrict__ x, const float* __restrict__ dinv,
                           float* __restrict__ y, float* __restrict__ sv) {
    int lane = threadIdx.x & 63;
    int node = blockIdx.x * 4 + (threadIdx.x >> 6);
    if (node >= NN) return;
    int e = offs[node], end = offs[node + 1];
    int c = lane * 2;
    float ax = 0.f, ay = 0.f, sacc = 0.f;
    for (; e + 1 < end; e += 2) {
        int s0 = sorted_src[e], s1 = sorted_src[e + 1];
        float f0 = dinv[s0], f1 = dinv[s1];
        float2 v0 = *(const float2*)&x[(size_t)s0 * 128 + c];
        float2 v1 = *(const float2*)&x[(size_t)s1 * 128 + c];
        ax += f0 * v0.x + f1 * v1.x;
        ay += f0 * v0.y + f1 * v1.y;
        sacc += f0 + f1;
    }
    if (e < end) {
        int s0 = sorted_src[e];
        float f0 = dinv[s0];
        float2 v0 = *(const float2*)&x[(size_t)s0 * 128 + c];
        ax += f0 * v0.x;
        ay += f0 * v0.y;
        sacc += f0;
    }
    float di = dinv[node];
    float2 xo = *(const float2*)&x[(size_t)node * 128 + c];
    float2 o;
    o.x = di * (ax + di * xo.x);
    o.y = di * (ay + di * xo.y);
    *(float2*)&y[(size_t)node * 128 + c] = o;
    if (lane == 0) sv[node] = di * (sacc + di);
}

// ---------------------------------------------------------------------------
// Gate GEMM: 64 rows x 128 cols per block, K=256 over virtual [y | A1].
// FUSED=false (r gate): out = H * sigmoid(a_r)            (A1 = H)
// FUSED=true  (z+h)   : out = z*H + (1-z)*tanh(a_h)       (A1z = H, A1h = HR)
// ---------------------------------------------------------------------------
template <bool FUSED>
__launch_bounds__(256, 2)
__global__ void gate_gemm(const float* __restrict__ Y,
                          const float* __restrict__ H,
                          const float* __restrict__ HR,
                          const float* __restrict__ B0, const float* __restrict__ B1,
                          const float* __restrict__ v0, const float* __restrict__ c0,
                          const float* __restrict__ v1, const float* __restrict__ c1,
                          const float* __restrict__ svec,
                          float* __restrict__ out) {
    __shared__ float As0[32][64];
    __shared__ float As1[FUSED ? 32 : 1][64];
    __shared__ float Bs0[32][128];
    __shared__ float Bs1[FUSED ? 32 : 1][128];

    const int tid = threadIdx.x;
    const int rowBase = blockIdx.x * 64;
    const int lar = tid >> 2, lak = (tid & 3) * 8;
    const int lbk = tid >> 3, lbc = (tid & 7) * 16;
    const int tr = (tid >> 4) * 4, tc = (tid & 15) * 8;

    float acc0[4][8] = {};
    float acc1[4][8] = {};

    const int grow = rowBase + lar;
    const bool inr = grow < NN;

    for (int kc = 0; kc < 256; kc += 32) {
        float4 av0 = {0, 0, 0, 0}, av1 = {0, 0, 0, 0};
        if (inr) {
            const float* p = ((kc < 128) ? Y : H) + (size_t)grow * 128 + (kc & 127) + lak;
            av0 = *(const float4*)p;
            av1 = *(const float4*)(p + 4);
        }
        As0[lak + 0][lar] = av0.x; As0[lak + 1][lar] = av0.y;
        As0[lak + 2][lar] = av0.z; As0[lak + 3][lar] = av0.w;
        As0[lak + 4][lar] = av1.x; As0[lak + 5][lar] = av1.y;
        As0[lak + 6][lar] = av1.z; As0[lak + 7][lar] = av1.w;
        if (FUSED) {
            float4 bv0 = av0, bv1 = av1;
            if (kc >= 128) {
                bv0 = make_float4(0, 0, 0, 0); bv1 = make_float4(0, 0, 0, 0);
                if (inr) {
                    const float* p = HR + (size_t)grow * 128 + (kc - 128) + lak;
                    bv0 = *(const float4*)p;
                    bv1 = *(const float4*)(p + 4);
                }
            }
            As1[lak + 0][lar] = bv0.x; As1[lak + 1][lar] = bv0.y;
            As1[lak + 2][lar] = bv0.z; As1[lak + 3][lar] = bv0.w;
            As1[lak + 4][lar] = bv1.x; As1[lak + 5][lar] = bv1.y;
            As1[lak + 6][lar] = bv1.z; As1[lak + 7][lar] = bv1.w;
        }
        {
            const float* p = B0 + (size_t)(kc + lbk) * 128 + lbc;
            *(float4*)&Bs0[lbk][lbc]      = *(const float4*)p;
            *(float4*)&Bs0[lbk][lbc + 4]  = *(const float4*)(p + 4);
            *(float4*)&Bs0[lbk][lbc + 8]  = *(const float4*)(p + 8);
            *(float4*)&Bs0[lbk][lbc + 12] = *(const float4*)(p + 12);
            if (FUSED) {
                const float* q = B1 + (size_t)(kc + lbk) * 128 + lbc;
                *(float4*)&Bs1[lbk][lbc]      = *(const float4*)q;
                *(float4*)&Bs1[lbk][lbc + 4]  = *(const float4*)(q + 4);
                *(float4*)&Bs1[lbk][lbc + 8]  = *(const float4*)(q + 8);
                *(float4*)&Bs1[lbk][lbc + 12] = *(const float4*)(q + 12);
            }
        }
        __syncthreads();

        #pragma unroll
        for (int kk = 0; kk < 32; kk++) {
            float4 a4 = *(const float4*)&As0[kk][tr];
            float a[4] = {a4.x, a4.y, a4.z, a4.w};
            float b0[8];
            *(float4*)&b0[0] = *(const float4*)&Bs0[kk][tc];
            *(float4*)&b0[4] = *(const float4*)&Bs0[kk][tc + 4];
            #pragma unroll
            for (int i = 0; i < 4; i++)
                #pragma unroll
                for (int j = 0; j < 8; j++) acc0[i][j] += a[i] * b0[j];
            if (FUSED) {
                float4 c4v = *(const float4*)&As1[kk][tr];
                float aa[4] = {c4v.x, c4v.y, c4v.z, c4v.w};
                float b1r[8];
                *(float4*)&b1r[0] = *(const float4*)&Bs1[kk][tc];
                *(float4*)&b1r[4] = *(const float4*)&Bs1[kk][tc + 4];
                #pragma unroll
                for (int i = 0; i < 4; i++)
                    #pragma unroll
                    for (int j = 0; j < 8; j++) acc1[i][j] += aa[i] * b1r[j];
            }
        }
        __syncthreads();
    }

    #pragma unroll
    for (int i = 0; i < 4; i++) {
        int row = rowBase + tr + i;
        if (row >= NN) break;
        float srow = svec[row];
        #pragma unroll
        for (int j = 0; j < 8; j++) {
            int col = tc + j;
            size_t o = (size_t)row * 128 + col;
            float a = acc0[i][j] + srow * v0[col] + c0[col];
            if (FUSED) {
                float z = 1.f / (1.f + expf(-a));
                float b = acc1[i][j] + srow * v1[col] + c1[col];
                float ht = tanhf(b);
                out[o] = z * H[o] + (1.f - z) * ht;
            } else {
                out[o] = H[o] / (1.f + expf(-a));
            }
        }
    }
}

// ---------------------------------------------------------------------------
__global__ void maxpool_partial(const float* __restrict__ H, float* __restrict__ part) {
    int c = threadIdx.x;  // 128
    float m = -1e30f;
    for (int r = blockIdx.x; r < NN; r += gridDim.x)
        m = fmaxf(m, H[(size_t)r * 128 + c]);
    part[blockIdx.x * 128 + c] = m;
}

__global__ void final_out(const float* __restrict__ part, const float* __restrict__ W2,
                          const float* __restrict__ b2, float* __restrict__ out) {
    __shared__ float hmax[128];
    int tid = threadIdx.x;  // 128
    float m = -1e30f;
    for (int b = 0; b < 256; b++) m = fmaxf(m, part[b * 128 + tid]);
    hmax[tid] = m;
    __syncthreads();
    if (tid < 10) {
        float sacc = b2[tid];
        for (int c = 0; c < 128; c++) sacc += hmax[c] * W2[c * 10 + tid];
        out[tid] = sacc;
    }
}

extern "C" void kernel_launch(void* const* d_in, const int* in_sizes, int n_in,
                              void* d_out, int out_size, void* d_ws, size_t ws_size,
                              hipStream_t stream) {
    const float* x[3]     = {(const float*)d_in[0], (const float*)d_in[2], (const float*)d_in[4]};
    const int*   edges[3] = {(const int*)d_in[1], (const int*)d_in[3], (const int*)d_in[5]};
    const float* W1 = (const float*)d_in[6];
    const float* b1 = (const float*)d_in[7];
    const float* convW[3] = {(const float*)d_in[8], (const float*)d_in[12], (const float*)d_in[16]};
    const float* convb[3] = {(const float*)d_in[9], (const float*)d_in[13], (const float*)d_in[17]};
    const float* linW[3]  = {(const float*)d_in[10], (const float*)d_in[14], (const float*)d_in[18]};
    const float* linb[3]  = {(const float*)d_in[11], (const float*)d_in[15], (const float*)d_in[19]};
    const float* W2 = (const float*)d_in[20];
    const float* b2 = (const float*)d_in[21];

    float* ws   = (float*)d_ws;
    float* B3   = ws;                  // 3*256*128 = 98304
    float* v3   = B3 + 98304;          // 384
    float* c3   = v3 + 384;            // 384
    float* M    = c3 + 384;            // 3*128*128 = 49152
    float* dinv = M + 49152;           // NN
    float* sv   = dinv + NN;           // NN
    float* part = sv + NN;             // 32768
    int*   deg  = (int*)(part + 32768);     // NN (also reused as cursor)
    int*   offs = deg + NN;                 // NN+1
    int*   partial = offs + NN + 4;         // 128
    int*   sorted_src = partial + 128;      // EE
    float* agg  = (float*)(sorted_src + EE);  // NN*128 (y)
    float* bufA = agg + (size_t)NN * 128;
    float* bufB = bufA + (size_t)NN * 128;
    // total ~ 162.5 MB

    prep1<<<192, 256, 0, stream>>>(convW[0], convW[1], convW[2],
                                   linW[0], linW[1], linW[2], M);
    prep2<<<384, 256, 0, stream>>>(W1, M, linW[0], linW[1], linW[2], B3);
    prep3<<<2, 256, 0, stream>>>(b1, M, convb[0], convb[1], convb[2],
                                 linW[0], linW[1], linW[2],
                                 linb[0], linb[1], linb[2], v3, c3);

    hipMemsetAsync(bufA, 0, (size_t)NN * 128 * sizeof(float), stream);  // H = 0

    float* P = bufA;  // H in
    float* Q = bufB;  // H out

    for (int t = 0; t < 3; t++) {
        const int* src = edges[t];
        const int* dst = edges[t] + EE;

        hipMemsetAsync(deg, 0, NN * sizeof(int), stream);
        hist_kernel<<<2048, 256, 0, stream>>>(dst, deg);
        dinv_kernel<<<(NN + 255) / 256, 256, 0, stream>>>(deg, dinv);
        scan_local<<<SCAN_NB, SCAN_B, 0, stream>>>(deg, offs, partial);
        scan_carry<<<1, 64, 0, stream>>>(partial, offs);
        scan_add<<<SCAN_NB, SCAN_B, 0, stream>>>(offs, partial);
        hipMemsetAsync(deg, 0, NN * sizeof(int), stream);  // deg -> cursor
        bucket_fill<<<2048, 256, 0, stream>>>(src, dst, offs, deg, sorted_src);
        gather_agg<<<25000, 256, 0, stream>>>(sorted_src, offs, x[t], dinv, agg, sv);

        // r gate: Q = H * sigmoid(a_r)
        gate_gemm<false><<<1563, 256, 0, stream>>>(
            agg, P, nullptr, B3 + 1 * 32768, nullptr,
            v3 + 128, c3 + 128, nullptr, nullptr, sv, Q);
        // z + h gates: Q = z*H + (1-z)*tanh(a_h)   (in place over Hr)
        gate_gemm<true><<<1563, 256, 0, stream>>>(
            agg, P, Q, B3 + 0 * 32768, B3 + 2 * 32768,
            v3 + 0, c3 + 0, v3 + 256, c3 + 256, sv, Q);

        float* tmp = P; P = Q; Q = tmp;  // H <- new H
    }

    maxpool_partial<<<256, 128, 0, stream>>>(P, part);
    final_out<<<1, 128, 0, stream>>>(part, W2, b2, (float*)d_out);
}

// Round 4
// 2096.526 us; speedup vs baseline: 2.7939x; 1.0360x over previous
//
#include <hip/hip_runtime.h>
#include <hip/hip_bf16.h>
#include <math.h>

#define NN 100000
#define EE 1600000
#define SCAN_B 1024
#define SCAN_NB 98   // ceil(100000/1024)

typedef __attribute__((ext_vector_type(8))) short bfrag;   // 8 bf16 = 4 VGPR
typedef __attribute__((ext_vector_type(4))) float facc;    // 4 f32 acc

// ---------------------------------------------------------------------------
// Weight folding:  M_g = convW_g @ linW_g[0:128,:]        (128x128)
//                  B3_g = [ W1 @ M_g ; linW_g[128:256,:] ] (256x128)
//                  v_g = b1 @ M_g ; c_g = convb_g @ linW_g[0:128,:] + linb_g
// Gate pre-activation: a_g = [y | H] @ B3_g + s*v_g + c_g
// y = Norm(x), s = Norm(1), Norm = D^-1/2 (A+I) D^-1/2
// ---------------------------------------------------------------------------
__global__ void prep1(const float* __restrict__ Wcz, const float* __restrict__ Wcr,
                      const float* __restrict__ Wch,
                      const float* __restrict__ Wlz, const float* __restrict__ Wlr,
                      const float* __restrict__ Wlh,
                      float* __restrict__ M) {
    int idx = blockIdx.x * 256 + threadIdx.x;   // 3*16384
    int g = idx >> 14, r = idx & 16383;
    int i = r >> 7, j = r & 127;
    const float* Wc = g == 0 ? Wcz : (g == 1 ? Wcr : Wch);
    const float* Wl = g == 0 ? Wlz : (g == 1 ? Wlr : Wlh);
    float s = 0.f;
    for (int m = 0; m < 128; m++) s += Wc[i * 128 + m] * Wl[m * 128 + j];
    M[idx] = s;
}

__global__ void prep2(const float* __restrict__ W1, const float* __restrict__ M,
                      const float* __restrict__ Wlz, const float* __restrict__ Wlr,
                      const float* __restrict__ Wlh,
                      float* __restrict__ B) {
    int idx = blockIdx.x * 256 + threadIdx.x;  // 3*256*128
    int g = idx >> 15, r = idx & 32767;
    int k = r >> 7, j = r & 127;
    float o;
    if (k < 128) {
        const float* Mg = M + g * 16384;
        float sacc = 0.f;
        for (int m = 0; m < 128; m++) sacc += W1[k * 128 + m] * Mg[m * 128 + j];
        o = sacc;
    } else {
        const float* Wl = g == 0 ? Wlz : (g == 1 ? Wlr : Wlh);
        o = Wl[k * 128 + j];
    }
    B[idx] = o;
}

__global__ void prep3(const float* __restrict__ b1, const float* __restrict__ M,
                      const float* __restrict__ bcz, const float* __restrict__ bcr,
                      const float* __restrict__ bch,
                      const float* __restrict__ Wlz, const float* __restrict__ Wlr,
                      const float* __restrict__ Wlh,
                      const float* __restrict__ blz, const float* __restrict__ blr,
                      const float* __restrict__ blh,
                      float* __restrict__ v, float* __restrict__ c) {
    int idx = blockIdx.x * 256 + threadIdx.x;
    if (idx >= 384) return;
    int g = idx >> 7, j = idx & 127;
    const float* Mg = M + g * 16384;
    float sv = 0.f;
    for (int m = 0; m < 128; m++) sv += b1[m] * Mg[m * 128 + j];
    v[idx] = sv;
    const float* bc = g == 0 ? bcz : (g == 1 ? bcr : bch);
    const float* Wl = g == 0 ? Wlz : (g == 1 ? Wlr : Wlh);
    const float* bl = g == 0 ? blz : (g == 1 ? blr : blh);
    float sc = bl[j];
    for (int m = 0; m < 128; m++) sc += bc[m] * Wl[m * 128 + j];
    c[idx] = sc;
}

// Frag-packed bf16 B for MFMA. Frag f=(gcf*8+kf): elem (lane,i) =
// B3[g][kf*32+(lane>>4)*8+i][(gcf&7)*16+(lane&15)], g = gcf>>3 (zr) or 2 (h).
__global__ void pack_zr(const float* __restrict__ B3, __hip_bfloat16* __restrict__ out) {
    int idx = blockIdx.x * 256 + threadIdx.x;  // 65536
    if (idx >= 65536) return;
    int i = idx & 7, lane = (idx >> 3) & 63, kf = (idx >> 9) & 7, gcf = idx >> 12;
    int g = gcf >> 3;
    int j = (gcf & 7) * 16 + (lane & 15);
    int k = kf * 32 + (lane >> 4) * 8 + i;
    out[idx] = __float2bfloat16(B3[g * 32768 + k * 128 + j]);
}

__global__ void pack_h(const float* __restrict__ B3, __hip_bfloat16* __restrict__ out) {
    int idx = blockIdx.x * 256 + threadIdx.x;  // 32768
    if (idx >= 32768) return;
    int i = idx & 7, lane = (idx >> 3) & 63, kf = (idx >> 9) & 7, cf = idx >> 12;
    int j = cf * 16 + (lane & 15);
    int k = kf * 32 + (lane >> 4) * 8 + i;
    out[idx] = __float2bfloat16(B3[2 * 32768 + k * 128 + j]);
}

// ---------------------------------------------------------------------------
// CSR build: histogram -> exclusive scan -> bucket fill
// ---------------------------------------------------------------------------
__global__ void hist_kernel(const int* __restrict__ dst, int* __restrict__ deg) {
    int i = blockIdx.x * blockDim.x + threadIdx.x;
    int stride = gridDim.x * blockDim.x;
    for (; i < EE; i += stride) atomicAdd(&deg[dst[i]], 1);
}

__global__ void dinv_kernel(const int* __restrict__ deg, float* __restrict__ dinv) {
    int i = blockIdx.x * blockDim.x + threadIdx.x;
    if (i < NN) dinv[i] = rsqrtf((float)deg[i] + 1.0f);  // +1 = self loop
}

__global__ void scan_local(const int* __restrict__ deg, int* __restrict__ offs,
                           int* __restrict__ partial) {
    __shared__ int sm[SCAN_B];
    int t = threadIdx.x;
    int i = blockIdx.x * SCAN_B + t;
    int v = (i < NN) ? deg[i] : 0;
    sm[t] = v;
    __syncthreads();
    #pragma unroll
    for (int off = 1; off < SCAN_B; off <<= 1) {
        int x = (t >= off) ? sm[t - off] : 0;
        __syncthreads();
        sm[t] += x;
        __syncthreads();
    }
    if (i < NN) offs[i] = sm[t] - v;
    if (t == SCAN_B - 1) partial[blockIdx.x] = sm[t];
}

__global__ void scan_carry(int* __restrict__ partial, int* __restrict__ offs) {
    if (threadIdx.x == 0) {
        int carry = 0;
        for (int b = 0; b < SCAN_NB; b++) {
            int p = partial[b];
            partial[b] = carry;
            carry += p;
        }
        offs[NN] = carry;  // == EE
    }
}

__global__ void scan_add(int* __restrict__ offs, const int* __restrict__ partial) {
    int i = blockIdx.x * SCAN_B + threadIdx.x;
    if (i < NN) offs[i] += partial[blockIdx.x];
}

__global__ void bucket_fill(const int* __restrict__ src, const int* __restrict__ dst,
                            const int* __restrict__ offs, int* __restrict__ cursor,
                            int* __restrict__ sorted_src) {
    int i = blockIdx.x * blockDim.x + threadIdx.x;
    int stride = gridDim.x * blockDim.x;
    for (; i < EE; i += stride) {
        int d = dst[i];
        int pos = offs[d] + atomicAdd(&cursor[d], 1);
        sorted_src[pos] = src[i];
    }
}

// ---------------------------------------------------------------------------
// Gather aggregation: one wave per dst node, y written in bf16.
// ---------------------------------------------------------------------------
__global__ void gather_agg(const int* __restrict__ sorted_src,
                           const int* __restrict__ offs,
                           const float* __restrict__ x, const float* __restrict__ dinv,
                           __hip_bfloat16* __restrict__ y, float* __restrict__ sv) {
    int lane = threadIdx.x & 63;
    int node = blockIdx.x * 4 + (threadIdx.x >> 6);
    if (node >= NN) return;
    int e = offs[node], end = offs[node + 1];
    int c = lane * 2;
    float ax = 0.f, ay = 0.f, sacc = 0.f;
    for (; e + 1 < end; e += 2) {
        int s0 = sorted_src[e], s1 = sorted_src[e + 1];
        float f0 = dinv[s0], f1 = dinv[s1];
        float2 v0 = *(const float2*)&x[(size_t)s0 * 128 + c];
        float2 v1 = *(const float2*)&x[(size_t)s1 * 128 + c];
        ax += f0 * v0.x + f1 * v1.x;
        ay += f0 * v0.y + f1 * v1.y;
        sacc += f0 + f1;
    }
    if (e < end) {
        int s0 = sorted_src[e];
        float f0 = dinv[s0];
        float2 v0 = *(const float2*)&x[(size_t)s0 * 128 + c];
        ax += f0 * v0.x;
        ay += f0 * v0.y;
        sacc += f0;
    }
    float di = dinv[node];
    float2 xo = *(const float2*)&x[(size_t)node * 128 + c];
    __hip_bfloat162 hv;
    hv.x = __float2bfloat16(di * (ax + di * xo.x));
    hv.y = __float2bfloat16(di * (ay + di * xo.y));
    *(__hip_bfloat162*)&y[(size_t)node * 128 + c] = hv;
    if (lane == 0) sv[node] = di * (sacc + di);
}

// ---------------------------------------------------------------------------
// MFMA gate GEMMs. Wave = 64 rows x 128 cols, K=256 over [y|H] (zr) / [y|Hr] (h).
// A-frag: lane l -> row=l&15, k=(l>>4)*8+i (one b128 from bf16 row-major).
// B-frag: frag-packed, one coalesced b128 per lane.
// C/D: col=lane&15, row=(lane>>4)*4+reg (verified gfx950 layout).
// ---------------------------------------------------------------------------
__launch_bounds__(256)
__global__ void gates_zr(const __hip_bfloat16* __restrict__ ybf,
                         const __hip_bfloat16* __restrict__ Hbf,
                         const float* __restrict__ H,
                         const __hip_bfloat16* __restrict__ Bzr,
                         const float* __restrict__ v3, const float* __restrict__ c3,
                         const float* __restrict__ svec,
                         __hip_bfloat16* __restrict__ Zbf,
                         __hip_bfloat16* __restrict__ Hrbf) {
    const int lane = threadIdx.x & 63;
    const int wid = threadIdx.x >> 6;
    const int gate = blockIdx.y;
    const int rowBase = blockIdx.x * 256 + wid * 64;
    const int l15 = lane & 15, lk = lane >> 4;

    facc zero = {0.f, 0.f, 0.f, 0.f};
    facc acc[4][8];
    #pragma unroll
    for (int i = 0; i < 4; i++)
        #pragma unroll
        for (int j = 0; j < 8; j++) acc[i][j] = zero;

    for (int kf = 0; kf < 8; kf++) {
        const __hip_bfloat16* Asrc = (kf < 4) ? ybf : Hbf;
        const int koff = (kf & 3) * 32 + lk * 8;
        bfrag a[4];
        #pragma unroll
        for (int rf = 0; rf < 4; rf++) {
            int row = rowBase + rf * 16 + l15;
            if (row < NN) a[rf] = *(const bfrag*)&Asrc[(size_t)row * 128 + koff];
            else { bfrag zz = {0,0,0,0,0,0,0,0}; a[rf] = zz; }
        }
        #pragma unroll
        for (int cf = 0; cf < 8; cf++) {
            bfrag b = *(const bfrag*)&Bzr[(size_t)(((gate * 8 + cf) * 8 + kf) * 64 + lane) * 8];
            #pragma unroll
            for (int rf = 0; rf < 4; rf++)
                acc[rf][cf] = __builtin_amdgcn_mfma_f32_16x16x32_bf16(a[rf], b, acc[rf][cf], 0, 0, 0);
        }
    }

    const int cbase = gate * 128;
    #pragma unroll
    for (int rf = 0; rf < 4; rf++) {
        #pragma unroll
        for (int r = 0; r < 4; r++) {
            int row = rowBase + rf * 16 + lk * 4 + r;
            if (row >= NN) continue;
            float srow = svec[row];
            #pragma unroll
            for (int cf = 0; cf < 8; cf++) {
                int col = cf * 16 + l15;
                float aval = acc[rf][cf][r] + srow * v3[cbase + col] + c3[cbase + col];
                size_t o = (size_t)row * 128 + col;
                if (gate == 0) {
                    Zbf[o] = __float2bfloat16(1.f / (1.f + expf(-aval)));
                } else {
                    Hrbf[o] = __float2bfloat16(H[o] / (1.f + expf(-aval)));
                }
            }
        }
    }
}

__launch_bounds__(256)
__global__ void gate_h(const __hip_bfloat16* __restrict__ ybf,
                       const __hip_bfloat16* __restrict__ Hrbf,
                       const __hip_bfloat16* __restrict__ Bh,
                       const float* __restrict__ v3, const float* __restrict__ c3,
                       const float* __restrict__ svec,
                       const __hip_bfloat16* __restrict__ Zbf,
                       float* __restrict__ H,
                       __hip_bfloat16* __restrict__ Hbf) {
    const int lane = threadIdx.x & 63;
    const int wid = threadIdx.x >> 6;
    const int rowBase = blockIdx.x * 256 + wid * 64;
    const int l15 = lane & 15, lk = lane >> 4;

    facc zero = {0.f, 0.f, 0.f, 0.f};
    facc acc[4][8];
    #pragma unroll
    for (int i = 0; i < 4; i++)
        #pragma unroll
        for (int j = 0; j < 8; j++) acc[i][j] = zero;

    for (int kf = 0; kf < 8; kf++) {
        const __hip_bfloat16* Asrc = (kf < 4) ? ybf : Hrbf;
        const int koff = (kf & 3) * 32 + lk * 8;
        bfrag a[4];
        #pragma unroll
        for (int rf = 0; rf < 4; rf++) {
            int row = rowBase + rf * 16 + l15;
            if (row < NN) a[rf] = *(const bfrag*)&Asrc[(size_t)row * 128 + koff];
            else { bfrag zz = {0,0,0,0,0,0,0,0}; a[rf] = zz; }
        }
        #pragma unroll
        for (int cf = 0; cf < 8; cf++) {
            bfrag b = *(const bfrag*)&Bh[(size_t)((cf * 8 + kf) * 64 + lane) * 8];
            #pragma unroll
            for (int rf = 0; rf < 4; rf++)
                acc[rf][cf] = __builtin_amdgcn_mfma_f32_16x16x32_bf16(a[rf], b, acc[rf][cf], 0, 0, 0);
        }
    }

    #pragma unroll
    for (int rf = 0; rf < 4; rf++) {
        #pragma unroll
        for (int r = 0; r < 4; r++) {
            int row = rowBase + rf * 16 + lk * 4 + r;
            if (row >= NN) continue;
            float srow = svec[row];
            #pragma unroll
            for (int cf = 0; cf < 8; cf++) {
                int col = cf * 16 + l15;
                float aval = acc[rf][cf][r] + srow * v3[256 + col] + c3[256 + col];
                size_t o = (size_t)row * 128 + col;
                float ht = tanhf(aval);
                float z = __bfloat162float(Zbf[o]);
                float hn = z * H[o] + (1.f - z) * ht;
                H[o] = hn;
                Hbf[o] = __float2bfloat16(hn);
            }
        }
    }
}

// ---------------------------------------------------------------------------
__global__ void maxpool_partial(const float* __restrict__ H, float* __restrict__ part) {
    int c = threadIdx.x;  // 128
    float m = -1e30f;
    for (int r = blockIdx.x; r < NN; r += gridDim.x)
        m = fmaxf(m, H[(size_t)r * 128 + c]);
    part[blockIdx.x * 128 + c] = m;
}

__global__ void final_out(const float* __restrict__ part, const float* __restrict__ W2,
                          const float* __restrict__ b2, float* __restrict__ out) {
    __shared__ float hmax[128];
    int tid = threadIdx.x;  // 128
    float m = -1e30f;
    for (int b = 0; b < 256; b++) m = fmaxf(m, part[b * 128 + tid]);
    hmax[tid] = m;
    __syncthreads();
    if (tid < 10) {
        float sacc = b2[tid];
        for (int c = 0; c < 128; c++) sacc += hmax[c] * W2[c * 10 + tid];
        out[tid] = sacc;
    }
}

extern "C" void kernel_launch(void* const* d_in, const int* in_sizes, int n_in,
                              void* d_out, int out_size, void* d_ws, size_t ws_size,
                              hipStream_t stream) {
    const float* x[3]     = {(const float*)d_in[0], (const float*)d_in[2], (const float*)d_in[4]};
    const int*   edges[3] = {(const int*)d_in[1], (const int*)d_in[3], (const int*)d_in[5]};
    const float* W1 = (const float*)d_in[6];
    const float* b1 = (const float*)d_in[7];
    const float* convW[3] = {(const float*)d_in[8], (const float*)d_in[12], (const float*)d_in[16]};
    const float* convb[3] = {(const float*)d_in[9], (const float*)d_in[13], (const float*)d_in[17]};
    const float* linW[3]  = {(const float*)d_in[10], (const float*)d_in[14], (const float*)d_in[18]};
    const float* linb[3]  = {(const float*)d_in[11], (const float*)d_in[15], (const float*)d_in[19]};
    const float* W2 = (const float*)d_in[20];
    const float* b2 = (const float*)d_in[21];

    float* ws   = (float*)d_ws;
    float* B3   = ws;                  // 98304
    float* v3   = B3 + 98304;          // 384
    float* c3   = v3 + 384;            // 384
    float* M    = c3 + 384;            // 49152
    float* dinv = M + 49152;           // NN
    float* svb  = dinv + NN;           // NN
    float* part = svb + NN;            // 32768
    int*   deg  = (int*)(part + 32768);     // NN (reused as cursor)
    int*   offs = deg + NN;                 // NN+4
    int*   partial = offs + NN + 4;         // 128
    int*   sorted_src = partial + 128;      // EE
    __hip_bfloat16* Bzr  = (__hip_bfloat16*)(sorted_src + EE);   // 65536
    __hip_bfloat16* Bh   = Bzr + 65536;                          // 32768
    __hip_bfloat16* ybf  = Bh + 32768;                           // NN*128
    __hip_bfloat16* Hbf  = ybf + (size_t)NN * 128;               // NN*128
    __hip_bfloat16* Hrbf = Hbf + (size_t)NN * 128;               // NN*128
    __hip_bfloat16* Zbf  = Hrbf + (size_t)NN * 128;              // NN*128
    float* H = (float*)(Zbf + (size_t)NN * 128);                 // NN*128 f32
    // total ~162.6 MB

    prep1<<<192, 256, 0, stream>>>(convW[0], convW[1], convW[2],
                                   linW[0], linW[1], linW[2], M);
    prep2<<<384, 256, 0, stream>>>(W1, M, linW[0], linW[1], linW[2], B3);
    prep3<<<2, 256, 0, stream>>>(b1, M, convb[0], convb[1], convb[2],
                                 linW[0], linW[1], linW[2],
                                 linb[0], linb[1], linb[2], v3, c3);
    pack_zr<<<256, 256, 0, stream>>>(B3, Bzr);
    pack_h<<<128, 256, 0, stream>>>(B3, Bh);

    hipMemsetAsync(H, 0, (size_t)NN * 128 * sizeof(float), stream);
    hipMemsetAsync(Hbf, 0, (size_t)NN * 128 * sizeof(__hip_bfloat16), stream);

    for (int t = 0; t < 3; t++) {
        const int* src = edges[t];
        const int* dst = edges[t] + EE;

        hipMemsetAsync(deg, 0, NN * sizeof(int), stream);
        hist_kernel<<<2048, 256, 0, stream>>>(dst, deg);
        dinv_kernel<<<(NN + 255) / 256, 256, 0, stream>>>(deg, dinv);
        scan_local<<<SCAN_NB, SCAN_B, 0, stream>>>(deg, offs, partial);
        scan_carry<<<1, 64, 0, stream>>>(partial, offs);
        scan_add<<<SCAN_NB, SCAN_B, 0, stream>>>(offs, partial);
        hipMemsetAsync(deg, 0, NN * sizeof(int), stream);  // deg -> cursor
        bucket_fill<<<2048, 256, 0, stream>>>(src, dst, offs, deg, sorted_src);
        gather_agg<<<25000, 256, 0, stream>>>(sorted_src, offs, x[t], dinv, ybf, svb);

        gates_zr<<<dim3(391, 2), 256, 0, stream>>>(ybf, Hbf, H, Bzr, v3, c3, svb,
                                                   Zbf, Hrbf);
        gate_h<<<391, 256, 0, stream>>>(ybf, Hrbf, Bh, v3, c3, svb, Zbf, H, Hbf);
    }

    maxpool_partial<<<256, 128, 0, stream>>>(H, part);
    final_out<<<1, 128, 0, stream>>>(part, W2, b2, (float*)d_out);
}

// Round 5
// 1664.874 us; speedup vs baseline: 3.5183x; 1.2593x over previous
//
#include <hip/hip_runtime.h>
#include <hip/hip_bf16.h>
#include <math.h>

#define NN 100000
#define EE 1600000
#define SCAN_B 1024
#define SCAN_NB 98   // ceil(100000/1024)
#define NTILES 3125  // NN / 32 exactly

typedef __attribute__((ext_vector_type(8))) short bfrag;   // 8 bf16 = 4 VGPR
typedef __attribute__((ext_vector_type(4))) float facc;    // 4 f32 acc

// ---------------------------------------------------------------------------
// Weight folding:  M_g = convW_g @ linW_g[0:128,:]        (128x128)
//                  B3_g = [ W1 @ M_g ; linW_g[128:256,:] ] (256x128)
//                  v_g = b1 @ M_g ; c_g = convb_g @ linW_g[0:128,:] + linb_g
// Gate pre-activation: a_g = [y | H] @ B3_g + s*v_g + c_g
// y = Norm(x), s = Norm(1), Norm = D^-1/2 (A+I) D^-1/2
// ---------------------------------------------------------------------------
__global__ void prep1(const float* __restrict__ Wcz, const float* __restrict__ Wcr,
                      const float* __restrict__ Wch,
                      const float* __restrict__ Wlz, const float* __restrict__ Wlr,
                      const float* __restrict__ Wlh,
                      float* __restrict__ M) {
    int idx = blockIdx.x * 256 + threadIdx.x;   // 3*16384
    int g = idx >> 14, r = idx & 16383;
    int i = r >> 7, j = r & 127;
    const float* Wc = g == 0 ? Wcz : (g == 1 ? Wcr : Wch);
    const float* Wl = g == 0 ? Wlz : (g == 1 ? Wlr : Wlh);
    float s = 0.f;
    for (int m = 0; m < 128; m++) s += Wc[i * 128 + m] * Wl[m * 128 + j];
    M[idx] = s;
}

__global__ void prep2(const float* __restrict__ W1, const float* __restrict__ M,
                      const float* __restrict__ Wlz, const float* __restrict__ Wlr,
                      const float* __restrict__ Wlh,
                      float* __restrict__ B) {
    int idx = blockIdx.x * 256 + threadIdx.x;  // 3*256*128
    int g = idx >> 15, r = idx & 32767;
    int k = r >> 7, j = r & 127;
    float o;
    if (k < 128) {
        const float* Mg = M + g * 16384;
        float sacc = 0.f;
        for (int m = 0; m < 128; m++) sacc += W1[k * 128 + m] * Mg[m * 128 + j];
        o = sacc;
    } else {
        const float* Wl = g == 0 ? Wlz : (g == 1 ? Wlr : Wlh);
        o = Wl[k * 128 + j];
    }
    B[idx] = o;
}

__global__ void prep3(const float* __restrict__ b1, const float* __restrict__ M,
                      const float* __restrict__ bcz, const float* __restrict__ bcr,
                      const float* __restrict__ bch,
                      const float* __restrict__ Wlz, const float* __restrict__ Wlr,
                      const float* __restrict__ Wlh,
                      const float* __restrict__ blz, const float* __restrict__ blr,
                      const float* __restrict__ blh,
                      float* __restrict__ v, float* __restrict__ c) {
    int idx = blockIdx.x * 256 + threadIdx.x;
    if (idx >= 384) return;
    int g = idx >> 7, j = idx & 127;
    const float* Mg = M + g * 16384;
    float sv = 0.f;
    for (int m = 0; m < 128; m++) sv += b1[m] * Mg[m * 128 + j];
    v[idx] = sv;
    const float* bc = g == 0 ? bcz : (g == 1 ? bcr : bch);
    const float* Wl = g == 0 ? Wlz : (g == 1 ? Wlr : Wlh);
    const float* bl = g == 0 ? blz : (g == 1 ? blr : blh);
    float sc = bl[j];
    for (int m = 0; m < 128; m++) sc += bc[m] * Wl[m * 128 + j];
    c[idx] = sc;
}

// Frag-packed bf16 B for MFMA. Frag f=(gcf*8+kf): elem (lane,i) =
// B3[g][kf*32+(lane>>4)*8+i][(gcf&7)*16+(lane&15)], g = gcf>>3 (zr) or 2 (h).
__global__ void pack_zr(const float* __restrict__ B3, __hip_bfloat16* __restrict__ out) {
    int idx = blockIdx.x * 256 + threadIdx.x;  // 65536
    if (idx >= 65536) return;
    int i = idx & 7, lane = (idx >> 3) & 63, kf = (idx >> 9) & 7, gcf = idx >> 12;
    int g = gcf >> 3;
    int j = (gcf & 7) * 16 + (lane & 15);
    int k = kf * 32 + (lane >> 4) * 8 + i;
    out[idx] = __float2bfloat16(B3[g * 32768 + k * 128 + j]);
}

__global__ void pack_h(const float* __restrict__ B3, __hip_bfloat16* __restrict__ out) {
    int idx = blockIdx.x * 256 + threadIdx.x;  // 32768
    if (idx >= 32768) return;
    int i = idx & 7, lane = (idx >> 3) & 63, kf = (idx >> 9) & 7, cf = idx >> 12;
    int j = cf * 16 + (lane & 15);
    int k = kf * 32 + (lane >> 4) * 8 + i;
    out[idx] = __float2bfloat16(B3[2 * 32768 + k * 128 + j]);
}

// ---------------------------------------------------------------------------
// CSR build: histogram -> exclusive scan -> bucket fill
// ---------------------------------------------------------------------------
__global__ void hist_kernel(const int* __restrict__ dst, int* __restrict__ deg) {
    int i = blockIdx.x * blockDim.x + threadIdx.x;
    int stride = gridDim.x * blockDim.x;
    for (; i < EE; i += stride) atomicAdd(&deg[dst[i]], 1);
}

__global__ void dinv_kernel(const int* __restrict__ deg, float* __restrict__ dinv) {
    int i = blockIdx.x * blockDim.x + threadIdx.x;
    if (i < NN) dinv[i] = rsqrtf((float)deg[i] + 1.0f);  // +1 = self loop
}

__global__ void scan_local(const int* __restrict__ deg, int* __restrict__ offs,
                           int* __restrict__ partial) {
    __shared__ int sm[SCAN_B];
    int t = threadIdx.x;
    int i = blockIdx.x * SCAN_B + t;
    int v = (i < NN) ? deg[i] : 0;
    sm[t] = v;
    __syncthreads();
    #pragma unroll
    for (int off = 1; off < SCAN_B; off <<= 1) {
        int x = (t >= off) ? sm[t - off] : 0;
        __syncthreads();
        sm[t] += x;
        __syncthreads();
    }
    if (i < NN) offs[i] = sm[t] - v;
    if (t == SCAN_B - 1) partial[blockIdx.x] = sm[t];
}

__global__ void scan_carry(int* __restrict__ partial, int* __restrict__ offs) {
    if (threadIdx.x == 0) {
        int carry = 0;
        for (int b = 0; b < SCAN_NB; b++) {
            int p = partial[b];
            partial[b] = carry;
            carry += p;
        }
        offs[NN] = carry;  // == EE
    }
}

__global__ void scan_add(int* __restrict__ offs, const int* __restrict__ partial) {
    int i = blockIdx.x * SCAN_B + threadIdx.x;
    if (i < NN) offs[i] += partial[blockIdx.x];
}

__global__ void bucket_fill(const int* __restrict__ src, const int* __restrict__ dst,
                            const int* __restrict__ offs, int* __restrict__ cursor,
                            int* __restrict__ sorted_src) {
    int i = blockIdx.x * blockDim.x + threadIdx.x;
    int stride = gridDim.x * blockDim.x;
    for (; i < EE; i += stride) {
        int d = dst[i];
        int pos = offs[d] + atomicAdd(&cursor[d], 1);
        sorted_src[pos] = src[i];
    }
}

// ---------------------------------------------------------------------------
// Gather aggregation: one wave per dst node, y written in bf16.
// ---------------------------------------------------------------------------
__global__ void gather_agg(const int* __restrict__ sorted_src,
                           const int* __restrict__ offs,
                           const float* __restrict__ x, const float* __restrict__ dinv,
                           __hip_bfloat16* __restrict__ y, float* __restrict__ sv) {
    int lane = threadIdx.x & 63;
    int node = blockIdx.x * 4 + (threadIdx.x >> 6);
    if (node >= NN) return;
    int e = offs[node], end = offs[node + 1];
    int c = lane * 2;
    float ax = 0.f, ay = 0.f, sacc = 0.f;
    for (; e + 1 < end; e += 2) {
        int s0 = sorted_src[e], s1 = sorted_src[e + 1];
        float f0 = dinv[s0], f1 = dinv[s1];
        float2 v0 = *(const float2*)&x[(size_t)s0 * 128 + c];
        float2 v1 = *(const float2*)&x[(size_t)s1 * 128 + c];
        ax += f0 * v0.x + f1 * v1.x;
        ay += f0 * v0.y + f1 * v1.y;
        sacc += f0 + f1;
    }
    if (e < end) {
        int s0 = sorted_src[e];
        float f0 = dinv[s0];
        float2 v0 = *(const float2*)&x[(size_t)s0 * 128 + c];
        ax += f0 * v0.x;
        ay += f0 * v0.y;
        sacc += f0;
    }
    float di = dinv[node];
    float2 xo = *(const float2*)&x[(size_t)node * 128 + c];
    __hip_bfloat162 hv;
    hv.x = __float2bfloat16(di * (ax + di * xo.x));
    hv.y = __float2bfloat16(di * (ay + di * xo.y));
    *(__hip_bfloat162*)&y[(size_t)node * 128 + c] = hv;
    if (lane == 0) sv[node] = di * (sacc + di);
}

// ---------------------------------------------------------------------------
// MFMA gate GEMMs, B-resident-in-registers + grid-stride over 32-row tiles.
// Wave combo = (gate, col-half): holds B-frags for its 64 cols (8kf x 4cf =
// 128 VGPR), loops tiles: 16 indep A-loads -> 64 MFMAs -> epilogue.
// A-frag: lane l -> row=l&15, k=(l>>4)*8+i. C/D: col=lane&15, row=(lane>>4)*4+r.
// ---------------------------------------------------------------------------
__launch_bounds__(256)
__global__ void gates_zr(const __hip_bfloat16* __restrict__ ybf,
                         const __hip_bfloat16* __restrict__ Hbf,
                         const float* __restrict__ H,
                         const __hip_bfloat16* __restrict__ Bzr,
                         const float* __restrict__ v3, const float* __restrict__ c3,
                         const float* __restrict__ svec,
                         __hip_bfloat16* __restrict__ Zbf,
                         __hip_bfloat16* __restrict__ Hrbf) {
    const int lane = threadIdx.x & 63;
    const int wid = threadIdx.x >> 6;
    const int gate = wid >> 1;          // 0=z, 1=r
    const int half = wid & 1;           // col half
    const int widx = blockIdx.x;        // wave index within combo
    const int nw = gridDim.x;           // waves per combo
    const int l15 = lane & 15, lk = lane >> 4;

    // B-frags resident: cols half*64 + cfi*16, cfi=0..3
    bfrag B[8][4];
    #pragma unroll
    for (int kf = 0; kf < 8; kf++)
        #pragma unroll
        for (int cfi = 0; cfi < 4; cfi++)
            B[kf][cfi] = *(const bfrag*)&Bzr[
                (size_t)(((gate * 8 + half * 4 + cfi) * 8 + kf) * 64 + lane) * 8];

    // per-lane bias terms (col fixed per lane per cfi)
    float vv[4], cc[4];
    #pragma unroll
    for (int cfi = 0; cfi < 4; cfi++) {
        int col = half * 64 + cfi * 16 + l15;
        vv[cfi] = v3[gate * 128 + col];
        cc[cfi] = c3[gate * 128 + col];
    }

    for (int tile = widx; tile < NTILES; tile += nw) {
        const int rowBase = tile * 32;

        bfrag a[8][2];
        #pragma unroll
        for (int kf = 0; kf < 8; kf++) {
            const __hip_bfloat16* Asrc = (kf < 4) ? ybf : Hbf;
            const int koff = (kf & 3) * 32 + lk * 8;
            #pragma unroll
            for (int rf = 0; rf < 2; rf++)
                a[kf][rf] = *(const bfrag*)&Asrc[(size_t)(rowBase + rf * 16 + l15) * 128 + koff];
        }

        facc acc[2][4];
        #pragma unroll
        for (int rf = 0; rf < 2; rf++)
            #pragma unroll
            for (int cfi = 0; cfi < 4; cfi++) acc[rf][cfi] = (facc){0.f, 0.f, 0.f, 0.f};

        #pragma unroll
        for (int kf = 0; kf < 8; kf++)
            #pragma unroll
            for (int cfi = 0; cfi < 4; cfi++)
                #pragma unroll
                for (int rf = 0; rf < 2; rf++)
                    acc[rf][cfi] = __builtin_amdgcn_mfma_f32_16x16x32_bf16(
                        a[kf][rf], B[kf][cfi], acc[rf][cfi], 0, 0, 0);

        #pragma unroll
        for (int rf = 0; rf < 2; rf++) {
            #pragma unroll
            for (int r = 0; r < 4; r++) {
                const int row = rowBase + rf * 16 + lk * 4 + r;
                const float srow = svec[row];
                #pragma unroll
                for (int cfi = 0; cfi < 4; cfi++) {
                    const int col = half * 64 + cfi * 16 + l15;
                    const float aval = acc[rf][cfi][r] + srow * vv[cfi] + cc[cfi];
                    const size_t o = (size_t)row * 128 + col;
                    const float sg = 1.f / (1.f + expf(-aval));
                    if (gate == 0) Zbf[o] = __float2bfloat16(sg);
                    else           Hrbf[o] = __float2bfloat16(H[o] * sg);
                }
            }
        }
    }
}

__launch_bounds__(256)
__global__ void gate_h(const __hip_bfloat16* __restrict__ ybf,
                       const __hip_bfloat16* __restrict__ Hrbf,
                       const __hip_bfloat16* __restrict__ Bh,
                       const float* __restrict__ v3, const float* __restrict__ c3,
                       const float* __restrict__ svec,
                       const __hip_bfloat16* __restrict__ Zbf,
                       float* __restrict__ H,
                       __hip_bfloat16* __restrict__ Hbf) {
    const int lane = threadIdx.x & 63;
    const int wid = threadIdx.x >> 6;
    const int half = wid & 1;
    const int widx = blockIdx.x * 2 + (wid >> 1);  // wave index within combo
    const int nw = gridDim.x * 2;                  // waves per combo
    const int l15 = lane & 15, lk = lane >> 4;

    bfrag B[8][4];
    #pragma unroll
    for (int kf = 0; kf < 8; kf++)
        #pragma unroll
        for (int cfi = 0; cfi < 4; cfi++)
            B[kf][cfi] = *(const bfrag*)&Bh[
                (size_t)(((half * 4 + cfi) * 8 + kf) * 64 + lane) * 8];

    float vv[4], cc[4];
    #pragma unroll
    for (int cfi = 0; cfi < 4; cfi++) {
        int col = half * 64 + cfi * 16 + l15;
        vv[cfi] = v3[256 + col];
        cc[cfi] = c3[256 + col];
    }

    for (int tile = widx; tile < NTILES; tile += nw) {
        const int rowBase = tile * 32;

        bfrag a[8][2];
        #pragma unroll
        for (int kf = 0; kf < 8; kf++) {
            const __hip_bfloat16* Asrc = (kf < 4) ? ybf : Hrbf;
            const int koff = (kf & 3) * 32 + lk * 8;
            #pragma unroll
            for (int rf = 0; rf < 2; rf++)
                a[kf][rf] = *(const bfrag*)&Asrc[(size_t)(rowBase + rf * 16 + l15) * 128 + koff];
        }

        facc acc[2][4];
        #pragma unroll
        for (int rf = 0; rf < 2; rf++)
            #pragma unroll
            for (int cfi = 0; cfi < 4; cfi++) acc[rf][cfi] = (facc){0.f, 0.f, 0.f, 0.f};

        #pragma unroll
        for (int kf = 0; kf < 8; kf++)
            #pragma unroll
            for (int cfi = 0; cfi < 4; cfi++)
                #pragma unroll
                for (int rf = 0; rf < 2; rf++)
                    acc[rf][cfi] = __builtin_amdgcn_mfma_f32_16x16x32_bf16(
                        a[kf][rf], B[kf][cfi], acc[rf][cfi], 0, 0, 0);

        #pragma unroll
        for (int rf = 0; rf < 2; rf++) {
            #pragma unroll
            for (int r = 0; r < 4; r++) {
                const int row = rowBase + rf * 16 + lk * 4 + r;
                const float srow = svec[row];
                #pragma unroll
                for (int cfi = 0; cfi < 4; cfi++) {
                    const int col = half * 64 + cfi * 16 + l15;
                    const float aval = acc[rf][cfi][r] + srow * vv[cfi] + cc[cfi];
                    const size_t o = (size_t)row * 128 + col;
                    const float ht = tanhf(aval);
                    const float z = __bfloat162float(Zbf[o]);
                    const float hn = z * H[o] + (1.f - z) * ht;
                    H[o] = hn;
                    Hbf[o] = __float2bfloat16(hn);
                }
            }
        }
    }
}

// ---------------------------------------------------------------------------
__global__ void maxpool_partial(const float* __restrict__ H, float* __restrict__ part) {
    int c = threadIdx.x;  // 128
    float m = -1e30f;
    for (int r = blockIdx.x; r < NN; r += gridDim.x)
        m = fmaxf(m, H[(size_t)r * 128 + c]);
    part[blockIdx.x * 128 + c] = m;
}

__global__ void final_out(const float* __restrict__ part, const float* __restrict__ W2,
                          const float* __restrict__ b2, float* __restrict__ out) {
    __shared__ float hmax[128];
    int tid = threadIdx.x;  // 128
    float m = -1e30f;
    for (int b = 0; b < 256; b++) m = fmaxf(m, part[b * 128 + tid]);
    hmax[tid] = m;
    __syncthreads();
    if (tid < 10) {
        float sacc = b2[tid];
        for (int c = 0; c < 128; c++) sacc += hmax[c] * W2[c * 10 + tid];
        out[tid] = sacc;
    }
}

extern "C" void kernel_launch(void* const* d_in, const int* in_sizes, int n_in,
                              void* d_out, int out_size, void* d_ws, size_t ws_size,
                              hipStream_t stream) {
    const float* x[3]     = {(const float*)d_in[0], (const float*)d_in[2], (const float*)d_in[4]};
    const int*   edges[3] = {(const int*)d_in[1], (const int*)d_in[3], (const int*)d_in[5]};
    const float* W1 = (const float*)d_in[6];
    const float* b1 = (const float*)d_in[7];
    const float* convW[3] = {(const float*)d_in[8], (const float*)d_in[12], (const float*)d_in[16]};
    const float* convb[3] = {(const float*)d_in[9], (const float*)d_in[13], (const float*)d_in[17]};
    const float* linW[3]  = {(const float*)d_in[10], (const float*)d_in[14], (const float*)d_in[18]};
    const float* linb[3]  = {(const float*)d_in[11], (const float*)d_in[15], (const float*)d_in[19]};
    const float* W2 = (const float*)d_in[20];
    const float* b2 = (const float*)d_in[21];

    float* ws   = (float*)d_ws;
    float* B3   = ws;                  // 98304
    float* v3   = B3 + 98304;          // 384
    float* c3   = v3 + 384;            // 384
    float* M    = c3 + 384;            // 49152
    float* dinv = M + 49152;           // NN
    float* svb  = dinv + NN;           // NN
    float* part = svb + NN;            // 32768
    int*   deg  = (int*)(part + 32768);     // NN (reused as cursor)
    int*   offs = deg + NN;                 // NN+4
    int*   partial = offs + NN + 4;         // 128
    int*   sorted_src = partial + 128;      // EE
    __hip_bfloat16* Bzr  = (__hip_bfloat16*)(sorted_src + EE);   // 65536
    __hip_bfloat16* Bh   = Bzr + 65536;                          // 32768
    __hip_bfloat16* ybf  = Bh + 32768;                           // NN*128
    __hip_bfloat16* Hbf  = ybf + (size_t)NN * 128;               // NN*128
    __hip_bfloat16* Hrbf = Hbf + (size_t)NN * 128;               // NN*128
    __hip_bfloat16* Zbf  = Hrbf + (size_t)NN * 128;              // NN*128
    float* H = (float*)(Zbf + (size_t)NN * 128);                 // NN*128 f32
    // total ~162.6 MB

    prep1<<<192, 256, 0, stream>>>(convW[0], convW[1], convW[2],
                                   linW[0], linW[1], linW[2], M);
    prep2<<<384, 256, 0, stream>>>(W1, M, linW[0], linW[1], linW[2], B3);
    prep3<<<2, 256, 0, stream>>>(b1, M, convb[0], convb[1], convb[2],
                                 linW[0], linW[1], linW[2],
                                 linb[0], linb[1], linb[2], v3, c3);
    pack_zr<<<256, 256, 0, stream>>>(B3, Bzr);
    pack_h<<<128, 256, 0, stream>>>(B3, Bh);

    hipMemsetAsync(H, 0, (size_t)NN * 128 * sizeof(float), stream);
    hipMemsetAsync(Hbf, 0, (size_t)NN * 128 * sizeof(__hip_bfloat16), stream);

    for (int t = 0; t < 3; t++) {
        const int* src = edges[t];
        const int* dst = edges[t] + EE;

        hipMemsetAsync(deg, 0, NN * sizeof(int), stream);
        hist_kernel<<<2048, 256, 0, stream>>>(dst, deg);
        dinv_kernel<<<(NN + 255) / 256, 256, 0, stream>>>(deg, dinv);
        scan_local<<<SCAN_NB, SCAN_B, 0, stream>>>(deg, offs, partial);
        scan_carry<<<1, 64, 0, stream>>>(partial, offs);
        scan_add<<<SCAN_NB, SCAN_B, 0, stream>>>(offs, partial);
        hipMemsetAsync(deg, 0, NN * sizeof(int), stream);  // deg -> cursor
        bucket_fill<<<2048, 256, 0, stream>>>(src, dst, offs, deg, sorted_src);
        gather_agg<<<25000, 256, 0, stream>>>(sorted_src, offs, x[t], dinv, ybf, svb);

        gates_zr<<<512, 256, 0, stream>>>(ybf, Hbf, H, Bzr, v3, c3, svb, Zbf, Hrbf);
        gate_h<<<256, 256, 0, stream>>>(ybf, Hrbf, Bh, v3, c3, svb, Zbf, H, Hbf);
    }

    maxpool_partial<<<256, 128, 0, stream>>>(H, part);
    final_out<<<1, 128, 0, stream>>>(part, W2, b2, (float*)d_out);
}

// Round 6
// 1594.806 us; speedup vs baseline: 3.6729x; 1.0439x over previous
//
#include <hip/hip_runtime.h>
#include <hip/hip_bf16.h>
#include <math.h>

#define NN 100000
#define EE 1600000
#define SCAN_B 1024
#define SCAN_NB 98   // ceil(100000/1024)
#define NTILES 3125  // NN / 32 exactly

typedef __attribute__((ext_vector_type(8))) short bfrag;   // 8 bf16 = 4 VGPR
typedef __attribute__((ext_vector_type(4))) float facc;    // 4 f32 acc

__device__ __forceinline__ float bflo(unsigned u) {
    return __uint_as_float((u & 0xffffu) << 16);
}
__device__ __forceinline__ float bfhi(unsigned u) {
    return __uint_as_float(u & 0xffff0000u);
}
__device__ __forceinline__ unsigned short f2bf(float f) {
    __hip_bfloat16 b = __float2bfloat16(f);
    return *(unsigned short*)&b;
}

// ---------------------------------------------------------------------------
// Weight folding:  M_g = convW_g @ linW_g[0:128,:]        (128x128)
//                  B3_g = [ W1 @ M_g ; linW_g[128:256,:] ] (256x128)
//                  v_g = b1 @ M_g ; c_g = convb_g @ linW_g[0:128,:] + linb_g
// Gate pre-activation: a_g = [y | H] @ B3_g + s*v_g + c_g
// y = Norm(x), s = Norm(1), Norm = D^-1/2 (A+I) D^-1/2
// ---------------------------------------------------------------------------
__global__ void prep1(const float* __restrict__ Wcz, const float* __restrict__ Wcr,
                      const float* __restrict__ Wch,
                      const float* __restrict__ Wlz, const float* __restrict__ Wlr,
                      const float* __restrict__ Wlh,
                      float* __restrict__ M) {
    int idx = blockIdx.x * 256 + threadIdx.x;   // 3*16384
    int g = idx >> 14, r = idx & 16383;
    int i = r >> 7, j = r & 127;
    const float* Wc = g == 0 ? Wcz : (g == 1 ? Wcr : Wch);
    const float* Wl = g == 0 ? Wlz : (g == 1 ? Wlr : Wlh);
    float s = 0.f;
    for (int m = 0; m < 128; m++) s += Wc[i * 128 + m] * Wl[m * 128 + j];
    M[idx] = s;
}

__global__ void prep2(const float* __restrict__ W1, const float* __restrict__ M,
                      const float* __restrict__ Wlz, const float* __restrict__ Wlr,
                      const float* __restrict__ Wlh,
                      float* __restrict__ B) {
    int idx = blockIdx.x * 256 + threadIdx.x;  // 3*256*128
    int g = idx >> 15, r = idx & 32767;
    int k = r >> 7, j = r & 127;
    float o;
    if (k < 128) {
        const float* Mg = M + g * 16384;
        float sacc = 0.f;
        for (int m = 0; m < 128; m++) sacc += W1[k * 128 + m] * Mg[m * 128 + j];
        o = sacc;
    } else {
        const float* Wl = g == 0 ? Wlz : (g == 1 ? Wlr : Wlh);
        o = Wl[k * 128 + j];
    }
    B[idx] = o;
}

__global__ void prep3(const float* __restrict__ b1, const float* __restrict__ M,
                      const float* __restrict__ bcz, const float* __restrict__ bcr,
                      const float* __restrict__ bch,
                      const float* __restrict__ Wlz, const float* __restrict__ Wlr,
                      const float* __restrict__ Wlh,
                      const float* __restrict__ blz, const float* __restrict__ blr,
                      const float* __restrict__ blh,
                      float* __restrict__ v, float* __restrict__ c) {
    int idx = blockIdx.x * 256 + threadIdx.x;
    if (idx >= 384) return;
    int g = idx >> 7, j = idx & 127;
    const float* Mg = M + g * 16384;
    float sv = 0.f;
    for (int m = 0; m < 128; m++) sv += b1[m] * Mg[m * 128 + j];
    v[idx] = sv;
    const float* bc = g == 0 ? bcz : (g == 1 ? bcr : bch);
    const float* Wl = g == 0 ? Wlz : (g == 1 ? Wlr : Wlh);
    const float* bl = g == 0 ? blz : (g == 1 ? blr : blh);
    float sc = bl[j];
    for (int m = 0; m < 128; m++) sc += bc[m] * Wl[m * 128 + j];
    c[idx] = sc;
}

// Frag-packed bf16 B for MFMA. Frag f=(gcf*8+kf): elem (lane,i) =
// B3[g][kf*32+(lane>>4)*8+i][(gcf&7)*16+(lane&15)], g = gcf>>3 (zr) or 2 (h).
__global__ void pack_zr(const float* __restrict__ B3, __hip_bfloat16* __restrict__ out) {
    int idx = blockIdx.x * 256 + threadIdx.x;  // 65536
    if (idx >= 65536) return;
    int i = idx & 7, lane = (idx >> 3) & 63, kf = (idx >> 9) & 7, gcf = idx >> 12;
    int g = gcf >> 3;
    int j = (gcf & 7) * 16 + (lane & 15);
    int k = kf * 32 + (lane >> 4) * 8 + i;
    out[idx] = __float2bfloat16(B3[g * 32768 + k * 128 + j]);
}

__global__ void pack_h(const float* __restrict__ B3, __hip_bfloat16* __restrict__ out) {
    int idx = blockIdx.x * 256 + threadIdx.x;  // 32768
    if (idx >= 32768) return;
    int i = idx & 7, lane = (idx >> 3) & 63, kf = (idx >> 9) & 7, cf = idx >> 12;
    int j = cf * 16 + (lane & 15);
    int k = kf * 32 + (lane >> 4) * 8 + i;
    out[idx] = __float2bfloat16(B3[2 * 32768 + k * 128 + j]);
}

// ---------------------------------------------------------------------------
// CSR build: histogram -> exclusive scan -> bucket fill
// ---------------------------------------------------------------------------
__global__ void hist_kernel(const int* __restrict__ dst, int* __restrict__ deg) {
    int i = blockIdx.x * blockDim.x + threadIdx.x;
    int stride = gridDim.x * blockDim.x;
    for (; i < EE; i += stride) atomicAdd(&deg[dst[i]], 1);
}

__global__ void dinv_kernel(const int* __restrict__ deg, float* __restrict__ dinv) {
    int i = blockIdx.x * blockDim.x + threadIdx.x;
    if (i < NN) dinv[i] = rsqrtf((float)deg[i] + 1.0f);  // +1 = self loop
}

// xs[i,:] = bf16(dinv[i] * x[i,:])
__global__ void xscale_bf(const float* __restrict__ x, const float* __restrict__ dinv,
                          __hip_bfloat16* __restrict__ xs) {
    int idx = blockIdx.x * 256 + threadIdx.x;   // NN*32 threads, 4 elems each
    int row = idx >> 5, c4 = (idx & 31) * 4;
    float di = dinv[row];
    float4 v = *(const float4*)&x[(size_t)row * 128 + c4];
    uint2 o;
    o.x = (unsigned)f2bf(di * v.x) | ((unsigned)f2bf(di * v.y) << 16);
    o.y = (unsigned)f2bf(di * v.z) | ((unsigned)f2bf(di * v.w) << 16);
    *(uint2*)&xs[(size_t)row * 128 + c4] = o;
}

__global__ void scan_local(const int* __restrict__ deg, int* __restrict__ offs,
                           int* __restrict__ partial) {
    __shared__ int sm[SCAN_B];
    int t = threadIdx.x;
    int i = blockIdx.x * SCAN_B + t;
    int v = (i < NN) ? deg[i] : 0;
    sm[t] = v;
    __syncthreads();
    #pragma unroll
    for (int off = 1; off < SCAN_B; off <<= 1) {
        int x = (t >= off) ? sm[t - off] : 0;
        __syncthreads();
        sm[t] += x;
        __syncthreads();
    }
    if (i < NN) offs[i] = sm[t] - v;
    if (t == SCAN_B - 1) partial[blockIdx.x] = sm[t];
}

__global__ void scan_carry(int* __restrict__ partial, int* __restrict__ offs) {
    if (threadIdx.x == 0) {
        int carry = 0;
        for (int b = 0; b < SCAN_NB; b++) {
            int p = partial[b];
            partial[b] = carry;
            carry += p;
        }
        offs[NN] = carry;  // == EE
    }
}

__global__ void scan_add(int* __restrict__ offs, const int* __restrict__ partial) {
    int i = blockIdx.x * SCAN_B + threadIdx.x;
    if (i < NN) offs[i] += partial[blockIdx.x];
}

__global__ void bucket_fill(const int* __restrict__ src, const int* __restrict__ dst,
                            const int* __restrict__ offs, int* __restrict__ cursor,
                            int* __restrict__ sorted_src) {
    int i = blockIdx.x * blockDim.x + threadIdx.x;
    int stride = gridDim.x * blockDim.x;
    for (; i < EE; i += stride) {
        int d = dst[i];
        int pos = offs[d] + atomicAdd(&cursor[d], 1);
        sorted_src[pos] = src[i];
    }
}

// ---------------------------------------------------------------------------
// Gather aggregation: one wave per dst node, two edges per iteration
// (lanes 0-31 edge e, lanes 32-63 edge e+1; 4 bf16 = 8B per lane).
// y_i = dinv_i * ( sum_{s in N(i)} xs_s + xs_i ),  xs = dinv*x in bf16
// sv_i = dinv_i * ( sum dinv_s + dinv_i )
// ---------------------------------------------------------------------------
__global__ void gather_agg(const int* __restrict__ sorted_src,
                           const int* __restrict__ offs,
                           const __hip_bfloat16* __restrict__ xs,
                           const float* __restrict__ dinv,
                           __hip_bfloat16* __restrict__ y, float* __restrict__ sv) {
    const int lane = threadIdx.x & 63;
    const int half = lane >> 5;
    const int l31 = lane & 31;
    const int node = blockIdx.x * 4 + (threadIdx.x >> 6);
    if (node >= NN) return;
    const int beg = offs[node], end = offs[node + 1];

    float a0 = 0.f, a1 = 0.f, a2 = 0.f, a3 = 0.f, sacc = 0.f;
    for (int e = beg; e < end; e += 2) {
        int ei = e + half;
        bool ok = ei < end;
        int s = sorted_src[ok ? ei : e];
        float w = ok ? 1.f : 0.f;
        uint2 raw = *(const uint2*)&xs[(size_t)s * 128 + l31 * 4];
        a0 += w * bflo(raw.x);
        a1 += w * bfhi(raw.x);
        a2 += w * bflo(raw.y);
        a3 += w * bfhi(raw.y);
        sacc += w * dinv[s];
    }
    // combine the two halves
    a0 += __shfl_xor(a0, 32);
    a1 += __shfl_xor(a1, 32);
    a2 += __shfl_xor(a2, 32);
    a3 += __shfl_xor(a3, 32);
    sacc += __shfl_xor(sacc, 32);

    const float di = dinv[node];
    if (half == 0) {
        uint2 raw = *(const uint2*)&xs[(size_t)node * 128 + l31 * 4];
        a0 = di * (a0 + bflo(raw.x));
        a1 = di * (a1 + bfhi(raw.x));
        a2 = di * (a2 + bflo(raw.y));
        a3 = di * (a3 + bfhi(raw.y));
        uint2 o;
        o.x = (unsigned)f2bf(a0) | ((unsigned)f2bf(a1) << 16);
        o.y = (unsigned)f2bf(a2) | ((unsigned)f2bf(a3) << 16);
        *(uint2*)&y[(size_t)node * 128 + l31 * 4] = o;
    }
    if (lane == 0) sv[node] = di * (sacc + di);
}

// ---------------------------------------------------------------------------
// MFMA gate GEMMs, B-resident-in-registers + grid-stride over 32-row tiles.
// ---------------------------------------------------------------------------
__launch_bounds__(256)
__global__ void gates_zr(const __hip_bfloat16* __restrict__ ybf,
                         const __hip_bfloat16* __restrict__ Hbf,
                         const float* __restrict__ H,
                         const __hip_bfloat16* __restrict__ Bzr,
                         const float* __restrict__ v3, const float* __restrict__ c3,
                         const float* __restrict__ svec,
                         __hip_bfloat16* __restrict__ Zbf,
                         __hip_bfloat16* __restrict__ Hrbf) {
    const int lane = threadIdx.x & 63;
    const int wid = threadIdx.x >> 6;
    const int gate = wid >> 1;          // 0=z, 1=r
    const int half = wid & 1;           // col half
    const int widx = blockIdx.x;        // wave index within combo
    const int nw = gridDim.x;           // waves per combo
    const int l15 = lane & 15, lk = lane >> 4;

    bfrag B[8][4];
    #pragma unroll
    for (int kf = 0; kf < 8; kf++)
        #pragma unroll
        for (int cfi = 0; cfi < 4; cfi++)
            B[kf][cfi] = *(const bfrag*)&Bzr[
                (size_t)(((gate * 8 + half * 4 + cfi) * 8 + kf) * 64 + lane) * 8];

    float vv[4], cc[4];
    #pragma unroll
    for (int cfi = 0; cfi < 4; cfi++) {
        int col = half * 64 + cfi * 16 + l15;
        vv[cfi] = v3[gate * 128 + col];
        cc[cfi] = c3[gate * 128 + col];
    }

    for (int tile = widx; tile < NTILES; tile += nw) {
        const int rowBase = tile * 32;

        bfrag a[8][2];
        #pragma unroll
        for (int kf = 0; kf < 8; kf++) {
            const __hip_bfloat16* Asrc = (kf < 4) ? ybf : Hbf;
            const int koff = (kf & 3) * 32 + lk * 8;
            #pragma unroll
            for (int rf = 0; rf < 2; rf++)
                a[kf][rf] = *(const bfrag*)&Asrc[(size_t)(rowBase + rf * 16 + l15) * 128 + koff];
        }

        facc acc[2][4];
        #pragma unroll
        for (int rf = 0; rf < 2; rf++)
            #pragma unroll
            for (int cfi = 0; cfi < 4; cfi++) acc[rf][cfi] = (facc){0.f, 0.f, 0.f, 0.f};

        #pragma unroll
        for (int kf = 0; kf < 8; kf++)
            #pragma unroll
            for (int cfi = 0; cfi < 4; cfi++)
                #pragma unroll
                for (int rf = 0; rf < 2; rf++)
                    acc[rf][cfi] = __builtin_amdgcn_mfma_f32_16x16x32_bf16(
                        a[kf][rf], B[kf][cfi], acc[rf][cfi], 0, 0, 0);

        #pragma unroll
        for (int rf = 0; rf < 2; rf++) {
            #pragma unroll
            for (int r = 0; r < 4; r++) {
                const int row = rowBase + rf * 16 + lk * 4 + r;
                const float srow = svec[row];
                #pragma unroll
                for (int cfi = 0; cfi < 4; cfi++) {
                    const int col = half * 64 + cfi * 16 + l15;
                    const float aval = acc[rf][cfi][r] + srow * vv[cfi] + cc[cfi];
                    const size_t o = (size_t)row * 128 + col;
                    const float sg = 1.f / (1.f + expf(-aval));
                    if (gate == 0) Zbf[o] = __float2bfloat16(sg);
                    else           Hrbf[o] = __float2bfloat16(H[o] * sg);
                }
            }
        }
    }
}

__launch_bounds__(256)
__global__ void gate_h(const __hip_bfloat16* __restrict__ ybf,
                       const __hip_bfloat16* __restrict__ Hrbf,
                       const __hip_bfloat16* __restrict__ Bh,
                       const float* __restrict__ v3, const float* __restrict__ c3,
                       const float* __restrict__ svec,
                       const __hip_bfloat16* __restrict__ Zbf,
                       float* __restrict__ H,
                       __hip_bfloat16* __restrict__ Hbf) {
    const int lane = threadIdx.x & 63;
    const int wid = threadIdx.x >> 6;
    const int half = wid & 1;
    const int widx = blockIdx.x * 2 + (wid >> 1);  // wave index within combo
    const int nw = gridDim.x * 2;                  // waves per combo
    const int l15 = lane & 15, lk = lane >> 4;

    bfrag B[8][4];
    #pragma unroll
    for (int kf = 0; kf < 8; kf++)
        #pragma unroll
        for (int cfi = 0; cfi < 4; cfi++)
            B[kf][cfi] = *(const bfrag*)&Bh[
                (size_t)(((half * 4 + cfi) * 8 + kf) * 64 + lane) * 8];

    float vv[4], cc[4];
    #pragma unroll
    for (int cfi = 0; cfi < 4; cfi++) {
        int col = half * 64 + cfi * 16 + l15;
        vv[cfi] = v3[256 + col];
        cc[cfi] = c3[256 + col];
    }

    for (int tile = widx; tile < NTILES; tile += nw) {
        const int rowBase = tile * 32;

        bfrag a[8][2];
        #pragma unroll
        for (int kf = 0; kf < 8; kf++) {
            const __hip_bfloat16* Asrc = (kf < 4) ? ybf : Hrbf;
            const int koff = (kf & 3) * 32 + lk * 8;
            #pragma unroll
            for (int rf = 0; rf < 2; rf++)
                a[kf][rf] = *(const bfrag*)&Asrc[(size_t)(rowBase + rf * 16 + l15) * 128 + koff];
        }

        facc acc[2][4];
        #pragma unroll
        for (int rf = 0; rf < 2; rf++)
            #pragma unroll
            for (int cfi = 0; cfi < 4; cfi++) acc[rf][cfi] = (facc){0.f, 0.f, 0.f, 0.f};

        #pragma unroll
        for (int kf = 0; kf < 8; kf++)
            #pragma unroll
            for (int cfi = 0; cfi < 4; cfi++)
                #pragma unroll
                for (int rf = 0; rf < 2; rf++)
                    acc[rf][cfi] = __builtin_amdgcn_mfma_f32_16x16x32_bf16(
                        a[kf][rf], B[kf][cfi], acc[rf][cfi], 0, 0, 0);

        #pragma unroll
        for (int rf = 0; rf < 2; rf++) {
            #pragma unroll
            for (int r = 0; r < 4; r++) {
                const int row = rowBase + rf * 16 + lk * 4 + r;
                const float srow = svec[row];
                #pragma unroll
                for (int cfi = 0; cfi < 4; cfi++) {
                    const int col = half * 64 + cfi * 16 + l15;
                    const float aval = acc[rf][cfi][r] + srow * vv[cfi] + cc[cfi];
                    const size_t o = (size_t)row * 128 + col;
                    const float ht = tanhf(aval);
                    const float z = __bfloat162float(Zbf[o]);
                    const float hn = z * H[o] + (1.f - z) * ht;
                    H[o] = hn;
                    Hbf[o] = __float2bfloat16(hn);
                }
            }
        }
    }
}

// ---------------------------------------------------------------------------
__global__ void maxpool_partial(const float* __restrict__ H, float* __restrict__ part) {
    int c = threadIdx.x;  // 128
    float m = -1e30f;
    for (int r = blockIdx.x; r < NN; r += gridDim.x)
        m = fmaxf(m, H[(size_t)r * 128 + c]);
    part[blockIdx.x * 128 + c] = m;
}

__global__ void final_out(const float* __restrict__ part, const float* __restrict__ W2,
                          const float* __restrict__ b2, float* __restrict__ out) {
    __shared__ float hmax[128];
    int tid = threadIdx.x;  // 128
    float m = -1e30f;
    for (int b = 0; b < 256; b++) m = fmaxf(m, part[b * 128 + tid]);
    hmax[tid] = m;
    __syncthreads();
    if (tid < 10) {
        float sacc = b2[tid];
        for (int c = 0; c < 128; c++) sacc += hmax[c] * W2[c * 10 + tid];
        out[tid] = sacc;
    }
}

extern "C" void kernel_launch(void* const* d_in, const int* in_sizes, int n_in,
                              void* d_out, int out_size, void* d_ws, size_t ws_size,
                              hipStream_t stream) {
    const float* x[3]     = {(const float*)d_in[0], (const float*)d_in[2], (const float*)d_in[4]};
    const int*   edges[3] = {(const int*)d_in[1], (const int*)d_in[3], (const int*)d_in[5]};
    const float* W1 = (const float*)d_in[6];
    const float* b1 = (const float*)d_in[7];
    const float* convW[3] = {(const float*)d_in[8], (const float*)d_in[12], (const float*)d_in[16]};
    const float* convb[3] = {(const float*)d_in[9], (const float*)d_in[13], (const float*)d_in[17]};
    const float* linW[3]  = {(const float*)d_in[10], (const float*)d_in[14], (const float*)d_in[18]};
    const float* linb[3]  = {(const float*)d_in[11], (const float*)d_in[15], (const float*)d_in[19]};
    const float* W2 = (const float*)d_in[20];
    const float* b2 = (const float*)d_in[21];

    float* ws   = (float*)d_ws;
    float* B3   = ws;                  // 98304
    float* v3   = B3 + 98304;          // 384
    float* c3   = v3 + 384;            // 384
    float* M    = c3 + 384;            // 49152
    float* dinv = M + 49152;           // NN
    float* svb  = dinv + NN;           // NN
    float* part = svb + NN;            // 32768
    int*   deg  = (int*)(part + 32768);     // NN (reused as cursor)
    int*   offs = deg + NN;                 // NN+4
    int*   partial = offs + NN + 4;         // 128
    int*   sorted_src = partial + 128;      // EE
    __hip_bfloat16* Bzr  = (__hip_bfloat16*)(sorted_src + EE);   // 65536
    __hip_bfloat16* Bh   = Bzr + 65536;                          // 32768
    __hip_bfloat16* ybf  = Bh + 32768;                           // NN*128
    __hip_bfloat16* Hbf  = ybf + (size_t)NN * 128;               // NN*128
    __hip_bfloat16* Hrbf = Hbf + (size_t)NN * 128;               // NN*128 (aliased as xs)
    __hip_bfloat16* Zbf  = Hrbf + (size_t)NN * 128;              // NN*128
    float* H = (float*)(Zbf + (size_t)NN * 128);                 // NN*128 f32
    __hip_bfloat16* xs = Hrbf;  // alias: xs live only gather-phase, Hr live only gate-phase
    // total ~162.6 MB

    prep1<<<192, 256, 0, stream>>>(convW[0], convW[1], convW[2],
                                   linW[0], linW[1], linW[2], M);
    prep2<<<384, 256, 0, stream>>>(W1, M, linW[0], linW[1], linW[2], B3);
    prep3<<<2, 256, 0, stream>>>(b1, M, convb[0], convb[1], convb[2],
                                 linW[0], linW[1], linW[2],
                                 linb[0], linb[1], linb[2], v3, c3);
    pack_zr<<<256, 256, 0, stream>>>(B3, Bzr);
    pack_h<<<128, 256, 0, stream>>>(B3, Bh);

    hipMemsetAsync(H, 0, (size_t)NN * 128 * sizeof(float), stream);
    hipMemsetAsync(Hbf, 0, (size_t)NN * 128 * sizeof(__hip_bfloat16), stream);

    for (int t = 0; t < 3; t++) {
        const int* src = edges[t];
        const int* dst = edges[t] + EE;

        hipMemsetAsync(deg, 0, NN * sizeof(int), stream);
        hist_kernel<<<2048, 256, 0, stream>>>(dst, deg);
        dinv_kernel<<<(NN + 255) / 256, 256, 0, stream>>>(deg, dinv);
        xscale_bf<<<12500, 256, 0, stream>>>(x[t], dinv, xs);
        scan_local<<<SCAN_NB, SCAN_B, 0, stream>>>(deg, offs, partial);
        scan_carry<<<1, 64, 0, stream>>>(partial, offs);
        scan_add<<<SCAN_NB, SCAN_B, 0, stream>>>(offs, partial);
        hipMemsetAsync(deg, 0, NN * sizeof(int), stream);  // deg -> cursor
        bucket_fill<<<2048, 256, 0, stream>>>(src, dst, offs, deg, sorted_src);
        gather_agg<<<25000, 256, 0, stream>>>(sorted_src, offs, xs, dinv, ybf, svb);

        gates_zr<<<512, 256, 0, stream>>>(ybf, Hbf, H, Bzr, v3, c3, svb, Zbf, Hrbf);
        gate_h<<<256, 256, 0, stream>>>(ybf, Hrbf, Bh, v3, c3, svb, Zbf, H, Hbf);
    }

    maxpool_partial<<<256, 128, 0, stream>>>(H, part);
    final_out<<<1, 128, 0, stream>>>(part, W2, b2, (float*)d_out);
}

// Round 7
// 1385.380 us; speedup vs baseline: 4.2281x; 1.1512x over previous
//
#include <hip/hip_runtime.h>
#include <hip/hip_bf16.h>
#include <math.h>

#define NN 100000
#define EE 1600000
#define SCAN_B 1024
#define SCAN_NB 98   // ceil(100000/1024)
#define NTILES 3125  // NN / 32 exactly

typedef __attribute__((ext_vector_type(8))) short bfrag;   // 8 bf16 = 4 VGPR
typedef __attribute__((ext_vector_type(4))) float facc;    // 4 f32 acc

__device__ __forceinline__ float bflo(unsigned u) {
    return __uint_as_float((u & 0xffffu) << 16);
}
__device__ __forceinline__ float bfhi(unsigned u) {
    return __uint_as_float(u & 0xffff0000u);
}
__device__ __forceinline__ unsigned short f2bf(float f) {
    __hip_bfloat16 b = __float2bfloat16(f);
    return *(unsigned short*)&b;
}

// ---------------------------------------------------------------------------
// Weight folding:  M_g = convW_g @ linW_g[0:128,:]        (128x128)
//                  B3_g = [ W1 @ M_g ; linW_g[128:256,:] ] (256x128)
//                  v_g = b1 @ M_g ; c_g = convb_g @ linW_g[0:128,:] + linb_g
// Gate pre-activation: a_g = [y | H] @ B3_g + s*v_g + c_g
// y = Norm(x), s = Norm(1), Norm = D^-1/2 (A+I) D^-1/2
// ---------------------------------------------------------------------------
__global__ void prep1(const float* __restrict__ Wcz, const float* __restrict__ Wcr,
                      const float* __restrict__ Wch,
                      const float* __restrict__ Wlz, const float* __restrict__ Wlr,
                      const float* __restrict__ Wlh,
                      float* __restrict__ M) {
    int idx = blockIdx.x * 256 + threadIdx.x;   // 3*16384
    int g = idx >> 14, r = idx & 16383;
    int i = r >> 7, j = r & 127;
    const float* Wc = g == 0 ? Wcz : (g == 1 ? Wcr : Wch);
    const float* Wl = g == 0 ? Wlz : (g == 1 ? Wlr : Wlh);
    float s = 0.f;
    for (int m = 0; m < 128; m++) s += Wc[i * 128 + m] * Wl[m * 128 + j];
    M[idx] = s;
}

__global__ void prep2(const float* __restrict__ W1, const float* __restrict__ M,
                      const float* __restrict__ Wlz, const float* __restrict__ Wlr,
                      const float* __restrict__ Wlh,
                      float* __restrict__ B) {
    int idx = blockIdx.x * 256 + threadIdx.x;  // 3*256*128
    int g = idx >> 15, r = idx & 32767;
    int k = r >> 7, j = r & 127;
    float o;
    if (k < 128) {
        const float* Mg = M + g * 16384;
        float sacc = 0.f;
        for (int m = 0; m < 128; m++) sacc += W1[k * 128 + m] * Mg[m * 128 + j];
        o = sacc;
    } else {
        const float* Wl = g == 0 ? Wlz : (g == 1 ? Wlr : Wlh);
        o = Wl[k * 128 + j];
    }
    B[idx] = o;
}

__global__ void prep3(const float* __restrict__ b1, const float* __restrict__ M,
                      const float* __restrict__ bcz, const float* __restrict__ bcr,
                      const float* __restrict__ bch,
                      const float* __restrict__ Wlz, const float* __restrict__ Wlr,
                      const float* __restrict__ Wlh,
                      const float* __restrict__ blz, const float* __restrict__ blr,
                      const float* __restrict__ blh,
                      float* __restrict__ v, float* __restrict__ c) {
    int idx = blockIdx.x * 256 + threadIdx.x;
    if (idx >= 384) return;
    int g = idx >> 7, j = idx & 127;
    const float* Mg = M + g * 16384;
    float sv = 0.f;
    for (int m = 0; m < 128; m++) sv += b1[m] * Mg[m * 128 + j];
    v[idx] = sv;
    const float* bc = g == 0 ? bcz : (g == 1 ? bcr : bch);
    const float* Wl = g == 0 ? Wlz : (g == 1 ? Wlr : Wlh);
    const float* bl = g == 0 ? blz : (g == 1 ? blr : blh);
    float sc = bl[j];
    for (int m = 0; m < 128; m++) sc += bc[m] * Wl[m * 128 + j];
    c[idx] = sc;
}

// Frag-packed bf16 B for MFMA. Frag f=(gcf*8+kf): elem (lane,i) =
// B3[g][kf*32+(lane>>4)*8+i][(gcf&7)*16+(lane&15)], g = gcf>>3 (zr) or 2 (h).
__global__ void pack_zr(const float* __restrict__ B3, __hip_bfloat16* __restrict__ out) {
    int idx = blockIdx.x * 256 + threadIdx.x;  // 65536
    if (idx >= 65536) return;
    int i = idx & 7, lane = (idx >> 3) & 63, kf = (idx >> 9) & 7, gcf = idx >> 12;
    int g = gcf >> 3;
    int j = (gcf & 7) * 16 + (lane & 15);
    int k = kf * 32 + (lane >> 4) * 8 + i;
    out[idx] = __float2bfloat16(B3[g * 32768 + k * 128 + j]);
}

__global__ void pack_h(const float* __restrict__ B3, __hip_bfloat16* __restrict__ out) {
    int idx = blockIdx.x * 256 + threadIdx.x;  // 32768
    if (idx >= 32768) return;
    int i = idx & 7, lane = (idx >> 3) & 63, kf = (idx >> 9) & 7, cf = idx >> 12;
    int j = cf * 16 + (lane & 15);
    int k = kf * 32 + (lane >> 4) * 8 + i;
    out[idx] = __float2bfloat16(B3[2 * 32768 + k * 128 + j]);
}

// ---------------------------------------------------------------------------
// CSR build: histogram -> exclusive scan -> bucket fill
// ---------------------------------------------------------------------------
__global__ void hist_kernel(const int* __restrict__ dst, int* __restrict__ deg) {
    int i = blockIdx.x * blockDim.x + threadIdx.x;
    int stride = gridDim.x * blockDim.x;
    for (; i < EE; i += stride) atomicAdd(&deg[dst[i]], 1);
}

__global__ void dinv_kernel(const int* __restrict__ deg, float* __restrict__ dinv) {
    int i = blockIdx.x * blockDim.x + threadIdx.x;
    if (i < NN) dinv[i] = rsqrtf((float)deg[i] + 1.0f);  // +1 = self loop
}

// xs[i,:] = bf16(dinv[i] * x[i,:])
__global__ void xscale_bf(const float* __restrict__ x, const float* __restrict__ dinv,
                          __hip_bfloat16* __restrict__ xs) {
    int idx = blockIdx.x * 256 + threadIdx.x;   // NN*32 threads, 4 elems each
    int row = idx >> 5, c4 = (idx & 31) * 4;
    float di = dinv[row];
    float4 v = *(const float4*)&x[(size_t)row * 128 + c4];
    uint2 o;
    o.x = (unsigned)f2bf(di * v.x) | ((unsigned)f2bf(di * v.y) << 16);
    o.y = (unsigned)f2bf(di * v.z) | ((unsigned)f2bf(di * v.w) << 16);
    *(uint2*)&xs[(size_t)row * 128 + c4] = o;
}

__global__ void scan_local(const int* __restrict__ deg, int* __restrict__ offs,
                           int* __restrict__ partial) {
    __shared__ int sm[SCAN_B];
    int t = threadIdx.x;
    int i = blockIdx.x * SCAN_B + t;
    int v = (i < NN) ? deg[i] : 0;
    sm[t] = v;
    __syncthreads();
    #pragma unroll
    for (int off = 1; off < SCAN_B; off <<= 1) {
        int x = (t >= off) ? sm[t - off] : 0;
        __syncthreads();
        sm[t] += x;
        __syncthreads();
    }
    if (i < NN) offs[i] = sm[t] - v;
    if (t == SCAN_B - 1) partial[blockIdx.x] = sm[t];
}

__global__ void scan_carry(int* __restrict__ partial, int* __restrict__ offs) {
    if (threadIdx.x == 0) {
        int carry = 0;
        for (int b = 0; b < SCAN_NB; b++) {
            int p = partial[b];
            partial[b] = carry;
            carry += p;
        }
        offs[NN] = carry;  // == EE
    }
}

__global__ void scan_add(int* __restrict__ offs, const int* __restrict__ partial) {
    int i = blockIdx.x * SCAN_B + threadIdx.x;
    if (i < NN) offs[i] += partial[blockIdx.x];
}

__global__ void bucket_fill(const int* __restrict__ src, const int* __restrict__ dst,
                            const int* __restrict__ offs, int* __restrict__ cursor,
                            int* __restrict__ sorted_src) {
    int i = blockIdx.x * blockDim.x + threadIdx.x;
    int stride = gridDim.x * blockDim.x;
    for (; i < EE; i += stride) {
        int d = dst[i];
        int pos = offs[d] + atomicAdd(&cursor[d], 1);
        sorted_src[pos] = src[i];
    }
}

// ---------------------------------------------------------------------------
// Gather aggregation: one wave per dst node, two edges per iteration.
// ---------------------------------------------------------------------------
__global__ void gather_agg(const int* __restrict__ sorted_src,
                           const int* __restrict__ offs,
                           const __hip_bfloat16* __restrict__ xs,
                           const float* __restrict__ dinv,
                           __hip_bfloat16* __restrict__ y, float* __restrict__ sv) {
    const int lane = threadIdx.x & 63;
    const int half = lane >> 5;
    const int l31 = lane & 31;
    const int node = blockIdx.x * 4 + (threadIdx.x >> 6);
    if (node >= NN) return;
    const int beg = offs[node], end = offs[node + 1];

    float a0 = 0.f, a1 = 0.f, a2 = 0.f, a3 = 0.f, sacc = 0.f;
    for (int e = beg; e < end; e += 2) {
        int ei = e + half;
        bool ok = ei < end;
        int s = sorted_src[ok ? ei : e];
        float w = ok ? 1.f : 0.f;
        uint2 raw = *(const uint2*)&xs[(size_t)s * 128 + l31 * 4];
        a0 += w * bflo(raw.x);
        a1 += w * bfhi(raw.x);
        a2 += w * bflo(raw.y);
        a3 += w * bfhi(raw.y);
        sacc += w * dinv[s];
    }
    a0 += __shfl_xor(a0, 32);
    a1 += __shfl_xor(a1, 32);
    a2 += __shfl_xor(a2, 32);
    a3 += __shfl_xor(a3, 32);
    sacc += __shfl_xor(sacc, 32);

    const float di = dinv[node];
    if (half == 0) {
        uint2 raw = *(const uint2*)&xs[(size_t)node * 128 + l31 * 4];
        a0 = di * (a0 + bflo(raw.x));
        a1 = di * (a1 + bfhi(raw.x));
        a2 = di * (a2 + bflo(raw.y));
        a3 = di * (a3 + bfhi(raw.y));
        uint2 o;
        o.x = (unsigned)f2bf(a0) | ((unsigned)f2bf(a1) << 16);
        o.y = (unsigned)f2bf(a2) | ((unsigned)f2bf(a3) << 16);
        *(uint2*)&y[(size_t)node * 128 + l31 * 4] = o;
    }
    if (lane == 0) sv[node] = di * (sacc + di);
}

// ---------------------------------------------------------------------------
// Fully fused gate kernel. Block = 8 waves (512 thr); wave owns 16 cols.
// Per 32-row tile: a_z,a_r MFMA -> z,r in regs -> Hr via swizzled LDS ->
// a_h MFMA -> H_new. Zbf/Hrbf global buffers eliminated.
// A-frag: lane l -> row=l&15, k=(l>>4)*8+i. C/D: col=lane&15, row=(lane>>4)*4+r.
// ---------------------------------------------------------------------------
__launch_bounds__(512, 2)
__global__ void gate_fused(const __hip_bfloat16* __restrict__ ybf,
                           const __hip_bfloat16* __restrict__ Hbf,
                           float* __restrict__ H,
                           const __hip_bfloat16* __restrict__ Bzr,
                           const __hip_bfloat16* __restrict__ Bh,
                           const float* __restrict__ v3, const float* __restrict__ c3,
                           const float* __restrict__ svec,
                           __hip_bfloat16* __restrict__ Hbf_out) {
    __shared__ __hip_bfloat16 hrT[32 * 128];   // XOR-swizzled Hr tile (8 KB)
    const int lane = threadIdx.x & 63;
    const int wid = threadIdx.x >> 6;          // col-frag 0..7
    const int l15 = lane & 15, lk = lane >> 4;

    // resident B fragments (z, r, h) for this wave's 16 cols
    bfrag Bz[8], Br[8], Bhh[8];
    #pragma unroll
    for (int kf = 0; kf < 8; kf++) {
        Bz[kf]  = *(const bfrag*)&Bzr[(size_t)(((0 * 8 + wid) * 8 + kf) * 64 + lane) * 8];
        Br[kf]  = *(const bfrag*)&Bzr[(size_t)(((1 * 8 + wid) * 8 + kf) * 64 + lane) * 8];
        Bhh[kf] = *(const bfrag*)&Bh[(size_t)((wid * 8 + kf) * 64 + lane) * 8];
    }
    const int col = wid * 16 + l15;
    const float vz = v3[col],       cz = c3[col];
    const float vr = v3[128 + col], cr = c3[128 + col];
    const float vh = v3[256 + col], ch = c3[256 + col];

    for (int tile = blockIdx.x; tile < NTILES; tile += gridDim.x) {
        const int rowBase = tile * 32;

        // A-frags over K=256 of [y | H]
        bfrag ay[4][2], ahf[4][2];
        #pragma unroll
        for (int kf = 0; kf < 4; kf++) {
            const int koff = kf * 32 + lk * 8;
            #pragma unroll
            for (int rf = 0; rf < 2; rf++) {
                const size_t rowoff = (size_t)(rowBase + rf * 16 + l15) * 128 + koff;
                ay[kf][rf]  = *(const bfrag*)&ybf[rowoff];
                ahf[kf][rf] = *(const bfrag*)&Hbf[rowoff];
            }
        }

        facc az[2], ar[2];
        #pragma unroll
        for (int rf = 0; rf < 2; rf++) { az[rf] = (facc){0.f,0.f,0.f,0.f}; ar[rf] = (facc){0.f,0.f,0.f,0.f}; }

        #pragma unroll
        for (int kf = 0; kf < 4; kf++)
            #pragma unroll
            for (int rf = 0; rf < 2; rf++) {
                az[rf] = __builtin_amdgcn_mfma_f32_16x16x32_bf16(ay[kf][rf],  Bz[kf],     az[rf], 0, 0, 0);
                ar[rf] = __builtin_amdgcn_mfma_f32_16x16x32_bf16(ay[kf][rf],  Br[kf],     ar[rf], 0, 0, 0);
                az[rf] = __builtin_amdgcn_mfma_f32_16x16x32_bf16(ahf[kf][rf], Bz[kf + 4], az[rf], 0, 0, 0);
                ar[rf] = __builtin_amdgcn_mfma_f32_16x16x32_bf16(ahf[kf][rf], Br[kf + 4], ar[rf], 0, 0, 0);
            }

        // epilogue z/r: z kept in regs, Hr -> swizzled LDS
        float zv[2][4], Hf[2][4];
        #pragma unroll
        for (int rf = 0; rf < 2; rf++) {
            #pragma unroll
            for (int r = 0; r < 4; r++) {
                const int lrow = rf * 16 + lk * 4 + r;
                const int row = rowBase + lrow;
                const float sr = svec[row];
                const float azv = az[rf][r] + sr * vz + cz;
                const float arv = ar[rf][r] + sr * vr + cr;
                const float z  = 1.f / (1.f + expf(-azv));
                const float rr = 1.f / (1.f + expf(-arv));
                const float hf = H[(size_t)row * 128 + col];
                zv[rf][r] = z;
                Hf[rf][r] = hf;
                const int baddr = lrow * 256 + ((col * 2) ^ ((lrow & 7) << 4));
                *(__hip_bfloat16*)((char*)hrT + baddr) = __float2bfloat16(hf * rr);
            }
        }
        __syncthreads();   // Hr writes visible

        facc ah[2];
        #pragma unroll
        for (int rf = 0; rf < 2; rf++) ah[rf] = (facc){0.f,0.f,0.f,0.f};

        #pragma unroll
        for (int kf = 0; kf < 4; kf++)
            #pragma unroll
            for (int rf = 0; rf < 2; rf++)
                ah[rf] = __builtin_amdgcn_mfma_f32_16x16x32_bf16(ay[kf][rf], Bhh[kf], ah[rf], 0, 0, 0);

        #pragma unroll
        for (int kf = 0; kf < 4; kf++) {
            const int koff = kf * 32 + lk * 8;
            #pragma unroll
            for (int rf = 0; rf < 2; rf++) {
                const int lrow = rf * 16 + l15;
                const int baddr = lrow * 256 + ((koff * 2) ^ ((lrow & 7) << 4));
                bfrag hrf = *(const bfrag*)((char*)hrT + baddr);
                ah[rf] = __builtin_amdgcn_mfma_f32_16x16x32_bf16(hrf, Bhh[kf + 4], ah[rf], 0, 0, 0);
            }
        }

        // epilogue h: H_new = z*H + (1-z)*tanh(a_h)
        #pragma unroll
        for (int rf = 0; rf < 2; rf++) {
            #pragma unroll
            for (int r = 0; r < 4; r++) {
                const int row = rowBase + rf * 16 + lk * 4 + r;
                const float sr = svec[row];
                const float av = ah[rf][r] + sr * vh + ch;
                const float ht = tanhf(av);
                const float z = zv[rf][r];
                const float hn = z * Hf[rf][r] + (1.f - z) * ht;
                const size_t o = (size_t)row * 128 + col;
                H[o] = hn;
                Hbf_out[o] = __float2bfloat16(hn);
            }
        }
        __syncthreads();   // LDS reads done before next tile's writes
    }
}

// ---------------------------------------------------------------------------
__global__ void maxpool_partial(const float* __restrict__ H, float* __restrict__ part) {
    int c = threadIdx.x;  // 128
    float m = -1e30f;
    for (int r = blockIdx.x; r < NN; r += gridDim.x)
        m = fmaxf(m, H[(size_t)r * 128 + c]);
    part[blockIdx.x * 128 + c] = m;
}

__global__ void final_out(const float* __restrict__ part, const float* __restrict__ W2,
                          const float* __restrict__ b2, float* __restrict__ out) {
    __shared__ float hmax[128];
    int tid = threadIdx.x;  // 128
    float m = -1e30f;
    for (int b = 0; b < 256; b++) m = fmaxf(m, part[b * 128 + tid]);
    hmax[tid] = m;
    __syncthreads();
    if (tid < 10) {
        float sacc = b2[tid];
        for (int c = 0; c < 128; c++) sacc += hmax[c] * W2[c * 10 + tid];
        out[tid] = sacc;
    }
}

extern "C" void kernel_launch(void* const* d_in, const int* in_sizes, int n_in,
                              void* d_out, int out_size, void* d_ws, size_t ws_size,
                              hipStream_t stream) {
    const float* x[3]     = {(const float*)d_in[0], (const float*)d_in[2], (const float*)d_in[4]};
    const int*   edges[3] = {(const int*)d_in[1], (const int*)d_in[3], (const int*)d_in[5]};
    const float* W1 = (const float*)d_in[6];
    const float* b1 = (const float*)d_in[7];
    const float* convW[3] = {(const float*)d_in[8], (const float*)d_in[12], (const float*)d_in[16]};
    const float* convb[3] = {(const float*)d_in[9], (const float*)d_in[13], (const float*)d_in[17]};
    const float* linW[3]  = {(const float*)d_in[10], (const float*)d_in[14], (const float*)d_in[18]};
    const float* linb[3]  = {(const float*)d_in[11], (const float*)d_in[15], (const float*)d_in[19]};
    const float* W2 = (const float*)d_in[20];
    const float* b2 = (const float*)d_in[21];

    float* ws   = (float*)d_ws;
    float* B3   = ws;                  // 98304
    float* v3   = B3 + 98304;          // 384
    float* c3   = v3 + 384;            // 384
    float* M    = c3 + 384;            // 49152
    float* dinv = M + 49152;           // NN
    float* svb  = dinv + NN;           // NN
    float* part = svb + NN;            // 32768
    int*   deg  = (int*)(part + 32768);     // NN (reused as cursor)
    int*   offs = deg + NN;                 // NN+4
    int*   partial = offs + NN + 4;         // 128
    int*   sorted_src = partial + 128;      // EE
    __hip_bfloat16* Bzr = (__hip_bfloat16*)(sorted_src + EE);   // 65536
    __hip_bfloat16* Bh  = Bzr + 65536;                          // 32768
    __hip_bfloat16* ybf = Bh + 32768;                           // NN*128
    __hip_bfloat16* Hbf = ybf + (size_t)NN * 128;               // NN*128
    __hip_bfloat16* xs  = Hbf + (size_t)NN * 128;               // NN*128
    float* H = (float*)(xs + (size_t)NN * 128);                 // NN*128 f32
    // total ~137 MB

    prep1<<<192, 256, 0, stream>>>(convW[0], convW[1], convW[2],
                                   linW[0], linW[1], linW[2], M);
    prep2<<<384, 256, 0, stream>>>(W1, M, linW[0], linW[1], linW[2], B3);
    prep3<<<2, 256, 0, stream>>>(b1, M, convb[0], convb[1], convb[2],
                                 linW[0], linW[1], linW[2],
                                 linb[0], linb[1], linb[2], v3, c3);
    pack_zr<<<256, 256, 0, stream>>>(B3, Bzr);
    pack_h<<<128, 256, 0, stream>>>(B3, Bh);

    hipMemsetAsync(H, 0, (size_t)NN * 128 * sizeof(float), stream);
    hipMemsetAsync(Hbf, 0, (size_t)NN * 128 * sizeof(__hip_bfloat16), stream);

    for (int t = 0; t < 3; t++) {
        const int* src = edges[t];
        const int* dst = edges[t] + EE;

        hipMemsetAsync(deg, 0, NN * sizeof(int), stream);
        hist_kernel<<<2048, 256, 0, stream>>>(dst, deg);
        dinv_kernel<<<(NN + 255) / 256, 256, 0, stream>>>(deg, dinv);
        xscale_bf<<<12500, 256, 0, stream>>>(x[t], dinv, xs);
        scan_local<<<SCAN_NB, SCAN_B, 0, stream>>>(deg, offs, partial);
        scan_carry<<<1, 64, 0, stream>>>(partial, offs);
        scan_add<<<SCAN_NB, SCAN_B, 0, stream>>>(offs, partial);
        hipMemsetAsync(deg, 0, NN * sizeof(int), stream);  // deg -> cursor
        bucket_fill<<<2048, 256, 0, stream>>>(src, dst, offs, deg, sorted_src);
        gather_agg<<<25000, 256, 0, stream>>>(sorted_src, offs, xs, dinv, ybf, svb);

        gate_fused<<<640, 512, 0, stream>>>(ybf, Hbf, H, Bzr, Bh, v3, c3, svb, Hbf);
    }

    maxpool_partial<<<256, 128, 0, stream>>>(H, part);
    final_out<<<1, 128, 0, stream>>>(part, W2, b2, (float*)d_out);
}

// Round 8
// 1213.164 us; speedup vs baseline: 4.8283x; 1.1420x over previous
//
#include <hip/hip_runtime.h>
#include <hip/hip_bf16.h>
#include <math.h>

#define NN 100000
#define EE 1600000
#define SCAN_B 1024
#define SCAN_NB 98   // ceil(100000/1024)
#define NTILES 3125  // NN / 32 exactly

typedef __attribute__((ext_vector_type(8))) short bfrag;   // 8 bf16 = 4 VGPR
typedef __attribute__((ext_vector_type(4))) float facc;    // 4 f32 acc

__device__ __forceinline__ float bflo(unsigned u) {
    return __uint_as_float((u & 0xffffu) << 16);
}
__device__ __forceinline__ float bfhi(unsigned u) {
    return __uint_as_float(u & 0xffff0000u);
}
__device__ __forceinline__ unsigned short f2bf(float f) {
    __hip_bfloat16 b = __float2bfloat16(f);
    return *(unsigned short*)&b;
}

// ---------------------------------------------------------------------------
// Weight folding:  M_g = convW_g @ linW_g[0:128,:]        (128x128)
//                  B3_g = [ W1 @ M_g ; linW_g[128:256,:] ] (256x128)
//                  v_g = b1 @ M_g ; c_g = convb_g @ linW_g[0:128,:] + linb_g
// Gate pre-activation: a_g = [y | H] @ B3_g + s*v_g + c_g
// y = Norm(x), s = Norm(1), Norm = D^-1/2 (A+I) D^-1/2
// ---------------------------------------------------------------------------
__global__ void prep1(const float* __restrict__ Wcz, const float* __restrict__ Wcr,
                      const float* __restrict__ Wch,
                      const float* __restrict__ Wlz, const float* __restrict__ Wlr,
                      const float* __restrict__ Wlh,
                      float* __restrict__ M) {
    int idx = blockIdx.x * 256 + threadIdx.x;   // 3*16384
    int g = idx >> 14, r = idx & 16383;
    int i = r >> 7, j = r & 127;
    const float* Wc = g == 0 ? Wcz : (g == 1 ? Wcr : Wch);
    const float* Wl = g == 0 ? Wlz : (g == 1 ? Wlr : Wlh);
    float s = 0.f;
    for (int m = 0; m < 128; m++) s += Wc[i * 128 + m] * Wl[m * 128 + j];
    M[idx] = s;
}

__global__ void prep2(const float* __restrict__ W1, const float* __restrict__ M,
                      const float* __restrict__ Wlz, const float* __restrict__ Wlr,
                      const float* __restrict__ Wlh,
                      float* __restrict__ B) {
    int idx = blockIdx.x * 256 + threadIdx.x;  // 3*256*128
    int g = idx >> 15, r = idx & 32767;
    int k = r >> 7, j = r & 127;
    float o;
    if (k < 128) {
        const float* Mg = M + g * 16384;
        float sacc = 0.f;
        for (int m = 0; m < 128; m++) sacc += W1[k * 128 + m] * Mg[m * 128 + j];
        o = sacc;
    } else {
        const float* Wl = g == 0 ? Wlz : (g == 1 ? Wlr : Wlh);
        o = Wl[k * 128 + j];
    }
    B[idx] = o;
}

__global__ void prep3(const float* __restrict__ b1, const float* __restrict__ M,
                      const float* __restrict__ bcz, const float* __restrict__ bcr,
                      const float* __restrict__ bch,
                      const float* __restrict__ Wlz, const float* __restrict__ Wlr,
                      const float* __restrict__ Wlh,
                      const float* __restrict__ blz, const float* __restrict__ blr,
                      const float* __restrict__ blh,
                      float* __restrict__ v, float* __restrict__ c) {
    int idx = blockIdx.x * 256 + threadIdx.x;
    if (idx >= 384) return;
    int g = idx >> 7, j = idx & 127;
    const float* Mg = M + g * 16384;
    float sv = 0.f;
    for (int m = 0; m < 128; m++) sv += b1[m] * Mg[m * 128 + j];
    v[idx] = sv;
    const float* bc = g == 0 ? bcz : (g == 1 ? bcr : bch);
    const float* Wl = g == 0 ? Wlz : (g == 1 ? Wlr : Wlh);
    const float* bl = g == 0 ? blz : (g == 1 ? blr : blh);
    float sc = bl[j];
    for (int m = 0; m < 128; m++) sc += bc[m] * Wl[m * 128 + j];
    c[idx] = sc;
}

// Frag-packed bf16 B for MFMA. Frag f=(gcf*8+kf): elem (lane,i) =
// B3[g][kf*32+(lane>>4)*8+i][(gcf&7)*16+(lane&15)], g = gcf>>3 (zr) or 2 (h).
__global__ void pack_zr(const float* __restrict__ B3, __hip_bfloat16* __restrict__ out) {
    int idx = blockIdx.x * 256 + threadIdx.x;  // 65536
    if (idx >= 65536) return;
    int i = idx & 7, lane = (idx >> 3) & 63, kf = (idx >> 9) & 7, gcf = idx >> 12;
    int g = gcf >> 3;
    int j = (gcf & 7) * 16 + (lane & 15);
    int k = kf * 32 + (lane >> 4) * 8 + i;
    out[idx] = __float2bfloat16(B3[g * 32768 + k * 128 + j]);
}

__global__ void pack_h(const float* __restrict__ B3, __hip_bfloat16* __restrict__ out) {
    int idx = blockIdx.x * 256 + threadIdx.x;  // 32768
    if (idx >= 32768) return;
    int i = idx & 7, lane = (idx >> 3) & 63, kf = (idx >> 9) & 7, cf = idx >> 12;
    int j = cf * 16 + (lane & 15);
    int k = kf * 32 + (lane >> 4) * 8 + i;
    out[idx] = __float2bfloat16(B3[2 * 32768 + k * 128 + j]);
}

// ---------------------------------------------------------------------------
// CSR build: histogram -> exclusive scan (+dinv, +cursor-zero) -> bucket fill
// ---------------------------------------------------------------------------
__global__ void hist_kernel(const int* __restrict__ dst, int* __restrict__ deg) {
    int i = blockIdx.x * blockDim.x + threadIdx.x;
    int stride = gridDim.x * blockDim.x;
    for (; i < EE; i += stride) atomicAdd(&deg[dst[i]], 1);
}

// local exclusive scan + partials; also dinv[i] = rsqrt(deg+1) and deg := 0
__global__ void scan_local(int* __restrict__ deg, int* __restrict__ offs,
                           int* __restrict__ partial, float* __restrict__ dinv) {
    __shared__ int sm[SCAN_B];
    int t = threadIdx.x;
    int i = blockIdx.x * SCAN_B + t;
    int v = (i < NN) ? deg[i] : 0;
    sm[t] = v;
    __syncthreads();
    #pragma unroll
    for (int off = 1; off < SCAN_B; off <<= 1) {
        int x = (t >= off) ? sm[t - off] : 0;
        __syncthreads();
        sm[t] += x;
        __syncthreads();
    }
    if (i < NN) {
        offs[i] = sm[t] - v;
        dinv[i] = rsqrtf((float)v + 1.0f);  // +1 = self loop
        deg[i] = 0;                          // becomes bucket_fill cursor
    }
    if (t == SCAN_B - 1) partial[blockIdx.x] = sm[t];
}

__global__ void scan_carry(int* __restrict__ partial, int* __restrict__ offs) {
    if (threadIdx.x == 0) {
        int carry = 0;
        for (int b = 0; b < SCAN_NB; b++) {
            int p = partial[b];
            partial[b] = carry;
            carry += p;
        }
        offs[NN] = carry;  // == EE
    }
}

__global__ void scan_add(int* __restrict__ offs, const int* __restrict__ partial) {
    int i = blockIdx.x * SCAN_B + threadIdx.x;
    if (i < NN) offs[i] += partial[blockIdx.x];
}

// xs[i,:] = bf16(dinv[i] * x[i,:])
__global__ void xscale_bf(const float* __restrict__ x, const float* __restrict__ dinv,
                          __hip_bfloat16* __restrict__ xs) {
    int idx = blockIdx.x * 256 + threadIdx.x;   // NN*32 threads, 4 elems each
    int row = idx >> 5, c4 = (idx & 31) * 4;
    float di = dinv[row];
    float4 v = *(const float4*)&x[(size_t)row * 128 + c4];
    uint2 o;
    o.x = (unsigned)f2bf(di * v.x) | ((unsigned)f2bf(di * v.y) << 16);
    o.y = (unsigned)f2bf(di * v.z) | ((unsigned)f2bf(di * v.w) << 16);
    *(uint2*)&xs[(size_t)row * 128 + c4] = o;
}

__global__ void bucket_fill(const int* __restrict__ src, const int* __restrict__ dst,
                            const int* __restrict__ offs, int* __restrict__ cursor,
                            int* __restrict__ sorted_src) {
    int i = blockIdx.x * blockDim.x + threadIdx.x;
    int stride = gridDim.x * blockDim.x;
    for (; i < EE; i += stride) {
        int d = dst[i];
        int pos = offs[d] + atomicAdd(&cursor[d], 1);
        sorted_src[pos] = src[i];
    }
}

// ---------------------------------------------------------------------------
// Gather aggregation: one wave per dst node, FOUR edges per iteration
// (quarter q = lane>>4 handles edge e+q; 16 lanes x uint4 = full 256B row).
// y_i = dinv_i * ( sum_{s in N(i)} xs_s + xs_i ),  xs = dinv*x in bf16
// sv_i = dinv_i * ( sum dinv_s + dinv_i )
// ---------------------------------------------------------------------------
__global__ void gather_agg(const int* __restrict__ sorted_src,
                           const int* __restrict__ offs,
                           const __hip_bfloat16* __restrict__ xs,
                           const float* __restrict__ dinv,
                           __hip_bfloat16* __restrict__ y, float* __restrict__ sv) {
    const int lane = threadIdx.x & 63;
    const int q = lane >> 4;
    const int l16 = lane & 15;
    const int node = blockIdx.x * 4 + (threadIdx.x >> 6);
    if (node >= NN) return;
    const int beg = offs[node], end = offs[node + 1];

    float a[8] = {0.f, 0.f, 0.f, 0.f, 0.f, 0.f, 0.f, 0.f};
    float sacc = 0.f;
    for (int e = beg; e < end; e += 4) {
        int ei = e + q;
        bool ok = ei < end;
        int s = sorted_src[ok ? ei : e];
        float w = ok ? 1.f : 0.f;
        uint4 raw = *(const uint4*)&xs[(size_t)s * 128 + l16 * 8];
        a[0] += w * bflo(raw.x); a[1] += w * bfhi(raw.x);
        a[2] += w * bflo(raw.y); a[3] += w * bfhi(raw.y);
        a[4] += w * bflo(raw.z); a[5] += w * bfhi(raw.z);
        a[6] += w * bflo(raw.w); a[7] += w * bfhi(raw.w);
        sacc += w * dinv[s];
    }
    #pragma unroll
    for (int i = 0; i < 8; i++) {
        a[i] += __shfl_xor(a[i], 16);
        a[i] += __shfl_xor(a[i], 32);
    }
    sacc += __shfl_xor(sacc, 16);
    sacc += __shfl_xor(sacc, 32);

    const float di = dinv[node];
    if (q == 0) {
        uint4 raw = *(const uint4*)&xs[(size_t)node * 128 + l16 * 8];
        float o0 = di * (a[0] + bflo(raw.x)), o1 = di * (a[1] + bfhi(raw.x));
        float o2 = di * (a[2] + bflo(raw.y)), o3 = di * (a[3] + bfhi(raw.y));
        float o4 = di * (a[4] + bflo(raw.z)), o5 = di * (a[5] + bfhi(raw.z));
        float o6 = di * (a[6] + bflo(raw.w)), o7 = di * (a[7] + bfhi(raw.w));
        uint4 o;
        o.x = (unsigned)f2bf(o0) | ((unsigned)f2bf(o1) << 16);
        o.y = (unsigned)f2bf(o2) | ((unsigned)f2bf(o3) << 16);
        o.z = (unsigned)f2bf(o4) | ((unsigned)f2bf(o5) << 16);
        o.w = (unsigned)f2bf(o6) | ((unsigned)f2bf(o7) << 16);
        *(uint4*)&y[(size_t)node * 128 + l16 * 8] = o;
    }
    if (lane == 0) sv[node] = di * (sacc + di);
}

// ---------------------------------------------------------------------------
// Fully fused gate kernel, bf16-only H. Block = 8 waves; wave owns 16 cols.
// Per 32-row tile: a_z,a_r MFMA -> z,r regs -> Hr via swizzled LDS (double-
// buffered, ONE sync/tile) -> a_h MFMA -> H_new (bf16, in place).
// ---------------------------------------------------------------------------
__launch_bounds__(512, 2)
__global__ void gate_fused(const __hip_bfloat16* __restrict__ ybf,
                           __hip_bfloat16* __restrict__ Hbf,
                           const __hip_bfloat16* __restrict__ Bzr,
                           const __hip_bfloat16* __restrict__ Bh,
                           const float* __restrict__ v3, const float* __restrict__ c3,
                           const float* __restrict__ svec) {
    __shared__ __hip_bfloat16 hrT[2][32 * 128];   // 16 KB, double-buffered
    const int lane = threadIdx.x & 63;
    const int wid = threadIdx.x >> 6;             // col-frag 0..7
    const int l15 = lane & 15, lk = lane >> 4;

    bfrag Bz[8], Br[8], Bhh[8];
    #pragma unroll
    for (int kf = 0; kf < 8; kf++) {
        Bz[kf]  = *(const bfrag*)&Bzr[(size_t)(((0 * 8 + wid) * 8 + kf) * 64 + lane) * 8];
        Br[kf]  = *(const bfrag*)&Bzr[(size_t)(((1 * 8 + wid) * 8 + kf) * 64 + lane) * 8];
        Bhh[kf] = *(const bfrag*)&Bh[(size_t)((wid * 8 + kf) * 64 + lane) * 8];
    }
    const int col = wid * 16 + l15;
    const float vz = v3[col],       cz = c3[col];
    const float vr = v3[128 + col], cr = c3[128 + col];
    const float vh = v3[256 + col], ch = c3[256 + col];

    int par = 0;
    for (int tile = blockIdx.x; tile < NTILES; tile += gridDim.x, par ^= 1) {
        const int rowBase = tile * 32;

        bfrag ay[4][2], ahf[4][2];
        #pragma unroll
        for (int kf = 0; kf < 4; kf++) {
            const int koff = kf * 32 + lk * 8;
            #pragma unroll
            for (int rf = 0; rf < 2; rf++) {
                const size_t rowoff = (size_t)(rowBase + rf * 16 + l15) * 128 + koff;
                ay[kf][rf]  = *(const bfrag*)&ybf[rowoff];
                ahf[kf][rf] = *(const bfrag*)&Hbf[rowoff];
            }
        }

        facc az[2], ar[2];
        #pragma unroll
        for (int rf = 0; rf < 2; rf++) { az[rf] = (facc){0.f,0.f,0.f,0.f}; ar[rf] = (facc){0.f,0.f,0.f,0.f}; }

        #pragma unroll
        for (int kf = 0; kf < 4; kf++)
            #pragma unroll
            for (int rf = 0; rf < 2; rf++) {
                az[rf] = __builtin_amdgcn_mfma_f32_16x16x32_bf16(ay[kf][rf],  Bz[kf],     az[rf], 0, 0, 0);
                ar[rf] = __builtin_amdgcn_mfma_f32_16x16x32_bf16(ay[kf][rf],  Br[kf],     ar[rf], 0, 0, 0);
                az[rf] = __builtin_amdgcn_mfma_f32_16x16x32_bf16(ahf[kf][rf], Bz[kf + 4], az[rf], 0, 0, 0);
                ar[rf] = __builtin_amdgcn_mfma_f32_16x16x32_bf16(ahf[kf][rf], Br[kf + 4], ar[rf], 0, 0, 0);
            }

        // epilogue z/r: z,H kept in regs; Hr -> swizzled LDS (buffer `par`)
        float zv[2][4], Hf[2][4];
        #pragma unroll
        for (int rf = 0; rf < 2; rf++) {
            #pragma unroll
            for (int r = 0; r < 4; r++) {
                const int lrow = rf * 16 + lk * 4 + r;
                const int row = rowBase + lrow;
                const float sr = svec[row];
                const float azv = az[rf][r] + sr * vz + cz;
                const float arv = ar[rf][r] + sr * vr + cr;
                const float z  = 1.f / (1.f + expf(-azv));
                const float rr = 1.f / (1.f + expf(-arv));
                const float hf = __bfloat162float(Hbf[(size_t)row * 128 + col]);
                zv[rf][r] = z;
                Hf[rf][r] = hf;
                const int baddr = lrow * 256 + ((col * 2) ^ ((lrow & 7) << 4));
                *(__hip_bfloat16*)((char*)hrT[par] + baddr) = __float2bfloat16(hf * rr);
            }
        }

        // h-gate upper-K MFMAs (independent of LDS) before the barrier
        facc ah[2];
        #pragma unroll
        for (int rf = 0; rf < 2; rf++) ah[rf] = (facc){0.f,0.f,0.f,0.f};
        #pragma unroll
        for (int kf = 0; kf < 4; kf++)
            #pragma unroll
            for (int rf = 0; rf < 2; rf++)
                ah[rf] = __builtin_amdgcn_mfma_f32_16x16x32_bf16(ay[kf][rf], Bhh[kf], ah[rf], 0, 0, 0);

        __syncthreads();   // Hr tile visible

        #pragma unroll
        for (int kf = 0; kf < 4; kf++) {
            const int koff = kf * 32 + lk * 8;
            #pragma unroll
            for (int rf = 0; rf < 2; rf++) {
                const int lrow = rf * 16 + l15;
                const int baddr = lrow * 256 + ((koff * 2) ^ ((lrow & 7) << 4));
                bfrag hrf = *(const bfrag*)((char*)hrT[par] + baddr);
                ah[rf] = __builtin_amdgcn_mfma_f32_16x16x32_bf16(hrf, Bhh[kf + 4], ah[rf], 0, 0, 0);
            }
        }

        // epilogue h: H_new = z*H + (1-z)*tanh(a_h), bf16 in place
        #pragma unroll
        for (int rf = 0; rf < 2; rf++) {
            #pragma unroll
            for (int r = 0; r < 4; r++) {
                const int row = rowBase + rf * 16 + lk * 4 + r;
                const float sr = svec[row];
                const float av = ah[rf][r] + sr * vh + ch;
                const float ht = tanhf(av);
                const float z = zv[rf][r];
                const float hn = z * Hf[rf][r] + (1.f - z) * ht;
                Hbf[(size_t)row * 128 + col] = __float2bfloat16(hn);
            }
        }
    }
}

// ---------------------------------------------------------------------------
__global__ void maxpool_partial(const __hip_bfloat16* __restrict__ H,
                                float* __restrict__ part) {
    int c = threadIdx.x;  // 128
    float m = -1e30f;
    for (int r = blockIdx.x; r < NN; r += gridDim.x)
        m = fmaxf(m, __bfloat162float(H[(size_t)r * 128 + c]));
    part[blockIdx.x * 128 + c] = m;
}

__global__ void final_out(const float* __restrict__ part, const float* __restrict__ W2,
                          const float* __restrict__ b2, float* __restrict__ out) {
    __shared__ float hmax[128];
    int tid = threadIdx.x;  // 128
    float m = -1e30f;
    for (int b = 0; b < 256; b++) m = fmaxf(m, part[b * 128 + tid]);
    hmax[tid] = m;
    __syncthreads();
    if (tid < 10) {
        float sacc = b2[tid];
        for (int c = 0; c < 128; c++) sacc += hmax[c] * W2[c * 10 + tid];
        out[tid] = sacc;
    }
}

extern "C" void kernel_launch(void* const* d_in, const int* in_sizes, int n_in,
                              void* d_out, int out_size, void* d_ws, size_t ws_size,
                              hipStream_t stream) {
    const float* x[3]     = {(const float*)d_in[0], (const float*)d_in[2], (const float*)d_in[4]};
    const int*   edges[3] = {(const int*)d_in[1], (const int*)d_in[3], (const int*)d_in[5]};
    const float* W1 = (const float*)d_in[6];
    const float* b1 = (const float*)d_in[7];
    const float* convW[3] = {(const float*)d_in[8], (const float*)d_in[12], (const float*)d_in[16]};
    const float* convb[3] = {(const float*)d_in[9], (const float*)d_in[13], (const float*)d_in[17]};
    const float* linW[3]  = {(const float*)d_in[10], (const float*)d_in[14], (const float*)d_in[18]};
    const float* linb[3]  = {(const float*)d_in[11], (const float*)d_in[15], (const float*)d_in[19]};
    const float* W2 = (const float*)d_in[20];
    const float* b2 = (const float*)d_in[21];

    float* ws   = (float*)d_ws;
    float* B3   = ws;                  // 98304
    float* v3   = B3 + 98304;          // 384
    float* c3   = v3 + 384;            // 384
    float* M    = c3 + 384;            // 49152
    float* dinv = M + 49152;           // NN
    float* svb  = dinv + NN;           // NN
    float* part = svb + NN;            // 32768
    int*   deg  = (int*)(part + 32768);     // NN (reused as cursor)
    int*   offs = deg + NN;                 // NN+4
    int*   partial = offs + NN + 4;         // 128
    int*   sorted_src = partial + 128;      // EE
    __hip_bfloat16* Bzr = (__hip_bfloat16*)(sorted_src + EE);   // 65536
    __hip_bfloat16* Bh  = Bzr + 65536;                          // 32768
    __hip_bfloat16* ybf = Bh + 32768;                           // NN*128
    __hip_bfloat16* Hbf = ybf + (size_t)NN * 128;               // NN*128
    __hip_bfloat16* xs  = Hbf + (size_t)NN * 128;               // NN*128
    // total ~86 MB

    prep1<<<192, 256, 0, stream>>>(convW[0], convW[1], convW[2],
                                   linW[0], linW[1], linW[2], M);
    prep2<<<384, 256, 0, stream>>>(W1, M, linW[0], linW[1], linW[2], B3);
    prep3<<<2, 256, 0, stream>>>(b1, M, convb[0], convb[1], convb[2],
                                 linW[0], linW[1], linW[2],
                                 linb[0], linb[1], linb[2], v3, c3);
    pack_zr<<<256, 256, 0, stream>>>(B3, Bzr);
    pack_h<<<128, 256, 0, stream>>>(B3, Bh);

    hipMemsetAsync(Hbf, 0, (size_t)NN * 128 * sizeof(__hip_bfloat16), stream);

    for (int t = 0; t < 3; t++) {
        const int* src = edges[t];
        const int* dst = edges[t] + EE;

        hipMemsetAsync(deg, 0, NN * sizeof(int), stream);
        hist_kernel<<<2048, 256, 0, stream>>>(dst, deg);
        scan_local<<<SCAN_NB, SCAN_B, 0, stream>>>(deg, offs, partial, dinv);
        scan_carry<<<1, 64, 0, stream>>>(partial, offs);
        scan_add<<<SCAN_NB, SCAN_B, 0, stream>>>(offs, partial);
        xscale_bf<<<12500, 256, 0, stream>>>(x[t], dinv, xs);
        bucket_fill<<<2048, 256, 0, stream>>>(src, dst, offs, deg, sorted_src);
        gather_agg<<<25000, 256, 0, stream>>>(sorted_src, offs, xs, dinv, ybf, svb);

        gate_fused<<<512, 512, 0, stream>>>(ybf, Hbf, Bzr, Bh, v3, c3, svb);
    }

    maxpool_partial<<<256, 128, 0, stream>>>(Hbf, part);
    final_out<<<1, 128, 0, stream>>>(part, W2, b2, (float*)d_out);
}

// Round 9
// 1174.993 us; speedup vs baseline: 4.9852x; 1.0325x over previous
//
#include <hip/hip_runtime.h>
#include <hip/hip_bf16.h>
#include <math.h>

#define NN 100000
#define EE 1600000
#define SCAN_B 1024
#define SCAN_NB 98   // ceil(100000/1024)
#define NTILES 3125  // NN / 32 exactly
#define MPGRID 512   // maxpool partial blocks

typedef __attribute__((ext_vector_type(8))) short bfrag;   // 8 bf16 = 4 VGPR
typedef __attribute__((ext_vector_type(4))) float facc;    // 4 f32 acc

__device__ __forceinline__ float bflo(unsigned u) {
    return __uint_as_float((u & 0xffffu) << 16);
}
__device__ __forceinline__ float bfhi(unsigned u) {
    return __uint_as_float(u & 0xffff0000u);
}
__device__ __forceinline__ unsigned short f2bf(float f) {
    __hip_bfloat16 b = __float2bfloat16(f);
    return *(unsigned short*)&b;
}

// ---------------------------------------------------------------------------
// Weight folding:  M_g = convW_g @ linW_g[0:128,:]        (128x128)
//                  B3_g = [ W1 @ M_g ; linW_g[128:256,:] ] (256x128)
//                  v_g = b1 @ M_g ; c_g = convb_g @ linW_g[0:128,:] + linb_g
// Gate pre-activation: a_g = [y | H] @ B3_g + s*v_g + c_g
// y = Norm(x), s = Norm(1), Norm = D^-1/2 (A+I) D^-1/2
// ---------------------------------------------------------------------------
__global__ void prep1(const float* __restrict__ Wcz, const float* __restrict__ Wcr,
                      const float* __restrict__ Wch,
                      const float* __restrict__ Wlz, const float* __restrict__ Wlr,
                      const float* __restrict__ Wlh,
                      float* __restrict__ M) {
    int idx = blockIdx.x * 256 + threadIdx.x;   // 3*16384
    int g = idx >> 14, r = idx & 16383;
    int i = r >> 7, j = r & 127;
    const float* Wc = g == 0 ? Wcz : (g == 1 ? Wcr : Wch);
    const float* Wl = g == 0 ? Wlz : (g == 1 ? Wlr : Wlh);
    float s = 0.f;
    for (int m = 0; m < 128; m++) s += Wc[i * 128 + m] * Wl[m * 128 + j];
    M[idx] = s;
}

__global__ void prep2(const float* __restrict__ W1, const float* __restrict__ M,
                      const float* __restrict__ Wlz, const float* __restrict__ Wlr,
                      const float* __restrict__ Wlh,
                      float* __restrict__ B) {
    int idx = blockIdx.x * 256 + threadIdx.x;  // 3*256*128
    int g = idx >> 15, r = idx & 32767;
    int k = r >> 7, j = r & 127;
    float o;
    if (k < 128) {
        const float* Mg = M + g * 16384;
        float sacc = 0.f;
        for (int m = 0; m < 128; m++) sacc += W1[k * 128 + m] * Mg[m * 128 + j];
        o = sacc;
    } else {
        const float* Wl = g == 0 ? Wlz : (g == 1 ? Wlr : Wlh);
        o = Wl[k * 128 + j];
    }
    B[idx] = o;
}

__global__ void prep3(const float* __restrict__ b1, const float* __restrict__ M,
                      const float* __restrict__ bcz, const float* __restrict__ bcr,
                      const float* __restrict__ bch,
                      const float* __restrict__ Wlz, const float* __restrict__ Wlr,
                      const float* __restrict__ Wlh,
                      const float* __restrict__ blz, const float* __restrict__ blr,
                      const float* __restrict__ blh,
                      float* __restrict__ v, float* __restrict__ c) {
    int idx = blockIdx.x * 256 + threadIdx.x;
    if (idx >= 384) return;
    int g = idx >> 7, j = idx & 127;
    const float* Mg = M + g * 16384;
    float sv = 0.f;
    for (int m = 0; m < 128; m++) sv += b1[m] * Mg[m * 128 + j];
    v[idx] = sv;
    const float* bc = g == 0 ? bcz : (g == 1 ? bcr : bch);
    const float* Wl = g == 0 ? Wlz : (g == 1 ? Wlr : Wlh);
    const float* bl = g == 0 ? blz : (g == 1 ? blr : blh);
    float sc = bl[j];
    for (int m = 0; m < 128; m++) sc += bc[m] * Wl[m * 128 + j];
    c[idx] = sc;
}

// Frag-packed bf16 B for MFMA. Frag f=(gcf*8+kf): elem (lane,i) =
// B3[g][kf*32+(lane>>4)*8+i][(gcf&7)*16+(lane&15)], g = gcf>>3 (zr) or 2 (h).
__global__ void pack_zr(const float* __restrict__ B3, __hip_bfloat16* __restrict__ out) {
    int idx = blockIdx.x * 256 + threadIdx.x;  // 65536
    if (idx >= 65536) return;
    int i = idx & 7, lane = (idx >> 3) & 63, kf = (idx >> 9) & 7, gcf = idx >> 12;
    int g = gcf >> 3;
    int j = (gcf & 7) * 16 + (lane & 15);
    int k = kf * 32 + (lane >> 4) * 8 + i;
    out[idx] = __float2bfloat16(B3[g * 32768 + k * 128 + j]);
}

__global__ void pack_h(const float* __restrict__ B3, __hip_bfloat16* __restrict__ out) {
    int idx = blockIdx.x * 256 + threadIdx.x;  // 32768
    if (idx >= 32768) return;
    int i = idx & 7, lane = (idx >> 3) & 63, kf = (idx >> 9) & 7, cf = idx >> 12;
    int j = cf * 16 + (lane & 15);
    int k = kf * 32 + (lane >> 4) * 8 + i;
    out[idx] = __float2bfloat16(B3[2 * 32768 + k * 128 + j]);
}

// ---------------------------------------------------------------------------
// CSR build: histogram -> exclusive scan (+dinv, +cursor-zero) -> bucket fill
// ---------------------------------------------------------------------------
__global__ void hist_kernel(const int* __restrict__ dst, int* __restrict__ deg) {
    int i = blockIdx.x * blockDim.x + threadIdx.x;
    int stride = gridDim.x * blockDim.x;
    for (; i < EE; i += stride) atomicAdd(&deg[dst[i]], 1);
}

// local exclusive scan + partials; also dinv[i] = rsqrt(deg+1) and deg := 0
__global__ void scan_local(int* __restrict__ deg, int* __restrict__ offs,
                           int* __restrict__ partial, float* __restrict__ dinv) {
    __shared__ int sm[SCAN_B];
    int t = threadIdx.x;
    int i = blockIdx.x * SCAN_B + t;
    int v = (i < NN) ? deg[i] : 0;
    sm[t] = v;
    __syncthreads();
    #pragma unroll
    for (int off = 1; off < SCAN_B; off <<= 1) {
        int x = (t >= off) ? sm[t - off] : 0;
        __syncthreads();
        sm[t] += x;
        __syncthreads();
    }
    if (i < NN) {
        offs[i] = sm[t] - v;
        dinv[i] = rsqrtf((float)v + 1.0f);  // +1 = self loop
        deg[i] = 0;                          // becomes bucket_fill cursor
    }
    if (t == SCAN_B - 1) partial[blockIdx.x] = sm[t];
}

// parallel exclusive scan of the 98 block partials (one 128-thread block)
__global__ void scan_carry(int* __restrict__ partial, int* __restrict__ offs) {
    __shared__ int sm[128];
    int t = threadIdx.x;
    int v = (t < SCAN_NB) ? partial[t] : 0;
    sm[t] = v;
    __syncthreads();
    #pragma unroll
    for (int off = 1; off < 128; off <<= 1) {
        int x = (t >= off) ? sm[t - off] : 0;
        __syncthreads();
        sm[t] += x;
        __syncthreads();
    }
    if (t < SCAN_NB) partial[t] = sm[t] - v;   // exclusive
    if (t == SCAN_NB - 1) offs[NN] = sm[t];    // == EE
}

__global__ void scan_add(int* __restrict__ offs, const int* __restrict__ partial) {
    int i = blockIdx.x * SCAN_B + threadIdx.x;
    if (i < NN) offs[i] += partial[blockIdx.x];
}

// xs[i,:] = bf16(dinv[i] * x[i,:])
__global__ void xscale_bf(const float* __restrict__ x, const float* __restrict__ dinv,
                          __hip_bfloat16* __restrict__ xs) {
    int idx = blockIdx.x * 256 + threadIdx.x;   // NN*32 threads, 4 elems each
    int row = idx >> 5, c4 = (idx & 31) * 4;
    float di = dinv[row];
    float4 v = *(const float4*)&x[(size_t)row * 128 + c4];
    uint2 o;
    o.x = (unsigned)f2bf(di * v.x) | ((unsigned)f2bf(di * v.y) << 16);
    o.y = (unsigned)f2bf(di * v.z) | ((unsigned)f2bf(di * v.w) << 16);
    *(uint2*)&xs[(size_t)row * 128 + c4] = o;
}

__global__ void bucket_fill(const int* __restrict__ src, const int* __restrict__ dst,
                            const int* __restrict__ offs, int* __restrict__ cursor,
                            int* __restrict__ sorted_src) {
    int i = blockIdx.x * blockDim.x + threadIdx.x;
    int stride = gridDim.x * blockDim.x;
    for (; i < EE; i += stride) {
        int d = dst[i];
        int pos = offs[d] + atomicAdd(&cursor[d], 1);
        sorted_src[pos] = src[i];
    }
}

// ---------------------------------------------------------------------------
// Gather aggregation: one wave per dst node, FOUR edges per iteration
// (quarter q = lane>>4 handles edge e+q; 16 lanes x uint4 = full 256B row).
// ---------------------------------------------------------------------------
__global__ void gather_agg(const int* __restrict__ sorted_src,
                           const int* __restrict__ offs,
                           const __hip_bfloat16* __restrict__ xs,
                           const float* __restrict__ dinv,
                           __hip_bfloat16* __restrict__ y, float* __restrict__ sv) {
    const int lane = threadIdx.x & 63;
    const int q = lane >> 4;
    const int l16 = lane & 15;
    const int node = blockIdx.x * 4 + (threadIdx.x >> 6);
    if (node >= NN) return;
    const int beg = offs[node], end = offs[node + 1];

    float a[8] = {0.f, 0.f, 0.f, 0.f, 0.f, 0.f, 0.f, 0.f};
    float sacc = 0.f;
    for (int e = beg; e < end; e += 4) {
        int ei = e + q;
        bool ok = ei < end;
        int s = sorted_src[ok ? ei : e];
        float w = ok ? 1.f : 0.f;
        uint4 raw = *(const uint4*)&xs[(size_t)s * 128 + l16 * 8];
        a[0] += w * bflo(raw.x); a[1] += w * bfhi(raw.x);
        a[2] += w * bflo(raw.y); a[3] += w * bfhi(raw.y);
        a[4] += w * bflo(raw.z); a[5] += w * bfhi(raw.z);
        a[6] += w * bflo(raw.w); a[7] += w * bfhi(raw.w);
        sacc += w * dinv[s];
    }
    #pragma unroll
    for (int i = 0; i < 8; i++) {
        a[i] += __shfl_xor(a[i], 16);
        a[i] += __shfl_xor(a[i], 32);
    }
    sacc += __shfl_xor(sacc, 16);
    sacc += __shfl_xor(sacc, 32);

    const float di = dinv[node];
    if (q == 0) {
        uint4 raw = *(const uint4*)&xs[(size_t)node * 128 + l16 * 8];
        float o0 = di * (a[0] + bflo(raw.x)), o1 = di * (a[1] + bfhi(raw.x));
        float o2 = di * (a[2] + bflo(raw.y)), o3 = di * (a[3] + bfhi(raw.y));
        float o4 = di * (a[4] + bflo(raw.z)), o5 = di * (a[5] + bfhi(raw.z));
        float o6 = di * (a[6] + bflo(raw.w)), o7 = di * (a[7] + bfhi(raw.w));
        uint4 o;
        o.x = (unsigned)f2bf(o0) | ((unsigned)f2bf(o1) << 16);
        o.y = (unsigned)f2bf(o2) | ((unsigned)f2bf(o3) << 16);
        o.z = (unsigned)f2bf(o4) | ((unsigned)f2bf(o5) << 16);
        o.w = (unsigned)f2bf(o6) | ((unsigned)f2bf(o7) << 16);
        *(uint4*)&y[(size_t)node * 128 + l16 * 8] = o;
    }
    if (lane == 0) sv[node] = di * (sacc + di);
}

// ---------------------------------------------------------------------------
// Fully fused gate kernel, bf16-only H. Block = 8 waves; wave owns 16 cols.
// Per 32-row tile: a_z,a_r MFMA -> z,r regs -> Hr via swizzled LDS (double-
// buffered, ONE sync/tile) -> a_h MFMA -> H_new (bf16, in place).
// ---------------------------------------------------------------------------
__launch_bounds__(512, 2)
__global__ void gate_fused(const __hip_bfloat16* __restrict__ ybf,
                           __hip_bfloat16* __restrict__ Hbf,
                           const __hip_bfloat16* __restrict__ Bzr,
                           const __hip_bfloat16* __restrict__ Bh,
                           const float* __restrict__ v3, const float* __restrict__ c3,
                           const float* __restrict__ svec) {
    __shared__ __hip_bfloat16 hrT[2][32 * 128];   // 16 KB, double-buffered
    const int lane = threadIdx.x & 63;
    const int wid = threadIdx.x >> 6;             // col-frag 0..7
    const int l15 = lane & 15, lk = lane >> 4;

    bfrag Bz[8], Br[8], Bhh[8];
    #pragma unroll
    for (int kf = 0; kf < 8; kf++) {
        Bz[kf]  = *(const bfrag*)&Bzr[(size_t)(((0 * 8 + wid) * 8 + kf) * 64 + lane) * 8];
        Br[kf]  = *(const bfrag*)&Bzr[(size_t)(((1 * 8 + wid) * 8 + kf) * 64 + lane) * 8];
        Bhh[kf] = *(const bfrag*)&Bh[(size_t)((wid * 8 + kf) * 64 + lane) * 8];
    }
    const int col = wid * 16 + l15;
    const float vz = v3[col],       cz = c3[col];
    const float vr = v3[128 + col], cr = c3[128 + col];
    const float vh = v3[256 + col], ch = c3[256 + col];

    int par = 0;
    for (int tile = blockIdx.x; tile < NTILES; tile += gridDim.x, par ^= 1) {
        const int rowBase = tile * 32;

        bfrag ay[4][2], ahf[4][2];
        #pragma unroll
        for (int kf = 0; kf < 4; kf++) {
            const int koff = kf * 32 + lk * 8;
            #pragma unroll
            for (int rf = 0; rf < 2; rf++) {
                const size_t rowoff = (size_t)(rowBase + rf * 16 + l15) * 128 + koff;
                ay[kf][rf]  = *(const bfrag*)&ybf[rowoff];
                ahf[kf][rf] = *(const bfrag*)&Hbf[rowoff];
            }
        }

        facc az[2], ar[2];
        #pragma unroll
        for (int rf = 0; rf < 2; rf++) { az[rf] = (facc){0.f,0.f,0.f,0.f}; ar[rf] = (facc){0.f,0.f,0.f,0.f}; }

        #pragma unroll
        for (int kf = 0; kf < 4; kf++)
            #pragma unroll
            for (int rf = 0; rf < 2; rf++) {
                az[rf] = __builtin_amdgcn_mfma_f32_16x16x32_bf16(ay[kf][rf],  Bz[kf],     az[rf], 0, 0, 0);
                ar[rf] = __builtin_amdgcn_mfma_f32_16x16x32_bf16(ay[kf][rf],  Br[kf],     ar[rf], 0, 0, 0);
                az[rf] = __builtin_amdgcn_mfma_f32_16x16x32_bf16(ahf[kf][rf], Bz[kf + 4], az[rf], 0, 0, 0);
                ar[rf] = __builtin_amdgcn_mfma_f32_16x16x32_bf16(ahf[kf][rf], Br[kf + 4], ar[rf], 0, 0, 0);
            }

        // epilogue z/r: z,H kept in regs; Hr -> swizzled LDS (buffer `par`)
        float zv[2][4], Hf[2][4];
        #pragma unroll
        for (int rf = 0; rf < 2; rf++) {
            #pragma unroll
            for (int r = 0; r < 4; r++) {
                const int lrow = rf * 16 + lk * 4 + r;
                const int row = rowBase + lrow;
                const float sr = svec[row];
                const float azv = az[rf][r] + sr * vz + cz;
                const float arv = ar[rf][r] + sr * vr + cr;
                const float z  = 1.f / (1.f + expf(-azv));
                const float rr = 1.f / (1.f + expf(-arv));
                const float hf = __bfloat162float(Hbf[(size_t)row * 128 + col]);
                zv[rf][r] = z;
                Hf[rf][r] = hf;
                const int baddr = lrow * 256 + ((col * 2) ^ ((lrow & 7) << 4));
                *(__hip_bfloat16*)((char*)hrT[par] + baddr) = __float2bfloat16(hf * rr);
            }
        }

        // h-gate upper-K MFMAs (independent of LDS) before the barrier
        facc ah[2];
        #pragma unroll
        for (int rf = 0; rf < 2; rf++) ah[rf] = (facc){0.f,0.f,0.f,0.f};
        #pragma unroll
        for (int kf = 0; kf < 4; kf++)
            #pragma unroll
            for (int rf = 0; rf < 2; rf++)
                ah[rf] = __builtin_amdgcn_mfma_f32_16x16x32_bf16(ay[kf][rf], Bhh[kf], ah[rf], 0, 0, 0);

        __syncthreads();   // Hr tile visible

        #pragma unroll
        for (int kf = 0; kf < 4; kf++) {
            const int koff = kf * 32 + lk * 8;
            #pragma unroll
            for (int rf = 0; rf < 2; rf++) {
                const int lrow = rf * 16 + l15;
                const int baddr = lrow * 256 + ((koff * 2) ^ ((lrow & 7) << 4));
                bfrag hrf = *(const bfrag*)((char*)hrT[par] + baddr);
                ah[rf] = __builtin_amdgcn_mfma_f32_16x16x32_bf16(hrf, Bhh[kf + 4], ah[rf], 0, 0, 0);
            }
        }

        // epilogue h: H_new = z*H + (1-z)*tanh(a_h), bf16 in place
        #pragma unroll
        for (int rf = 0; rf < 2; rf++) {
            #pragma unroll
            for (int r = 0; r < 4; r++) {
                const int row = rowBase + rf * 16 + lk * 4 + r;
                const float sr = svec[row];
                const float av = ah[rf][r] + sr * vh + ch;
                const float ht = tanhf(av);
                const float z = zv[rf][r];
                const float hn = z * Hf[rf][r] + (1.f - z) * ht;
                Hbf[(size_t)row * 128 + col] = __float2bfloat16(hn);
            }
        }
    }
}

// ---------------------------------------------------------------------------
// Vectorized global max pool: block=256 (4 waves), 16 rows/iter/block,
// thread owns 8 cols via uint4; wave shfl-reduce + LDS cross-wave.
// ---------------------------------------------------------------------------
__global__ void maxpool_partial(const __hip_bfloat16* __restrict__ H,
                                float* __restrict__ part) {
    __shared__ float red[4][128];
    const int tid = threadIdx.x;
    const int lane = tid & 63;
    const int wid = tid >> 6;
    const int l16 = lane & 15;
    const int rowslot = wid * 4 + (lane >> 4);   // 0..15

    float m[8];
    #pragma unroll
    for (int i = 0; i < 8; i++) m[i] = -1e30f;

    for (int r = blockIdx.x * 16 + rowslot; r < NN; r += gridDim.x * 16) {
        uint4 raw = *(const uint4*)&H[(size_t)r * 128 + l16 * 8];
        m[0] = fmaxf(m[0], bflo(raw.x)); m[1] = fmaxf(m[1], bfhi(raw.x));
        m[2] = fmaxf(m[2], bflo(raw.y)); m[3] = fmaxf(m[3], bfhi(raw.y));
        m[4] = fmaxf(m[4], bflo(raw.z)); m[5] = fmaxf(m[5], bfhi(raw.z));
        m[6] = fmaxf(m[6], bflo(raw.w)); m[7] = fmaxf(m[7], bfhi(raw.w));
    }
    #pragma unroll
    for (int i = 0; i < 8; i++) {
        m[i] = fmaxf(m[i], __shfl_xor(m[i], 16));
        m[i] = fmaxf(m[i], __shfl_xor(m[i], 32));
    }
    if (lane < 16) {
        #pragma unroll
        for (int i = 0; i < 8; i++) red[wid][l16 * 8 + i] = m[i];
    }
    __syncthreads();
    if (tid < 128) {
        float v = fmaxf(fmaxf(red[0][tid], red[1][tid]),
                        fmaxf(red[2][tid], red[3][tid]));
        part[blockIdx.x * 128 + tid] = v;
    }
}

__global__ void final_out(const float* __restrict__ part, const float* __restrict__ W2,
                          const float* __restrict__ b2, float* __restrict__ out) {
    __shared__ float hmax[128];
    int tid = threadIdx.x;  // 128
    float m = -1e30f;
    for (int b = 0; b < MPGRID; b++) m = fmaxf(m, part[b * 128 + tid]);
    hmax[tid] = m;
    __syncthreads();
    if (tid < 10) {
        float sacc = b2[tid];
        for (int c = 0; c < 128; c++) sacc += hmax[c] * W2[c * 10 + tid];
        out[tid] = sacc;
    }
}

extern "C" void kernel_launch(void* const* d_in, const int* in_sizes, int n_in,
                              void* d_out, int out_size, void* d_ws, size_t ws_size,
                              hipStream_t stream) {
    const float* x[3]     = {(const float*)d_in[0], (const float*)d_in[2], (const float*)d_in[4]};
    const int*   edges[3] = {(const int*)d_in[1], (const int*)d_in[3], (const int*)d_in[5]};
    const float* W1 = (const float*)d_in[6];
    const float* b1 = (const float*)d_in[7];
    const float* convW[3] = {(const float*)d_in[8], (const float*)d_in[12], (const float*)d_in[16]};
    const float* convb[3] = {(const float*)d_in[9], (const float*)d_in[13], (const float*)d_in[17]};
    const float* linW[3]  = {(const float*)d_in[10], (const float*)d_in[14], (const float*)d_in[18]};
    const float* linb[3]  = {(const float*)d_in[11], (const float*)d_in[15], (const float*)d_in[19]};
    const float* W2 = (const float*)d_in[20];
    const float* b2 = (const float*)d_in[21];

    float* ws   = (float*)d_ws;
    float* B3   = ws;                  // 98304
    float* v3   = B3 + 98304;          // 384
    float* c3   = v3 + 384;            // 384
    float* M    = c3 + 384;            // 49152
    float* dinv = M + 49152;           // NN
    float* svb  = dinv + NN;           // NN
    float* part = svb + NN;            // MPGRID*128 = 65536
    int*   deg  = (int*)(part + 65536);     // NN (reused as cursor)
    int*   offs = deg + NN;                 // NN+4
    int*   partial = offs + NN + 4;         // 128
    int*   sorted_src = partial + 128;      // EE
    __hip_bfloat16* Bzr = (__hip_bfloat16*)(sorted_src + EE);   // 65536
    __hip_bfloat16* Bh  = Bzr + 65536;                          // 32768
    __hip_bfloat16* ybf = Bh + 32768;                           // NN*128
    __hip_bfloat16* Hbf = ybf + (size_t)NN * 128;               // NN*128
    __hip_bfloat16* xs  = Hbf + (size_t)NN * 128;               // NN*128
    // total ~86 MB

    prep1<<<192, 256, 0, stream>>>(convW[0], convW[1], convW[2],
                                   linW[0], linW[1], linW[2], M);
    prep2<<<384, 256, 0, stream>>>(W1, M, linW[0], linW[1], linW[2], B3);
    prep3<<<2, 256, 0, stream>>>(b1, M, convb[0], convb[1], convb[2],
                                 linW[0], linW[1], linW[2],
                                 linb[0], linb[1], linb[2], v3, c3);
    pack_zr<<<256, 256, 0, stream>>>(B3, Bzr);
    pack_h<<<128, 256, 0, stream>>>(B3, Bh);

    hipMemsetAsync(Hbf, 0, (size_t)NN * 128 * sizeof(__hip_bfloat16), stream);

    for (int t = 0; t < 3; t++) {
        const int* src = edges[t];
        const int* dst = edges[t] + EE;

        hipMemsetAsync(deg, 0, NN * sizeof(int), stream);
        hist_kernel<<<2048, 256, 0, stream>>>(dst, deg);
        scan_local<<<SCAN_NB, SCAN_B, 0, stream>>>(deg, offs, partial, dinv);
        scan_carry<<<1, 128, 0, stream>>>(partial, offs);
        scan_add<<<SCAN_NB, SCAN_B, 0, stream>>>(offs, partial);
        xscale_bf<<<12500, 256, 0, stream>>>(x[t], dinv, xs);
        bucket_fill<<<2048, 256, 0, stream>>>(src, dst, offs, deg, sorted_src);
        gather_agg<<<25000, 256, 0, stream>>>(sorted_src, offs, xs, dinv, ybf, svb);

        gate_fused<<<512, 512, 0, stream>>>(ybf, Hbf, Bzr, Bh, v3, c3, svb);
    }

    maxpool_partial<<<MPGRID, 256, 0, stream>>>(Hbf, part);
    final_out<<<1, 128, 0, stream>>>(part, W2, b2, (float*)d_out);
}

// Round 10
// 1122.600 us; speedup vs baseline: 5.2178x; 1.0467x over previous
//
#include <hip/hip_runtime.h>
#include <hip/hip_bf16.h>
#include <math.h>

#define NN 100000
#define EE 1600000
#define SCAN_B 1024
#define SCAN_NB 98   // ceil(100000/1024)
#define NTILES 3125  // NN / 32 exactly
#define MPGRID 512   // maxpool partial blocks
#define NCOH 12500   // NN / 8 nodes per XCD cohort

typedef __attribute__((ext_vector_type(8))) short bfrag;   // 8 bf16 = 4 VGPR
typedef __attribute__((ext_vector_type(4))) float facc;    // 4 f32 acc

__device__ __forceinline__ float bflo(unsigned u) {
    return __uint_as_float((u & 0xffffu) << 16);
}
__device__ __forceinline__ float bfhi(unsigned u) {
    return __uint_as_float(u & 0xffff0000u);
}
__device__ __forceinline__ unsigned short f2bf(float f) {
    __hip_bfloat16 b = __float2bfloat16(f);
    return *(unsigned short*)&b;
}

// ---------------------------------------------------------------------------
// Weight folding:  M_g = convW_g @ linW_g[0:128,:]        (128x128)
//                  B3_g = [ W1 @ M_g ; linW_g[128:256,:] ] (256x128)
//                  v_g = b1 @ M_g ; c_g = convb_g @ linW_g[0:128,:] + linb_g
// Gate pre-activation: a_g = [y | H] @ B3_g + s*v_g + c_g
// y = Norm(x), s = Norm(1), Norm = D^-1/2 (A+I) D^-1/2
// ---------------------------------------------------------------------------
__global__ void prep1(const float* __restrict__ Wcz, const float* __restrict__ Wcr,
                      const float* __restrict__ Wch,
                      const float* __restrict__ Wlz, const float* __restrict__ Wlr,
                      const float* __restrict__ Wlh,
                      float* __restrict__ M) {
    int idx = blockIdx.x * 256 + threadIdx.x;   // 3*16384
    int g = idx >> 14, r = idx & 16383;
    int i = r >> 7, j = r & 127;
    const float* Wc = g == 0 ? Wcz : (g == 1 ? Wcr : Wch);
    const float* Wl = g == 0 ? Wlz : (g == 1 ? Wlr : Wlh);
    float s = 0.f;
    for (int m = 0; m < 128; m++) s += Wc[i * 128 + m] * Wl[m * 128 + j];
    M[idx] = s;
}

__global__ void prep2(const float* __restrict__ W1, const float* __restrict__ M,
                      const float* __restrict__ Wlz, const float* __restrict__ Wlr,
                      const float* __restrict__ Wlh,
                      float* __restrict__ B) {
    int idx = blockIdx.x * 256 + threadIdx.x;  // 3*256*128
    int g = idx >> 15, r = idx & 32767;
    int k = r >> 7, j = r & 127;
    float o;
    if (k < 128) {
        const float* Mg = M + g * 16384;
        float sacc = 0.f;
        for (int m = 0; m < 128; m++) sacc += W1[k * 128 + m] * Mg[m * 128 + j];
        o = sacc;
    } else {
        const float* Wl = g == 0 ? Wlz : (g == 1 ? Wlr : Wlh);
        o = Wl[k * 128 + j];
    }
    B[idx] = o;
}

__global__ void prep3(const float* __restrict__ b1, const float* __restrict__ M,
                      const float* __restrict__ bcz, const float* __restrict__ bcr,
                      const float* __restrict__ bch,
                      const float* __restrict__ Wlz, const float* __restrict__ Wlr,
                      const float* __restrict__ Wlh,
                      const float* __restrict__ blz, const float* __restrict__ blr,
                      const float* __restrict__ blh,
                      float* __restrict__ v, float* __restrict__ c) {
    int idx = blockIdx.x * 256 + threadIdx.x;
    if (idx >= 384) return;
    int g = idx >> 7, j = idx & 127;
    const float* Mg = M + g * 16384;
    float sv = 0.f;
    for (int m = 0; m < 128; m++) sv += b1[m] * Mg[m * 128 + j];
    v[idx] = sv;
    const float* bc = g == 0 ? bcz : (g == 1 ? bcr : bch);
    const float* Wl = g == 0 ? Wlz : (g == 1 ? Wlr : Wlh);
    const float* bl = g == 0 ? blz : (g == 1 ? blr : blh);
    float sc = bl[j];
    for (int m = 0; m < 128; m++) sc += bc[m] * Wl[m * 128 + j];
    c[idx] = sc;
}

// Frag-packed bf16 B for MFMA. Frag f=(gcf*8+kf): elem (lane,i) =
// B3[g][kf*32+(lane>>4)*8+i][(gcf&7)*16+(lane&15)], g = gcf>>3 (zr) or 2 (h).
__global__ void pack_zr(const float* __restrict__ B3, __hip_bfloat16* __restrict__ out) {
    int idx = blockIdx.x * 256 + threadIdx.x;  // 65536
    if (idx >= 65536) return;
    int i = idx & 7, lane = (idx >> 3) & 63, kf = (idx >> 9) & 7, gcf = idx >> 12;
    int g = gcf >> 3;
    int j = (gcf & 7) * 16 + (lane & 15);
    int k = kf * 32 + (lane >> 4) * 8 + i;
    out[idx] = __float2bfloat16(B3[g * 32768 + k * 128 + j]);
}

__global__ void pack_h(const float* __restrict__ B3, __hip_bfloat16* __restrict__ out) {
    int idx = blockIdx.x * 256 + threadIdx.x;  // 32768
    if (idx >= 32768) return;
    int i = idx & 7, lane = (idx >> 3) & 63, kf = (idx >> 9) & 7, cf = idx >> 12;
    int j = cf * 16 + (lane & 15);
    int k = kf * 32 + (lane >> 4) * 8 + i;
    out[idx] = __float2bfloat16(B3[2 * 32768 + k * 128 + j]);
}

// ---------------------------------------------------------------------------
// CSR build: histogram -> exclusive scan (+dinv, +cursor-zero) -> bucket fill
// ---------------------------------------------------------------------------
__global__ void hist_kernel(const int* __restrict__ dst, int* __restrict__ deg) {
    int i = blockIdx.x * blockDim.x + threadIdx.x;
    int stride = gridDim.x * blockDim.x;
    for (; i < EE; i += stride) atomicAdd(&deg[dst[i]], 1);
}

// local exclusive scan + partials; also dinv[i] = rsqrt(deg+1) and deg := 0
__global__ void scan_local(int* __restrict__ deg, int* __restrict__ offs,
                           int* __restrict__ partial, float* __restrict__ dinv) {
    __shared__ int sm[SCAN_B];
    int t = threadIdx.x;
    int i = blockIdx.x * SCAN_B + t;
    int v = (i < NN) ? deg[i] : 0;
    sm[t] = v;
    __syncthreads();
    #pragma unroll
    for (int off = 1; off < SCAN_B; off <<= 1) {
        int x = (t >= off) ? sm[t - off] : 0;
        __syncthreads();
        sm[t] += x;
        __syncthreads();
    }
    if (i < NN) {
        offs[i] = sm[t] - v;
        dinv[i] = rsqrtf((float)v + 1.0f);  // +1 = self loop
        deg[i] = 0;                          // becomes bucket_fill cursor
    }
    if (t == SCAN_B - 1) partial[blockIdx.x] = sm[t];
}

// parallel exclusive scan of the 98 block partials (one 128-thread block)
__global__ void scan_carry(int* __restrict__ partial, int* __restrict__ offs) {
    __shared__ int sm[128];
    int t = threadIdx.x;
    int v = (t < SCAN_NB) ? partial[t] : 0;
    sm[t] = v;
    __syncthreads();
    #pragma unroll
    for (int off = 1; off < 128; off <<= 1) {
        int x = (t >= off) ? sm[t - off] : 0;
        __syncthreads();
        sm[t] += x;
        __syncthreads();
    }
    if (t < SCAN_NB) partial[t] = sm[t] - v;   // exclusive
    if (t == SCAN_NB - 1) offs[NN] = sm[t];    // == EE
}

__global__ void scan_add(int* __restrict__ offs, const int* __restrict__ partial) {
    int i = blockIdx.x * SCAN_B + threadIdx.x;
    if (i < NN) offs[i] += partial[blockIdx.x];
}

// xs[i,:] = bf16(dinv[i] * x[i,:])
__global__ void xscale_bf(const float* __restrict__ x, const float* __restrict__ dinv,
                          __hip_bfloat16* __restrict__ xs) {
    int idx = blockIdx.x * 256 + threadIdx.x;   // NN*32 threads, 4 elems each
    int row = idx >> 5, c4 = (idx & 31) * 4;
    float di = dinv[row];
    float4 v = *(const float4*)&x[(size_t)row * 128 + c4];
    uint2 o;
    o.x = (unsigned)f2bf(di * v.x) | ((unsigned)f2bf(di * v.y) << 16);
    o.y = (unsigned)f2bf(di * v.z) | ((unsigned)f2bf(di * v.w) << 16);
    *(uint2*)&xs[(size_t)row * 128 + c4] = o;
}

// XCD-partitioned bucket fill: cohort p = blockIdx&7 (round-robin block->XCD
// map) handles dst in [p*NCOH, p*NCOH+NCOH); its writes land in the contiguous
// sorted_src[offs[lo]..offs[hi]) region (~800 KB) kept in that XCD's L2, so
// 64B lines fill completely before writeback (kills the 16x write amplification
// of global random 4B scatter). dst[] is re-read 8x but L2/L3-cached.
__global__ void bucket_fill(const int* __restrict__ src, const int* __restrict__ dst,
                            const int* __restrict__ offs, int* __restrict__ cursor,
                            int* __restrict__ sorted_src) {
    const int coh = blockIdx.x & 7;
    const int lo = coh * NCOH, hi = lo + NCOH;   // NN = 8*NCOH exactly
    int i = (blockIdx.x >> 3) * blockDim.x + threadIdx.x;
    const int stride = (gridDim.x >> 3) * blockDim.x;
    for (; i < EE; i += stride) {
        int d = dst[i];
        if (d >= lo && d < hi) {
            int pos = offs[d] + atomicAdd(&cursor[d], 1);
            sorted_src[pos] = src[i];
        }
    }
}

// ---------------------------------------------------------------------------
// Gather aggregation: one wave per dst node, EIGHT edges per iteration
// (quarter q = lane>>4 handles edges e+q and e+4+q; two uint4 loads in
// flight per lane for latency hiding).
// ---------------------------------------------------------------------------
__global__ void gather_agg(const int* __restrict__ sorted_src,
                           const int* __restrict__ offs,
                           const __hip_bfloat16* __restrict__ xs,
                           const float* __restrict__ dinv,
                           __hip_bfloat16* __restrict__ y, float* __restrict__ sv) {
    const int lane = threadIdx.x & 63;
    const int q = lane >> 4;
    const int l16 = lane & 15;
    const int node = blockIdx.x * 4 + (threadIdx.x >> 6);
    if (node >= NN) return;
    const int beg = offs[node], end = offs[node + 1];

    float a[8] = {0.f, 0.f, 0.f, 0.f, 0.f, 0.f, 0.f, 0.f};
    float sacc = 0.f;
    for (int e = beg; e < end; e += 8) {
        const int ei0 = e + q, ei1 = e + 4 + q;
        const bool ok0 = ei0 < end, ok1 = ei1 < end;
        const int s0 = sorted_src[ok0 ? ei0 : beg];
        const int s1 = sorted_src[ok1 ? ei1 : beg];
        const float w0 = ok0 ? 1.f : 0.f, w1 = ok1 ? 1.f : 0.f;
        const uint4 r0 = *(const uint4*)&xs[(size_t)s0 * 128 + l16 * 8];
        const uint4 r1 = *(const uint4*)&xs[(size_t)s1 * 128 + l16 * 8];
        a[0] += w0 * bflo(r0.x); a[1] += w0 * bfhi(r0.x);
        a[2] += w0 * bflo(r0.y); a[3] += w0 * bfhi(r0.y);
        a[4] += w0 * bflo(r0.z); a[5] += w0 * bfhi(r0.z);
        a[6] += w0 * bflo(r0.w); a[7] += w0 * bfhi(r0.w);
        a[0] += w1 * bflo(r1.x); a[1] += w1 * bfhi(r1.x);
        a[2] += w1 * bflo(r1.y); a[3] += w1 * bfhi(r1.y);
        a[4] += w1 * bflo(r1.z); a[5] += w1 * bfhi(r1.z);
        a[6] += w1 * bflo(r1.w); a[7] += w1 * bfhi(r1.w);
        sacc += w0 * dinv[s0] + w1 * dinv[s1];
    }
    #pragma unroll
    for (int i = 0; i < 8; i++) {
        a[i] += __shfl_xor(a[i], 16);
        a[i] += __shfl_xor(a[i], 32);
    }
    sacc += __shfl_xor(sacc, 16);
    sacc += __shfl_xor(sacc, 32);

    const float di = dinv[node];
    if (q == 0) {
        uint4 raw = *(const uint4*)&xs[(size_t)node * 128 + l16 * 8];
        float o0 = di * (a[0] + bflo(raw.x)), o1 = di * (a[1] + bfhi(raw.x));
        float o2 = di * (a[2] + bflo(raw.y)), o3 = di * (a[3] + bfhi(raw.y));
        float o4 = di * (a[4] + bflo(raw.z)), o5 = di * (a[5] + bfhi(raw.z));
        float o6 = di * (a[6] + bflo(raw.w)), o7 = di * (a[7] + bfhi(raw.w));
        uint4 o;
        o.x = (unsigned)f2bf(o0) | ((unsigned)f2bf(o1) << 16);
        o.y = (unsigned)f2bf(o2) | ((unsigned)f2bf(o3) << 16);
        o.z = (unsigned)f2bf(o4) | ((unsigned)f2bf(o5) << 16);
        o.w = (unsigned)f2bf(o6) | ((unsigned)f2bf(o7) << 16);
        *(uint4*)&y[(size_t)node * 128 + l16 * 8] = o;
    }
    if (lane == 0) sv[node] = di * (sacc + di);
}

// ---------------------------------------------------------------------------
// Fully fused gate kernel, bf16-only H. Block = 8 waves; wave owns 16 cols.
// Per 32-row tile: a_z,a_r MFMA -> z,r regs -> Hr via swizzled LDS (double-
// buffered, ONE sync/tile) -> a_h MFMA -> H_new (bf16, in place).
// ---------------------------------------------------------------------------
__launch_bounds__(512, 2)
__global__ void gate_fused(const __hip_bfloat16* __restrict__ ybf,
                           __hip_bfloat16* __restrict__ Hbf,
                           const __hip_bfloat16* __restrict__ Bzr,
                           const __hip_bfloat16* __restrict__ Bh,
                           const float* __restrict__ v3, const float* __restrict__ c3,
                           const float* __restrict__ svec) {
    __shared__ __hip_bfloat16 hrT[2][32 * 128];   // 16 KB, double-buffered
    const int lane = threadIdx.x & 63;
    const int wid = threadIdx.x >> 6;             // col-frag 0..7
    const int l15 = lane & 15, lk = lane >> 4;

    bfrag Bz[8], Br[8], Bhh[8];
    #pragma unroll
    for (int kf = 0; kf < 8; kf++) {
        Bz[kf]  = *(const bfrag*)&Bzr[(size_t)(((0 * 8 + wid) * 8 + kf) * 64 + lane) * 8];
        Br[kf]  = *(const bfrag*)&Bzr[(size_t)(((1 * 8 + wid) * 8 + kf) * 64 + lane) * 8];
        Bhh[kf] = *(const bfrag*)&Bh[(size_t)((wid * 8 + kf) * 64 + lane) * 8];
    }
    const int col = wid * 16 + l15;
    const float vz = v3[col],       cz = c3[col];
    const float vr = v3[128 + col], cr = c3[128 + col];
    const float vh = v3[256 + col], ch = c3[256 + col];

    int par = 0;
    for (int tile = blockIdx.x; tile < NTILES; tile += gridDim.x, par ^= 1) {
        const int rowBase = tile * 32;

        bfrag ay[4][2], ahf[4][2];
        #pragma unroll
        for (int kf = 0; kf < 4; kf++) {
            const int koff = kf * 32 + lk * 8;
            #pragma unroll
            for (int rf = 0; rf < 2; rf++) {
                const size_t rowoff = (size_t)(rowBase + rf * 16 + l15) * 128 + koff;
                ay[kf][rf]  = *(const bfrag*)&ybf[rowoff];
                ahf[kf][rf] = *(const bfrag*)&Hbf[rowoff];
            }
        }

        facc az[2], ar[2];
        #pragma unroll
        for (int rf = 0; rf < 2; rf++) { az[rf] = (facc){0.f,0.f,0.f,0.f}; ar[rf] = (facc){0.f,0.f,0.f,0.f}; }

        #pragma unroll
        for (int kf = 0; kf < 4; kf++)
            #pragma unroll
            for (int rf = 0; rf < 2; rf++) {
                az[rf] = __builtin_amdgcn_mfma_f32_16x16x32_bf16(ay[kf][rf],  Bz[kf],     az[rf], 0, 0, 0);
                ar[rf] = __builtin_amdgcn_mfma_f32_16x16x32_bf16(ay[kf][rf],  Br[kf],     ar[rf], 0, 0, 0);
                az[rf] = __builtin_amdgcn_mfma_f32_16x16x32_bf16(ahf[kf][rf], Bz[kf + 4], az[rf], 0, 0, 0);
                ar[rf] = __builtin_amdgcn_mfma_f32_16x16x32_bf16(ahf[kf][rf], Br[kf + 4], ar[rf], 0, 0, 0);
            }

        // epilogue z/r: z,H kept in regs; Hr -> swizzled LDS (buffer `par`)
        float zv[2][4], Hf[2][4];
        #pragma unroll
        for (int rf = 0; rf < 2; rf++) {
            #pragma unroll
            for (int r = 0; r < 4; r++) {
                const int lrow = rf * 16 + lk * 4 + r;
                const int row = rowBase + lrow;
                const float sr = svec[row];
                const float azv = az[rf][r] + sr * vz + cz;
                const float arv = ar[rf][r] + sr * vr + cr;
                const float z  = 1.f / (1.f + expf(-azv));
                const float rr = 1.f / (1.f + expf(-arv));
                const float hf = __bfloat162float(Hbf[(size_t)row * 128 + col]);
                zv[rf][r] = z;
                Hf[rf][r] = hf;
                const int baddr = lrow * 256 + ((col * 2) ^ ((lrow & 7) << 4));
                *(__hip_bfloat16*)((char*)hrT[par] + baddr) = __float2bfloat16(hf * rr);
            }
        }

        // h-gate upper-K MFMAs (independent of LDS) before the barrier
        facc ah[2];
        #pragma unroll
        for (int rf = 0; rf < 2; rf++) ah[rf] = (facc){0.f,0.f,0.f,0.f};
        #pragma unroll
        for (int kf = 0; kf < 4; kf++)
            #pragma unroll
            for (int rf = 0; rf < 2; rf++)
                ah[rf] = __builtin_amdgcn_mfma_f32_16x16x32_bf16(ay[kf][rf], Bhh[kf], ah[rf], 0, 0, 0);

        __syncthreads();   // Hr tile visible

        #pragma unroll
        for (int kf = 0; kf < 4; kf++) {
            const int koff = kf * 32 + lk * 8;
            #pragma unroll
            for (int rf = 0; rf < 2; rf++) {
                const int lrow = rf * 16 + l15;
                const int baddr = lrow * 256 + ((koff * 2) ^ ((lrow & 7) << 4));
                bfrag hrf = *(const bfrag*)((char*)hrT[par] + baddr);
                ah[rf] = __builtin_amdgcn_mfma_f32_16x16x32_bf16(hrf, Bhh[kf + 4], ah[rf], 0, 0, 0);
            }
        }

        // epilogue h: H_new = z*H + (1-z)*tanh(a_h), bf16 in place
        #pragma unroll
        for (int rf = 0; rf < 2; rf++) {
            #pragma unroll
            for (int r = 0; r < 4; r++) {
                const int row = rowBase + rf * 16 + lk * 4 + r;
                const float sr = svec[row];
                const float av = ah[rf][r] + sr * vh + ch;
                const float ht = tanhf(av);
                const float z = zv[rf][r];
                const float hn = z * Hf[rf][r] + (1.f - z) * ht;
                Hbf[(size_t)row * 128 + col] = __float2bfloat16(hn);
            }
        }
    }
}

// ---------------------------------------------------------------------------
// Vectorized global max pool: block=256 (4 waves), 16 rows/iter/block,
// thread owns 8 cols via uint4; wave shfl-reduce + LDS cross-wave.
// ---------------------------------------------------------------------------
__global__ void maxpool_partial(const __hip_bfloat16* __restrict__ H,
                                float* __restrict__ part) {
    __shared__ float red[4][128];
    const int tid = threadIdx.x;
    const int lane = tid & 63;
    const int wid = tid >> 6;
    const int l16 = lane & 15;
    const int rowslot = wid * 4 + (lane >> 4);   // 0..15

    float m[8];
    #pragma unroll
    for (int i = 0; i < 8; i++) m[i] = -1e30f;

    for (int r = blockIdx.x * 16 + rowslot; r < NN; r += gridDim.x * 16) {
        uint4 raw = *(const uint4*)&H[(size_t)r * 128 + l16 * 8];
        m[0] = fmaxf(m[0], bflo(raw.x)); m[1] = fmaxf(m[1], bfhi(raw.x));
        m[2] = fmaxf(m[2], bflo(raw.y)); m[3] = fmaxf(m[3], bfhi(raw.y));
        m[4] = fmaxf(m[4], bflo(raw.z)); m[5] = fmaxf(m[5], bfhi(raw.z));
        m[6] = fmaxf(m[6], bflo(raw.w)); m[7] = fmaxf(m[7], bfhi(raw.w));
    }
    #pragma unroll
    for (int i = 0; i < 8; i++) {
        m[i] = fmaxf(m[i], __shfl_xor(m[i], 16));
        m[i] = fmaxf(m[i], __shfl_xor(m[i], 32));
    }
    if (lane < 16) {
        #pragma unroll
        for (int i = 0; i < 8; i++) red[wid][l16 * 8 + i] = m[i];
    }
    __syncthreads();
    if (tid < 128) {
        float v = fmaxf(fmaxf(red[0][tid], red[1][tid]),
                        fmaxf(red[2][tid], red[3][tid]));
        part[blockIdx.x * 128 + tid] = v;
    }
}

__global__ void final_out(const float* __restrict__ part, const float* __restrict__ W2,
                          const float* __restrict__ b2, float* __restrict__ out) {
    __shared__ float hmax[128];
    int tid = threadIdx.x;  // 128
    float m = -1e30f;
    for (int b = 0; b < MPGRID; b++) m = fmaxf(m, part[b * 128 + tid]);
    hmax[tid] = m;
    __syncthreads();
    if (tid < 10) {
        float sacc = b2[tid];
        for (int c = 0; c < 128; c++) sacc += hmax[c] * W2[c * 10 + tid];
        out[tid] = sacc;
    }
}

extern "C" void kernel_launch(void* const* d_in, const int* in_sizes, int n_in,
                              void* d_out, int out_size, void* d_ws, size_t ws_size,
                              hipStream_t stream) {
    const float* x[3]     = {(const float*)d_in[0], (const float*)d_in[2], (const float*)d_in[4]};
    const int*   edges[3] = {(const int*)d_in[1], (const int*)d_in[3], (const int*)d_in[5]};
    const float* W1 = (const float*)d_in[6];
    const float* b1 = (const float*)d_in[7];
    const float* convW[3] = {(const float*)d_in[8], (const float*)d_in[12], (const float*)d_in[16]};
    const float* convb[3] = {(const float*)d_in[9], (const float*)d_in[13], (const float*)d_in[17]};
    const float* linW[3]  = {(const float*)d_in[10], (const float*)d_in[14], (const float*)d_in[18]};
    const float* linb[3]  = {(const float*)d_in[11], (const float*)d_in[15], (const float*)d_in[19]};
    const float* W2 = (const float*)d_in[20];
    const float* b2 = (const float*)d_in[21];

    float* ws   = (float*)d_ws;
    float* B3   = ws;                  // 98304
    float* v3   = B3 + 98304;          // 384
    float* c3   = v3 + 384;            // 384
    float* M    = c3 + 384;            // 49152
    float* dinv = M + 49152;           // NN
    float* svb  = dinv + NN;           // NN
    float* part = svb + NN;            // MPGRID*128 = 65536
    int*   deg  = (int*)(part + 65536);     // NN (reused as cursor)
    int*   offs = deg + NN;                 // NN+4
    int*   partial = offs + NN + 4;         // 128
    int*   sorted_src = partial + 128;      // EE
    __hip_bfloat16* Bzr = (__hip_bfloat16*)(sorted_src + EE);   // 65536
    __hip_bfloat16* Bh  = Bzr + 65536;                          // 32768
    __hip_bfloat16* ybf = Bh + 32768;                           // NN*128
    __hip_bfloat16* Hbf = ybf + (size_t)NN * 128;               // NN*128
    __hip_bfloat16* xs  = Hbf + (size_t)NN * 128;               // NN*128
    // total ~86 MB

    prep1<<<192, 256, 0, stream>>>(convW[0], convW[1], convW[2],
                                   linW[0], linW[1], linW[2], M);
    prep2<<<384, 256, 0, stream>>>(W1, M, linW[0], linW[1], linW[2], B3);
    prep3<<<2, 256, 0, stream>>>(b1, M, convb[0], convb[1], convb[2],
                                 linW[0], linW[1], linW[2],
                                 linb[0], linb[1], linb[2], v3, c3);
    pack_zr<<<256, 256, 0, stream>>>(B3, Bzr);
    pack_h<<<128, 256, 0, stream>>>(B3, Bh);

    hipMemsetAsync(Hbf, 0, (size_t)NN * 128 * sizeof(__hip_bfloat16), stream);

    for (int t = 0; t < 3; t++) {
        const int* src = edges[t];
        const int* dst = edges[t] + EE;

        hipMemsetAsync(deg, 0, NN * sizeof(int), stream);
        hist_kernel<<<2048, 256, 0, stream>>>(dst, deg);
        scan_local<<<SCAN_NB, SCAN_B, 0, stream>>>(deg, offs, partial, dinv);
        scan_carry<<<1, 128, 0, stream>>>(partial, offs);
        scan_add<<<SCAN_NB, SCAN_B, 0, stream>>>(offs, partial);
        xscale_bf<<<12500, 256, 0, stream>>>(x[t], dinv, xs);
        bucket_fill<<<2048, 256, 0, stream>>>(src, dst, offs, deg, sorted_src);
        gather_agg<<<25000, 256, 0, stream>>>(sorted_src, offs, xs, dinv, ybf, svb);

        gate_fused<<<512, 512, 0, stream>>>(ybf, Hbf, Bzr, Bh, v3, c3, svb);
    }

    maxpool_partial<<<MPGRID, 256, 0, stream>>>(Hbf, part);
    final_out<<<1, 128, 0, stream>>>(part, W2, b2, (float*)d_out);
}